// Round 4
// baseline (4335.797 us; speedup 1.0000x reference)
//
#include <hip/hip_runtime.h>
#include <hip/hip_bf16.h>

#define H 128
#define HH 16384
#define LNUM 4
#define NN 4096
#define SS 8192
#define SKK 262144
#define EI 1048576
#define EG 65536
#define NGRAPH 64

typedef unsigned short u16;
typedef unsigned int u32;
typedef __attribute__((ext_vector_type(8))) short s16x8;
typedef __attribute__((ext_vector_type(4))) float f32x4;

__device__ __forceinline__ float b2f(u32 u){ return __uint_as_float(u<<16); }
__device__ __forceinline__ u16 f2b(float f){
  union { __hip_bfloat16 b; u16 u; } x;
  x.b=__float2bfloat16(f);
  return x.u;
}
__device__ __forceinline__ void unp8(uint4 v, float* f){
  f[0]=b2f(v.x&0xFFFF); f[1]=b2f(v.x>>16);
  f[2]=b2f(v.y&0xFFFF); f[3]=b2f(v.y>>16);
  f[4]=b2f(v.z&0xFFFF); f[5]=b2f(v.z>>16);
  f[6]=b2f(v.w&0xFFFF); f[7]=b2f(v.w>>16);
}
__device__ __forceinline__ void unp4(uint2 v, float* f){
  f[0]=b2f(v.x&0xFFFF); f[1]=b2f(v.x>>16);
  f[2]=b2f(v.y&0xFFFF); f[3]=b2f(v.y>>16);
}
__device__ __forceinline__ uint4 pk8(const float* f){
  uint4 r;
  r.x=(u32)f2b(f[0])|((u32)f2b(f[1])<<16);
  r.y=(u32)f2b(f[2])|((u32)f2b(f[3])<<16);
  r.z=(u32)f2b(f[4])|((u32)f2b(f[5])<<16);
  r.w=(u32)f2b(f[6])|((u32)f2b(f[7])<<16);
  return r;
}
__device__ __forceinline__ uint2 pk4(const float* f){
  uint2 r;
  r.x=(u32)f2b(f[0])|((u32)f2b(f[1])<<16);
  r.y=(u32)f2b(f[2])|((u32)f2b(f[3])<<16);
  return r;
}

struct CvtArgs {
  const void* p[26];
  int start[27];
};
struct TransArgs { int src[28]; };

// ---- dtype sniff
__global__ void k_sniff(const u16* __restrict__ a, int* __restrict__ flag){
  __shared__ int cnt;
  if(threadIdx.x==0) cnt=0;
  __syncthreads();
  int big=0;
  for(int i=threadIdx.x;i<2048;i+=256){
    int e=(a[i]>>7)&0xFF;
    if(e>=127) big++;
  }
  atomicAdd(&cnt,big);
  __syncthreads();
  if(threadIdx.x==0) *flag=(cnt<16)?1:0;
}

__global__ void k_convert(CvtArgs args, const int* __restrict__ flag, float* __restrict__ dst){
  int fl=*flag;
  int total=args.start[26];
  for(int i=blockIdx.x*blockDim.x+threadIdx.x;i<total;i+=gridDim.x*blockDim.x){
    int a=0;
    while(args.start[a+1]<=i) a++;
    int j=i-args.start[a];
    float v;
    if(fl) v=b2f(((const u16*)args.p[a])[j]);
    else   v=((const float*)args.p[a])[j];
    dst[i]=v;
  }
}

// ---- static weights: f32 [K][N] -> bf16 W^T [N][K]
__global__ __launch_bounds__(256) void k_trans(const float* __restrict__ par, TransArgs ta, u16* __restrict__ wt){
  const float* s=par+ta.src[blockIdx.x];
  u16* d=wt+(size_t)blockIdx.x*HH;
  for(int i=threadIdx.x;i<HH;i+=256){
    int n=i>>7, k=i&127;
    d[i]=f2b(s[(size_t)k*H+n]);
  }
}

// ---- bond emb f32 -> bf16
__global__ void k_cvtbond(const float* __restrict__ b, u16* __restrict__ bb){
  int i=blockIdx.x*blockDim.x+threadIdx.x;
  if(i<16*H) bb[i]=f2b(b[i]);
}

// ---- fold BN affine into cw1_top
__global__ __launch_bounds__(128) void k_prepw3(const float* __restrict__ w, const float* __restrict__ cb1,
                        const float* __restrict__ bnl, u16* __restrict__ wt3, float* __restrict__ bias3){
  __shared__ float red[128];
  int c=blockIdx.x, k=threadIdx.x;
  float wv=w[(size_t)k*H+c];
  wt3[(size_t)c*H+k]=f2b(bnl[k]*wv);
  red[k]=bnl[128+k]*wv;
  __syncthreads();
  for(int d=64;d>0;d>>=1){ if(k<d) red[k]+=red[k+d]; __syncthreads(); }
  if(k==0) bias3[c]=cb1[c]+red[0];
}

// ---- edge bucketing
__global__ void k_hist(const int* __restrict__ idx, int n, int shift, int* __restrict__ cnt){
  for(int i=blockIdx.x*blockDim.x+threadIdx.x;i<n;i+=gridDim.x*blockDim.x)
    atomicAdd(&cnt[idx[i]>>shift],1);
}

__global__ void k_scan(const int* __restrict__ cnt, int* __restrict__ off, int nbins){
  __shared__ int ts[1024];
  int t=threadIdx.x;
  int per=nbins>>10;
  int base=t*per;
  int s=0;
  for(int j=0;j<per;j++) s+=cnt[base+j];
  ts[t]=s;
  __syncthreads();
  for(int d=1;d<1024;d<<=1){
    int v=(t>=d)?ts[t-d]:0;
    __syncthreads();
    ts[t]+=v;
    __syncthreads();
  }
  int ex=(t==0)?0:ts[t-1];
  for(int j=0;j<per;j++){ off[base+j]=ex; ex+=cnt[base+j]; }
}

__global__ void k_scatter_i(const int* __restrict__ ei, const int* __restrict__ ea,
                            const int* __restrict__ off, int* __restrict__ cur, int* __restrict__ pack){
  for(int i=blockIdx.x*blockDim.x+threadIdx.x;i<EI;i+=gridDim.x*blockDim.x){
    int s=ei[i], d=ei[EI+i];
    int sub=d>>5;
    int pos=off[sub]+atomicAdd(&cur[sub],1);
    pack[pos]=((s&31)<<9)|((d&31)<<4)|(ea[i]&15);
  }
}

__global__ void k_scatter_g(const int* __restrict__ ei, const int* __restrict__ ea,
                            const int* __restrict__ off, int* __restrict__ cur, int* __restrict__ pack){
  for(int i=blockIdx.x*blockDim.x+threadIdx.x;i<EG;i+=gridDim.x*blockDim.x){
    int s=ei[i], d=ei[EG+i];
    int pos=off[d]+atomicAdd(&cur[d],1);
    pack[pos]=(s<<4)|(ea[i]&15);
  }
}

// ---- rf = relu(rwse @ rwse_w + rwse_b)
__global__ __launch_bounds__(128) void k_rwse(const float* __restrict__ rwse, const float* __restrict__ w,
                      const float* __restrict__ b, float* __restrict__ rf){
  __shared__ float ws[16*128];
  __shared__ float rv[16];
  int n=blockIdx.x, c=threadIdx.x;
  for(int i=c;i<2048;i+=128) ws[i]=w[i];
  if(c<16) rv[c]=rwse[n*16+c];
  __syncthreads();
  float acc=b[c];
  for(int j=0;j<16;j++) acc=fmaf(rv[j],ws[j*128+c],acc);
  rf[(size_t)n*H+c]=fmaxf(acc,0.f);
}

// ---- h0
__global__ void k_h0(const float* __restrict__ atom, const float* __restrict__ rf,
                     const int* __restrict__ xids, const int* __restrict__ nids,
                     const int* __restrict__ valid, u16* __restrict__ h){
  int i=blockIdx.x*blockDim.x+threadIdx.x;
  if(i>=SKK*16) return;
  int r=i>>4, q=i&15;
  const float4* ap=(const float4*)(atom+(size_t)xids[r]*H)+q*2;
  const float4* bp=(const float4*)(rf+(size_t)nids[r]*H)+q*2;
  float4 a0=ap[0],a1=ap[1],b0=bp[0],b1=bp[1];
  float vm=valid[r]?1.f:0.f;
  float f[8]={(a0.x+b0.x)*vm,(a0.y+b0.y)*vm,(a0.z+b0.z)*vm,(a0.w+b0.w)*vm,
              (a1.x+b1.x)*vm,(a1.y+b1.y)*vm,(a1.z+b1.z)*vm,(a1.w+b1.w)*vm};
  ((uint4*)h)[i]=pk8(f);
}

// ---- local GINE aggregation: 16 edge-slots x 16 channel-groups, LDS f32 atomics
__global__ __launch_bounds__(256) void k_local_agg(const u16* __restrict__ h, const u16* __restrict__ beb,
                           const int* __restrict__ eoff, const int* __restrict__ ecnt,
                           const int* __restrict__ epack, const float* __restrict__ epsp, int layer,
                           u16* __restrict__ hh){
  __shared__ u16 hs[32*128];
  __shared__ u16 bes[16*128];
  __shared__ float ag[32*128];
  int sub=blockIdx.x, t=threadIdx.x;
  size_t base=(size_t)sub*32*H;
  {
    const uint4* src=(const uint4*)(h+base);
    uint4* dst=(uint4*)hs;
    dst[t]=src[t]; dst[t+256]=src[t+256];
    if(t<256) ((uint4*)bes)[t]=((const uint4*)beb)[t];
    float4* az=(float4*)ag;
    az[t]=make_float4(0,0,0,0); az[t+256]=make_float4(0,0,0,0);
    az[t+512]=make_float4(0,0,0,0); az[t+768]=make_float4(0,0,0,0);
  }
  __syncthreads();
  int slot=t>>4;
  int c0=(((t&15)+slot)&15)*8;   // stagger to spread LDS atomic banks
  int o=eoff[sub], n=ecnt[sub];
  for(int i=slot;i<n;i+=16){
    int p=epack[o+i];
    int sl=p>>9, dl=(p>>4)&31, ea=p&15;
    uint4 hv=*(const uint4*)(hs+sl*128+c0);
    uint4 bv=*(const uint4*)(bes+ea*128+c0);
    float hf[8],bf8[8];
    unp8(hv,hf); unp8(bv,bf8);
    float* agp=ag+dl*128+c0;
    #pragma unroll
    for(int j=0;j<8;j++){
      float mv=fmaxf(hf[j]+bf8[j],0.f);
      atomicAdd(&agp[j],mv);
    }
  }
  __syncthreads();
  float ep=1.f+epsp[layer];
  #pragma unroll
  for(int b=0;b<2;b++){
    int idx=t+b*256;
    int r=idx>>4, ch=(idx&15)*8;
    const u16* hr=hs+r*128+ch;
    const float* ar=ag+r*128+ch;
    float o8[8];
    #pragma unroll
    for(int j=0;j<8;j++) o8[j]=fmaf(ep,b2f(hr[j]),ar[j]);
    ((uint4*)(hh+base))[idx]=pk8(o8);
  }
}

// ==== MFMA GEMM (swapped operands: D[outcol][xrow])
// lane owns: X-row = rowW+m*16+(lane&15); cols n*16+(lane>>4)*4+{0..3}
// MODE 0: out=A@W   MODE 1: relu(A@W+b)   MODE 2: relu+col stats
// MODE 3: gelu(A@W+b+rowbias[node])       MODE 4: LN(A@W+b); out=(res+v)*valid
template<int MODE>
__global__ __launch_bounds__(256) void k_mgemm(
    const u16* __restrict__ A, const u16* __restrict__ Wt,
    const float* __restrict__ bias, u16* __restrict__ out,
    const u16* __restrict__ rowbias,
    float* __restrict__ stats,
    const u16* __restrict__ res, const int* __restrict__ validv,
    const float* __restrict__ lng, const float* __restrict__ lnb)
{
  __shared__ float sst[256];
  int t=threadIdx.x;
  if(MODE==2){ if(t<256) sst[t]=0.f; __syncthreads(); }
  int wave=t>>6, lane=t&63;
  int lr=lane&15, lk=lane>>4;
  int rowW=blockIdx.x*128+wave*32;

  f32x4 acc[2][8];
  #pragma unroll
  for(int m=0;m<2;m++)
    #pragma unroll
    for(int n=0;n<8;n++) acc[m][n]=(f32x4){0.f,0.f,0.f,0.f};

  const s16x8* B0=(const s16x8*)(A+(size_t)(rowW+lr)*H);
  const s16x8* B1=(const s16x8*)(A+(size_t)(rowW+16+lr)*H);

  #pragma unroll
  for(int kc=0;kc<4;kc++){
    s16x8 bf0=B0[kc*4+lk];
    s16x8 bf1=B1[kc*4+lk];
    #pragma unroll
    for(int n=0;n<8;n++){
      s16x8 af=*(const s16x8*)(Wt+(size_t)(n*16+lr)*H+kc*32+lk*8);
      acc[0][n]=__builtin_amdgcn_mfma_f32_16x16x32_bf16(af,bf0,acc[0][n],0,0,0);
      acc[1][n]=__builtin_amdgcn_mfma_f32_16x16x32_bf16(af,bf1,acc[1][n],0,0,0);
    }
  }

  if(MODE==4){
    #pragma unroll
    for(int m=0;m<2;m++){
      int row=rowW+m*16+lr;
      float s=0.f,q=0.f;
      #pragma unroll
      for(int n=0;n<8;n++){
        int c0=n*16+lk*4;
        float4 b4=*(const float4*)(bias+c0);
        float vb[4]={b4.x,b4.y,b4.z,b4.w};
        #pragma unroll
        for(int j=0;j<4;j++){
          float v=acc[m][n][j]+vb[j];
          acc[m][n][j]=v;
          s+=v; q+=v*v;
        }
      }
      s+=__shfl_xor(s,16); s+=__shfl_xor(s,32);
      q+=__shfl_xor(q,16); q+=__shfl_xor(q,32);
      float mu=s*(1.f/128.f);
      float rsig=rsqrtf(q*(1.f/128.f)-mu*mu+1e-5f);
      float vm=validv[row]?1.f:0.f;
      #pragma unroll
      for(int n=0;n<8;n++){
        int c0=n*16+lk*4;
        float4 g4=*(const float4*)(lng+c0);
        float4 e4=*(const float4*)(lnb+c0);
        float g[4]={g4.x,g4.y,g4.z,g4.w}, e[4]={e4.x,e4.y,e4.z,e4.w};
        float r4[4];
        unp4(*(const uint2*)(res+(size_t)row*H+c0),r4);
        float ov[4];
        #pragma unroll
        for(int j=0;j<4;j++)
          ov[j]=(r4[j]+(acc[m][n][j]-mu)*rsig*g[j]+e[j])*vm;
        *(uint2*)(out+(size_t)row*H+c0)=pk4(ov);
      }
    }
  } else {
    int nb=rowW>>6;
    int row0=rowW+lr, row1=rowW+16+lr;
    #pragma unroll
    for(int n=0;n<8;n++){
      int c0=n*16+lk*4;
      float vb[4]={0.f,0.f,0.f,0.f};
      if(bias){
        float4 b4=*(const float4*)(bias+c0);
        vb[0]=b4.x; vb[1]=b4.y; vb[2]=b4.z; vb[3]=b4.w;
      }
      float v0[4],v1[4];
      #pragma unroll
      for(int j=0;j<4;j++){ v0[j]=acc[0][n][j]+vb[j]; v1[j]=acc[1][n][j]+vb[j]; }
      if(MODE==3){
        float rb[4];
        unp4(*(const uint2*)(rowbias+(size_t)nb*H+c0),rb);
        #pragma unroll
        for(int j=0;j<4;j++){
          float x0=v0[j]+rb[j], x1=v1[j]+rb[j];
          v0[j]=0.5f*x0*(1.f+erff(x0*0.70710678118654752f));
          v1[j]=0.5f*x1*(1.f+erff(x1*0.70710678118654752f));
        }
      }
      if(MODE==1||MODE==2){
        #pragma unroll
        for(int j=0;j<4;j++){ v0[j]=fmaxf(v0[j],0.f); v1[j]=fmaxf(v1[j],0.f); }
      }
      *(uint2*)(out+(size_t)row0*H+c0)=pk4(v0);
      *(uint2*)(out+(size_t)row1*H+c0)=pk4(v1);
      if(MODE==2){
        float s[4],q[4];
        #pragma unroll
        for(int j=0;j<4;j++){
          s[j]=v0[j]+v1[j];
          q[j]=v0[j]*v0[j]+v1[j]*v1[j];
        }
        #pragma unroll
        for(int j=0;j<4;j++){
          #pragma unroll
          for(int d=1;d<16;d<<=1){
            s[j]+=__shfl_xor(s[j],d);
            q[j]+=__shfl_xor(q[j],d);
          }
        }
        if(lr==0){
          #pragma unroll
          for(int j=0;j<4;j++){
            atomicAdd(&sst[c0+j],s[j]);
            atomicAdd(&sst[128+c0+j],q[j]);
          }
        }
      }
    }
  }
  if(MODE==2){
    __syncthreads();
    if(t<256) atomicAdd(&stats[t],sst[t]);
  }
}

// ==== fused MLP: out = relu( relu(A@W1+b1) @ W2 + b2 ), optional col stats
template<int STATS>
__global__ __launch_bounds__(256) void k_mlp2(
    const u16* __restrict__ A, const u16* __restrict__ W1t, const float* __restrict__ b1,
    const u16* __restrict__ W2t, const float* __restrict__ b2,
    u16* __restrict__ out, float* __restrict__ stats)
{
  __shared__ u16 T[128*128];
  __shared__ float sst[256];
  int t=threadIdx.x;
  if(STATS){ if(t<256) sst[t]=0.f; __syncthreads(); }
  int wave=t>>6, lane=t&63;
  int lr=lane&15, lk=lane>>4;
  int rowW=blockIdx.x*128+wave*32;

  f32x4 acc[2][8];
  #pragma unroll
  for(int m=0;m<2;m++)
    #pragma unroll
    for(int n=0;n<8;n++) acc[m][n]=(f32x4){0.f,0.f,0.f,0.f};

  const s16x8* B0=(const s16x8*)(A+(size_t)(rowW+lr)*H);
  const s16x8* B1=(const s16x8*)(A+(size_t)(rowW+16+lr)*H);
  #pragma unroll
  for(int kc=0;kc<4;kc++){
    s16x8 bf0=B0[kc*4+lk];
    s16x8 bf1=B1[kc*4+lk];
    #pragma unroll
    for(int n=0;n<8;n++){
      s16x8 af=*(const s16x8*)(W1t+(size_t)(n*16+lr)*H+kc*32+lk*8);
      acc[0][n]=__builtin_amdgcn_mfma_f32_16x16x32_bf16(af,bf0,acc[0][n],0,0,0);
      acc[1][n]=__builtin_amdgcn_mfma_f32_16x16x32_bf16(af,bf1,acc[1][n],0,0,0);
    }
  }
  // relu(.+b1) -> swizzled LDS (wave-local rows; no barrier needed)
  #pragma unroll
  for(int m=0;m<2;m++){
    int rl=wave*32+m*16+lr;
    u32 rb=(u32)rl*256;
    #pragma unroll
    for(int n=0;n<8;n++){
      int c0=n*16+lk*4;
      float4 b4=*(const float4*)(b1+c0);
      float vb[4]={b4.x,b4.y,b4.z,b4.w};
      float v[4];
      #pragma unroll
      for(int j=0;j<4;j++) v[j]=fmaxf(acc[m][n][j]+vb[j],0.f);
      u32 off=rb+(((u32)(c0*2))^((u32)(rl&7)<<4));
      *(uint2*)((char*)T+off)=pk4(v);
    }
  }
  // phase 2
  #pragma unroll
  for(int m=0;m<2;m++)
    #pragma unroll
    for(int n=0;n<8;n++) acc[m][n]=(f32x4){0.f,0.f,0.f,0.f};
  int rl0=wave*32+lr, rl1=rl0+16;
  #pragma unroll
  for(int kc=0;kc<4;kc++){
    u32 cbyte=(u32)((kc*32+lk*8)*2);
    u32 o0=(u32)rl0*256+(cbyte^((u32)(rl0&7)<<4));
    u32 o1=(u32)rl1*256+(cbyte^((u32)(rl1&7)<<4));
    s16x8 bf0=*(const s16x8*)((char*)T+o0);
    s16x8 bf1=*(const s16x8*)((char*)T+o1);
    #pragma unroll
    for(int n=0;n<8;n++){
      s16x8 af=*(const s16x8*)(W2t+(size_t)(n*16+lr)*H+kc*32+lk*8);
      acc[0][n]=__builtin_amdgcn_mfma_f32_16x16x32_bf16(af,bf0,acc[0][n],0,0,0);
      acc[1][n]=__builtin_amdgcn_mfma_f32_16x16x32_bf16(af,bf1,acc[1][n],0,0,0);
    }
  }
  int row0=rowW+lr, row1=rowW+16+lr;
  #pragma unroll
  for(int n=0;n<8;n++){
    int c0=n*16+lk*4;
    float4 b4=*(const float4*)(b2+c0);
    float vb[4]={b4.x,b4.y,b4.z,b4.w};
    float v0[4],v1[4];
    #pragma unroll
    for(int j=0;j<4;j++){
      v0[j]=fmaxf(acc[0][n][j]+vb[j],0.f);
      v1[j]=fmaxf(acc[1][n][j]+vb[j],0.f);
    }
    *(uint2*)(out+(size_t)row0*H+c0)=pk4(v0);
    *(uint2*)(out+(size_t)row1*H+c0)=pk4(v1);
    if(STATS){
      float s[4],q[4];
      #pragma unroll
      for(int j=0;j<4;j++){
        s[j]=v0[j]+v1[j];
        q[j]=v0[j]*v0[j]+v1[j]*v1[j];
      }
      #pragma unroll
      for(int j=0;j<4;j++){
        #pragma unroll
        for(int d=1;d<16;d<<=1){
          s[j]+=__shfl_xor(s[j],d);
          q[j]+=__shfl_xor(q[j],d);
        }
      }
      if(lr==0){
        #pragma unroll
        for(int j=0;j<4;j++){
          atomicAdd(&sst[c0+j],s[j]);
          atomicAdd(&sst[128+c0+j],q[j]);
        }
      }
    }
  }
  if(STATS){
    __syncthreads();
    if(t<256) atomicAdd(&stats[t],sst[t]);
  }
}

// ---- BN stats -> per-column affine
__global__ void k_bnfin(const float* __restrict__ stl, const float* __restrict__ stg,
                        const float* __restrict__ gl, const float* __restrict__ bl,
                        const float* __restrict__ gg, const float* __restrict__ bg,
                        float* __restrict__ bnl, float* __restrict__ bnG){
  int c=threadIdx.x;
  {
    float mu=stl[c]*(1.f/262144.f);
    float var=stl[128+c]*(1.f/262144.f)-mu*mu;
    float s=gl[c]*rsqrtf(var+1e-5f);
    bnl[c]=s; bnl[128+c]=bl[c]-mu*s;
  }
  {
    float mu=stg[c]*(1.f/4096.f);
    float var=stg[128+c]*(1.f/4096.f)-mu*mu;
    float s=gg[c]*rsqrtf(var+1e-5f);
    bnG[c]=s; bnG[128+c]=bg[c]-mu*s;
  }
}

// ---- h_node = mean of two root rows
__global__ void k_npool(const u16* __restrict__ h, u16* __restrict__ hn){
  int i=blockIdx.x*blockDim.x+threadIdx.x;
  if(i>=NN*16) return;
  int n=i>>4, q=i&15;
  const uint4* hp=(const uint4*)h;
  float a[8],b[8],o[8];
  unp8(hp[(size_t)n*1024+q],a);
  unp8(hp[(size_t)n*1024+512+q],b);
  #pragma unroll
  for(int e=0;e<8;e++) o[e]=(a[e]+b[e])*0.5f;
  ((uint4*)hn)[i]=pk8(o);
}

// ---- global GINE aggregation per node
__global__ __launch_bounds__(128) void k_gagg(const u16* __restrict__ hn, const float* __restrict__ be,
                      const int* __restrict__ goff, const int* __restrict__ gcnt,
                      const int* __restrict__ gpack, const float* __restrict__ epsp, int layer,
                      u16* __restrict__ hhg){
  __shared__ float bes[16][128];
  int n=blockIdx.x, c=threadIdx.x;
  for(int i=0;i<16;i++) bes[i][c]=be[i*128+c];
  __syncthreads();
  float acc=0.f;
  int o=goff[n], e=o+gcnt[n];
  for(;o<e;o++){
    int p=gpack[o];
    acc+=fmaxf(b2f(hn[(size_t)(p>>4)*H+c])+bes[p&15][c],0.f);
  }
  hhg[(size_t)n*H+c]=f2b(fmaf(1.f+epsp[layer],b2f(hn[(size_t)n*H+c]),acc));
}

// ---- h_node' = h_node + BN_affine(a_g)
__global__ void k_bnadd(const u16* __restrict__ hn, const u16* __restrict__ ag,
                        const float* __restrict__ bnG, u16* __restrict__ hn2){
  int i=blockIdx.x*blockDim.x+threadIdx.x;
  if(i>=NN*H) return;
  int c=i&127;
  hn2[i]=f2b(b2f(hn[i])+fmaf(b2f(ag[i]),bnG[c],bnG[128+c]));
}

// ---- final pooling
__global__ __launch_bounds__(128) void k_pool(const u16* __restrict__ h, const int* __restrict__ valid,
                      const int* __restrict__ batch, float* __restrict__ oacc){
  __shared__ float cs[2];
  int n=blockIdx.x, c=threadIdx.x;
  if(c<2){
    int s=0;
    for(int j=0;j<32;j++) s+=valid[n*64+c*32+j];
    cs[c]=fmaxf((float)s,1.f);
  }
  __syncthreads();
  size_t base=(size_t)n*64*H;
  float a0=0.f,a1=0.f;
  for(int j=0;j<32;j++){
    a0+=b2f(h[base+(size_t)j*H+c]);
    a1+=b2f(h[base+(size_t)(32+j)*H+c]);
  }
  float nodef=0.5f*(a0/cs[0]+a1/cs[1]);
  atomicAdd(&oacc[batch[n]*H+c],nodef);
}

__global__ void k_out(const float* __restrict__ acc, const int* __restrict__ flag, void* __restrict__ out){
  int i=blockIdx.x*blockDim.x+threadIdx.x;
  if(i>=NGRAPH*H) return;
  if(*flag) ((__hip_bfloat16*)out)[i]=__float2bfloat16(acc[i]);
  else ((float*)out)[i]=acc[i];
}

extern "C" void kernel_launch(void* const* d_in, const int* in_sizes, int n_in,
                              void* d_out, int out_size, void* d_ws, size_t ws_size,
                              hipStream_t stream){
  (void)n_in; (void)out_size;
  int pofs[27]; pofs[0]=0;
  for(int i=0;i<26;i++) pofs[i+1]=pofs[i]+in_sizes[i];
  int ptot=pofs[26];

  char* wsb=(char*)d_ws;
  size_t off=0;
  auto alloc=[&](size_t bytes)->char*{ char* p=wsb+off; off+=(bytes+255)&~(size_t)255; return p; };
  int*   flag =(int*)  alloc(4);
  float* par  =(float*)alloc((size_t)ptot*4);
  u16*   h    =(u16*)  alloc((size_t)SKK*H*2);
  u16*   X    =(u16*)  alloc((size_t)SKK*H*2);
  u16*   wt   =(u16*)  alloc((size_t)28*HH*2);
  u16*   wt3  =(u16*)  alloc((size_t)HH*2);
  float* bias3=(float*)alloc(H*4);
  float* rf   =(float*)alloc((size_t)NN*H*4);
  u16*   bondb=(u16*)  alloc((size_t)16*H*2);
  u16*   hn   =(u16*)  alloc((size_t)NN*H*2);
  u16*   hhg  =(u16*)  alloc((size_t)NN*H*2);
  u16*   ag   =(u16*)  alloc((size_t)NN*H*2);
  u16*   hn2  =(u16*)  alloc((size_t)NN*H*2);
  u16*   bno  =(u16*)  alloc((size_t)NN*H*2);
  u16*   bb   =(u16*)  alloc((size_t)NN*H*2);
  float* stl  =(float*)alloc(256*4);
  float* stg  =(float*)alloc(256*4);
  float* bnl  =(float*)alloc(256*4);
  float* bnG  =(float*)alloc(256*4);
  float* oacc =(float*)alloc((size_t)NGRAPH*H*4);
  int* ecnt =(int*)alloc(SS*4);
  int* eoff =(int*)alloc(SS*4);
  int* ecur =(int*)alloc(SS*4);
  int* epack=(int*)alloc((size_t)EI*4);
  int* gcnt =(int*)alloc(NN*4);
  int* goff =(int*)alloc(NN*4);
  int* gcur =(int*)alloc(NN*4);
  int* gpack=(int*)alloc((size_t)EG*4);

  if(off>ws_size) return;

  const int* xids =(const int*)d_in[26];
  const int* iei  =(const int*)d_in[27];
  const int* iea  =(const int*)d_in[28];
  const int* gei  =(const int*)d_in[29];
  const int* gea  =(const int*)d_in[30];
  const int* nids =(const int*)d_in[31];
  const int* valid=(const int*)d_in[32];
  const int* batch=(const int*)d_in[33];

  const float* atom=par+pofs[0];
  const float* bond=par+pofs[1];
  const float* rw_w=par+pofs[2];
  const float* rw_b=par+pofs[3];
  const float* rwse=par+pofs[4];
  const float* leps=par+pofs[5];
  const float* lb1 =par+pofs[7];
  const float* lb2 =par+pofs[9];
  const float* lbng=par+pofs[10];
  const float* lbnb=par+pofs[11];
  const float* geps=par+pofs[12];
  const float* gb1 =par+pofs[14];
  const float* gb2 =par+pofs[16];
  const float* gbng=par+pofs[17];
  const float* gbnb=par+pofs[18];
  const float* cw1 =par+pofs[20];
  const float* cb1 =par+pofs[21];
  const float* cb2 =par+pofs[23];
  const float* lngp=par+pofs[24];
  const float* lnbp=par+pofs[25];

  k_sniff<<<1,256,0,stream>>>((const u16*)d_in[0], flag);
  CvtArgs ca;
  for(int i=0;i<26;i++){ ca.p[i]=d_in[i]; ca.start[i]=pofs[i]; }
  ca.start[26]=ptot;
  k_convert<<<1024,256,0,stream>>>(ca, flag, par);

  TransArgs ta;
  for(int l=0;l<LNUM;l++){
    ta.src[l*7+0]=pofs[6]+l*HH;           // lw1
    ta.src[l*7+1]=pofs[8]+l*HH;           // lw2
    ta.src[l*7+2]=pofs[13]+l*HH;          // gw1
    ta.src[l*7+3]=pofs[15]+l*HH;          // gw2
    ta.src[l*7+4]=pofs[19]+l*HH;          // bcw
    ta.src[l*7+5]=pofs[20]+l*2*HH+HH;     // cw1 bottom half
    ta.src[l*7+6]=pofs[22]+l*HH;          // cw2
  }
  k_trans<<<28,256,0,stream>>>(par, ta, wt);
  k_cvtbond<<<8,256,0,stream>>>(bond, bondb);

  (void)hipMemsetAsync(ecnt,0,SS*4,stream);
  (void)hipMemsetAsync(ecur,0,SS*4,stream);
  (void)hipMemsetAsync(gcnt,0,NN*4,stream);
  (void)hipMemsetAsync(gcur,0,NN*4,stream);
  (void)hipMemsetAsync(oacc,0,NGRAPH*H*4,stream);

  k_hist<<<2048,256,0,stream>>>(iei+EI, EI, 5, ecnt);
  k_scan<<<1,1024,0,stream>>>(ecnt, eoff, SS);
  k_scatter_i<<<2048,256,0,stream>>>(iei, iea, eoff, ecur, epack);
  k_hist<<<512,256,0,stream>>>(gei+EG, EG, 0, gcnt);
  k_scan<<<1,1024,0,stream>>>(gcnt, goff, NN);
  k_scatter_g<<<512,256,0,stream>>>(gei, gea, goff, gcur, gpack);

  k_rwse<<<NN,128,0,stream>>>(rwse, rw_w, rw_b, rf);
  k_h0<<<(SKK*16)/256,256,0,stream>>>(atom, rf, xids, nids, valid, h);

  for(int l=0;l<LNUM;l++){
    (void)hipMemsetAsync(stl,0,256*4,stream);
    (void)hipMemsetAsync(stg,0,256*4,stream);
    k_local_agg<<<SS,256,0,stream>>>(h, bondb, eoff, ecnt, epack, leps, l, X);
    k_mlp2<1><<<SKK/128,256,0,stream>>>(X, wt+(size_t)(l*7+0)*HH, lb1+l*H,
        wt+(size_t)(l*7+1)*HH, lb2+l*H, X, stl);
    k_npool<<<(NN*16)/256,256,0,stream>>>(h, hn);
    k_gagg<<<NN,128,0,stream>>>(hn, bond, goff, gcnt, gpack, geps, l, hhg);
    k_mlp2<1><<<NN/128,256,0,stream>>>(hhg, wt+(size_t)(l*7+2)*HH, gb1+l*H,
        wt+(size_t)(l*7+3)*HH, gb2+l*H, ag, stg);
    k_bnfin<<<1,128,0,stream>>>(stl, stg, lbng+l*H, lbnb+l*H, gbng+l*H, gbnb+l*H, bnl, bnG);
    k_bnadd<<<(NN*H+255)/256,256,0,stream>>>(hn, ag, bnG, hn2);
    k_mgemm<0><<<NN/128,256,0,stream>>>(hn2, wt+(size_t)(l*7+4)*HH, nullptr, bno,
        nullptr,nullptr,nullptr,nullptr,nullptr,nullptr);
    k_mgemm<0><<<NN/128,256,0,stream>>>(bno, wt+(size_t)(l*7+5)*HH, nullptr, bb,
        nullptr,nullptr,nullptr,nullptr,nullptr,nullptr);
    k_prepw3<<<128,128,0,stream>>>(cw1+(size_t)l*2*HH, cb1+l*H, bnl, wt3, bias3);
    k_mgemm<3><<<SKK/128,256,0,stream>>>(X, wt3, bias3, X,
        bb,nullptr,nullptr,nullptr,nullptr,nullptr);
    k_mgemm<4><<<SKK/128,256,0,stream>>>(X, wt+(size_t)(l*7+6)*HH, cb2+l*H, h,
        nullptr,nullptr, h, valid, lngp+l*H, lnbp+l*H);
  }
  k_pool<<<NN,128,0,stream>>>(h, valid, batch, oacc);
  k_out<<<(NGRAPH*H+255)/256,256,0,stream>>>(oacc, flag, d_out);
}

// Round 6
// 1962.485 us; speedup vs baseline: 2.2093x; 2.2093x over previous
//
#include <hip/hip_runtime.h>
#include <hip/hip_bf16.h>

#define H 128
#define HH 16384
#define LNUM 4
#define NN 4096
#define SS 8192
#define SKK 262144
#define EI 1048576
#define EG 65536
#define NGRAPH 64

typedef unsigned short u16;
typedef unsigned int u32;
typedef __attribute__((ext_vector_type(8))) short s16x8;
typedef __attribute__((ext_vector_type(4))) float f32x4;

__device__ __forceinline__ float b2f(u32 u){ return __uint_as_float(u<<16); }
__device__ __forceinline__ u16 f2b(float f){
  union { __hip_bfloat16 b; u16 u; } x;
  x.b=__float2bfloat16(f);
  return x.u;
}
__device__ __forceinline__ void unp8(uint4 v, float* f){
  f[0]=b2f(v.x&0xFFFF); f[1]=b2f(v.x>>16);
  f[2]=b2f(v.y&0xFFFF); f[3]=b2f(v.y>>16);
  f[4]=b2f(v.z&0xFFFF); f[5]=b2f(v.z>>16);
  f[6]=b2f(v.w&0xFFFF); f[7]=b2f(v.w>>16);
}
__device__ __forceinline__ void unp4(uint2 v, float* f){
  f[0]=b2f(v.x&0xFFFF); f[1]=b2f(v.x>>16);
  f[2]=b2f(v.y&0xFFFF); f[3]=b2f(v.y>>16);
}
__device__ __forceinline__ uint4 pk8(const float* f){
  uint4 r;
  r.x=(u32)f2b(f[0])|((u32)f2b(f[1])<<16);
  r.y=(u32)f2b(f[2])|((u32)f2b(f[3])<<16);
  r.z=(u32)f2b(f[4])|((u32)f2b(f[5])<<16);
  r.w=(u32)f2b(f[6])|((u32)f2b(f[7])<<16);
  return r;
}
__device__ __forceinline__ uint2 pk4(const float* f){
  uint2 r;
  r.x=(u32)f2b(f[0])|((u32)f2b(f[1])<<16);
  r.y=(u32)f2b(f[2])|((u32)f2b(f[3])<<16);
  return r;
}

struct CvtArgs {
  const void* p[26];
  int start[27];
};
struct TransArgs { int src[28]; };

// ---- dtype sniff
__global__ void k_sniff(const u16* __restrict__ a, int* __restrict__ flag){
  __shared__ int cnt;
  if(threadIdx.x==0) cnt=0;
  __syncthreads();
  int big=0;
  for(int i=threadIdx.x;i<2048;i+=256){
    int e=(a[i]>>7)&0xFF;
    if(e>=127) big++;
  }
  atomicAdd(&cnt,big);
  __syncthreads();
  if(threadIdx.x==0) *flag=(cnt<16)?1:0;
}

__global__ void k_convert(CvtArgs args, const int* __restrict__ flag, float* __restrict__ dst){
  int fl=*flag;
  int total=args.start[26];
  for(int i=blockIdx.x*blockDim.x+threadIdx.x;i<total;i+=gridDim.x*blockDim.x){
    int a=0;
    while(args.start[a+1]<=i) a++;
    int j=i-args.start[a];
    float v;
    if(fl) v=b2f(((const u16*)args.p[a])[j]);
    else   v=((const float*)args.p[a])[j];
    dst[i]=v;
  }
}

// ---- static weights: f32 [K][N] -> bf16 W^T [N][K]
__global__ __launch_bounds__(256) void k_trans(const float* __restrict__ par, TransArgs ta, u16* __restrict__ wt){
  const float* s=par+ta.src[blockIdx.x];
  u16* d=wt+(size_t)blockIdx.x*HH;
  for(int i=threadIdx.x;i<HH;i+=256){
    int n=i>>7, k=i&127;
    d[i]=f2b(s[(size_t)k*H+n]);
  }
}

// ---- bond emb f32 -> bf16
__global__ void k_cvtbond(const float* __restrict__ b, u16* __restrict__ bb){
  int i=blockIdx.x*blockDim.x+threadIdx.x;
  if(i<16*H) bb[i]=f2b(b[i]);
}

// ---- fold BN affine into cw1_top
__global__ __launch_bounds__(128) void k_prepw3(const float* __restrict__ w, const float* __restrict__ cb1,
                        const float* __restrict__ bnl, u16* __restrict__ wt3, float* __restrict__ bias3){
  __shared__ float red[128];
  int c=blockIdx.x, k=threadIdx.x;
  float wv=w[(size_t)k*H+c];
  wt3[(size_t)c*H+k]=f2b(bnl[k]*wv);
  red[k]=bnl[128+k]*wv;
  __syncthreads();
  for(int d=64;d>0;d>>=1){ if(k<d) red[k]+=red[k+d]; __syncthreads(); }
  if(k==0) bias3[c]=cb1[c]+red[0];
}

// ---- edge bucketing
__global__ void k_hist(const int* __restrict__ idx, int n, int shift, int* __restrict__ cnt){
  for(int i=blockIdx.x*blockDim.x+threadIdx.x;i<n;i+=gridDim.x*blockDim.x)
    atomicAdd(&cnt[idx[i]>>shift],1);
}

__global__ void k_scan(const int* __restrict__ cnt, int* __restrict__ off, int nbins){
  __shared__ int ts[1024];
  int t=threadIdx.x;
  int per=nbins>>10;
  int base=t*per;
  int s=0;
  for(int j=0;j<per;j++) s+=cnt[base+j];
  ts[t]=s;
  __syncthreads();
  for(int d=1;d<1024;d<<=1){
    int v=(t>=d)?ts[t-d]:0;
    __syncthreads();
    ts[t]+=v;
    __syncthreads();
  }
  int ex=(t==0)?0:ts[t-1];
  for(int j=0;j<per;j++){ off[base+j]=ex; ex+=cnt[base+j]; }
}

__global__ void k_scatter_i(const int* __restrict__ ei, const int* __restrict__ ea,
                            const int* __restrict__ off, int* __restrict__ cur, int* __restrict__ pack){
  for(int i=blockIdx.x*blockDim.x+threadIdx.x;i<EI;i+=gridDim.x*blockDim.x){
    int s=ei[i], d=ei[EI+i];
    int sub=d>>5;
    int pos=off[sub]+atomicAdd(&cur[sub],1);
    pack[pos]=((s&31)<<9)|((d&31)<<4)|(ea[i]&15);
  }
}

// ---- sort each subgraph's edges by dst-lane (in-LDS counting sort)
__global__ __launch_bounds__(128) void k_sortsub(const int* __restrict__ eoff, const int* __restrict__ ecnt,
                                                 int* __restrict__ epack){
  __shared__ int ein[512];
  __shared__ int eout[512];
  __shared__ int bcnt[32];
  __shared__ int bpos[32];
  int sub=blockIdx.x, t=threadIdx.x;
  int o=eoff[sub];
  int n=ecnt[sub]; if(n>512) n=512;
  for(int i=t;i<n;i+=128) ein[i]=epack[o+i];
  if(t<32) bcnt[t]=0;
  __syncthreads();
  for(int i=t;i<n;i+=128) atomicAdd(&bcnt[(ein[i]>>4)&31],1);
  __syncthreads();
  if(t==0){
    int s=0;
    for(int b=0;b<32;b++){ bpos[b]=s; s+=bcnt[b]; }
  }
  __syncthreads();
  for(int i=t;i<n;i+=128){
    int p=ein[i];
    int pos=atomicAdd(&bpos[(p>>4)&31],1);
    eout[pos]=p;
  }
  __syncthreads();
  for(int i=t;i<n;i+=128) epack[o+i]=eout[i];
}

__global__ void k_scatter_g(const int* __restrict__ ei, const int* __restrict__ ea,
                            const int* __restrict__ off, int* __restrict__ cur, int* __restrict__ pack){
  for(int i=blockIdx.x*blockDim.x+threadIdx.x;i<EG;i+=gridDim.x*blockDim.x){
    int s=ei[i], d=ei[EG+i];
    int pos=off[d]+atomicAdd(&cur[d],1);
    pack[pos]=(s<<4)|(ea[i]&15);
  }
}

// ---- rf = relu(rwse @ rwse_w + rwse_b)
__global__ __launch_bounds__(128) void k_rwse(const float* __restrict__ rwse, const float* __restrict__ w,
                      const float* __restrict__ b, float* __restrict__ rf){
  __shared__ float ws[16*128];
  __shared__ float rv[16];
  int n=blockIdx.x, c=threadIdx.x;
  for(int i=c;i<2048;i+=128) ws[i]=w[i];
  if(c<16) rv[c]=rwse[n*16+c];
  __syncthreads();
  float acc=b[c];
  for(int j=0;j<16;j++) acc=fmaf(rv[j],ws[j*128+c],acc);
  rf[(size_t)n*H+c]=fmaxf(acc,0.f);
}

// ---- h0
__global__ void k_h0(const float* __restrict__ atom, const float* __restrict__ rf,
                     const int* __restrict__ xids, const int* __restrict__ nids,
                     const int* __restrict__ valid, u16* __restrict__ h){
  int i=blockIdx.x*blockDim.x+threadIdx.x;
  if(i>=SKK*16) return;
  int r=i>>4, q=i&15;
  const float4* ap=(const float4*)(atom+(size_t)xids[r]*H)+q*2;
  const float4* bp=(const float4*)(rf+(size_t)nids[r]*H)+q*2;
  float4 a0=ap[0],a1=ap[1],b0=bp[0],b1=bp[1];
  float vm=valid[r]?1.f:0.f;
  float f[8]={(a0.x+b0.x)*vm,(a0.y+b0.y)*vm,(a0.z+b0.z)*vm,(a0.w+b0.w)*vm,
              (a1.x+b1.x)*vm,(a1.y+b1.y)*vm,(a1.z+b1.z)*vm,(a1.w+b1.w)*vm};
  ((uint4*)h)[i]=pk8(f);
}

// ---- local GINE aggregation: thread=channel, register acc over dst-sorted edges
__global__ __launch_bounds__(128) void k_local_agg(const u16* __restrict__ h, const u16* __restrict__ beb,
                           const int* __restrict__ eoff, const int* __restrict__ ecnt,
                           const int* __restrict__ epack, const float* __restrict__ epsp, int layer,
                           u16* __restrict__ hh){
  __shared__ u16 hs[32*128];     // 8KB
  __shared__ u16 bes[16*128];    // 4KB
  __shared__ float ag[32*128];   // 16KB
  __shared__ int epk[128];
  int sub=blockIdx.x, c=threadIdx.x;
  size_t base=(size_t)sub*32*H;
  {
    const uint4* src=(const uint4*)(h+base);
    uint4* dst=(uint4*)hs;
    for(int i=c;i<512;i+=128) dst[i]=src[i];
    const uint4* bsrc=(const uint4*)beb;
    uint4* bdst=(uint4*)bes;
    for(int i=c;i<256;i+=128) bdst[i]=bsrc[i];
    float4* az=(float4*)ag;
    for(int i=c;i<1024;i+=128) az[i]=make_float4(0,0,0,0);
  }
  int o=eoff[sub], n=ecnt[sub];
  float acc=0.f;
  int cur=-1;
  for(int b0=0;b0<n;b0+=128){
    __syncthreads();
    if(b0+c<n) epk[c]=epack[o+b0+c];
    __syncthreads();
    int lim=n-b0; if(lim>128) lim=128;
    #pragma unroll 4
    for(int i=0;i<lim;i++){
      int p=epk[i];
      int dl=(p>>4)&31;
      if(dl!=cur){
        if(cur>=0) ag[cur*128+c]=acc;
        acc=0.f; cur=dl;
      }
      acc+=fmaxf(b2f(hs[(p>>9)*128+c])+b2f(bes[(p&15)*128+c]),0.f);
    }
  }
  if(cur>=0) ag[cur*128+c]=acc;
  __syncthreads();   // epilogue reads other threads' columns of ag
  float ep=1.f+epsp[layer];
  for(int idx=c;idx<512;idx+=128){
    int r=idx>>4, ch=(idx&15)*8;
    float hv[8],o8[8];
    unp8(*(const uint4*)(hs+r*128+ch),hv);
    const float* ar=ag+r*128+ch;
    #pragma unroll
    for(int j=0;j<8;j++) o8[j]=fmaf(ep,hv[j],ar[j]);
    ((uint4*)(hh+base))[idx]=pk8(o8);
  }
}

// ==== MFMA GEMM (swapped operands: D[outcol][xrow])
// MODE 0: out=A@W   MODE 1: relu(A@W+b)   MODE 2: relu+col stats
// MODE 3: gelu(A@W+b+rowbias[node])       MODE 4: LN(A@W+b); out=(res+v)*valid
// MODES 3/4: LDS-staged coalesced stores
template<int MODE>
__global__ __launch_bounds__(256) void k_mgemm(
    const u16* __restrict__ A, const u16* __restrict__ Wt,
    const float* __restrict__ bias, u16* __restrict__ out,
    const u16* __restrict__ rowbias,
    float* __restrict__ stats,
    const u16* __restrict__ res, const int* __restrict__ validv,
    const float* __restrict__ lng, const float* __restrict__ lnb)
{
  __shared__ float sst[256];
  __shared__ u16 Tst[(MODE>=3)?(128*128):64];
  int t=threadIdx.x;
  if(MODE==2){ if(t<256) sst[t]=0.f; __syncthreads(); }
  int wave=t>>6, lane=t&63;
  int lr=lane&15, lk=lane>>4;
  int rowW=blockIdx.x*128+wave*32;

  f32x4 acc[2][8];
  #pragma unroll
  for(int m=0;m<2;m++)
    #pragma unroll
    for(int n=0;n<8;n++) acc[m][n]=(f32x4){0.f,0.f,0.f,0.f};

  const s16x8* B0=(const s16x8*)(A+(size_t)(rowW+lr)*H);
  const s16x8* B1=(const s16x8*)(A+(size_t)(rowW+16+lr)*H);

  #pragma unroll
  for(int kc=0;kc<4;kc++){
    s16x8 bf0=B0[kc*4+lk];
    s16x8 bf1=B1[kc*4+lk];
    #pragma unroll
    for(int n=0;n<8;n++){
      s16x8 af=*(const s16x8*)(Wt+(size_t)(n*16+lr)*H+kc*32+lk*8);
      acc[0][n]=__builtin_amdgcn_mfma_f32_16x16x32_bf16(af,bf0,acc[0][n],0,0,0);
      acc[1][n]=__builtin_amdgcn_mfma_f32_16x16x32_bf16(af,bf1,acc[1][n],0,0,0);
    }
  }

  if(MODE==4){
    #pragma unroll
    for(int m=0;m<2;m++){
      int row=rowW+m*16+lr;
      int rl=wave*32+m*16+lr;
      float s=0.f,q=0.f;
      #pragma unroll
      for(int n=0;n<8;n++){
        int c0=n*16+lk*4;
        float4 b4=*(const float4*)(bias+c0);
        float vb[4]={b4.x,b4.y,b4.z,b4.w};
        #pragma unroll
        for(int j=0;j<4;j++){
          float v=acc[m][n][j]+vb[j];
          acc[m][n][j]=v;
          s+=v; q+=v*v;
        }
      }
      s+=__shfl_xor(s,16); s+=__shfl_xor(s,32);
      q+=__shfl_xor(q,16); q+=__shfl_xor(q,32);
      float mu=s*(1.f/128.f);
      float rsig=rsqrtf(q*(1.f/128.f)-mu*mu+1e-5f);
      float vm=validv[row]?1.f:0.f;
      #pragma unroll
      for(int n=0;n<8;n++){
        int c0=n*16+lk*4;
        float4 g4=*(const float4*)(lng+c0);
        float4 e4=*(const float4*)(lnb+c0);
        float g[4]={g4.x,g4.y,g4.z,g4.w}, e[4]={e4.x,e4.y,e4.z,e4.w};
        float r4[4];
        unp4(*(const uint2*)(res+(size_t)row*H+c0),r4);
        float ov[4];
        #pragma unroll
        for(int j=0;j<4;j++)
          ov[j]=(r4[j]+(acc[m][n][j]-mu)*rsig*g[j]+e[j])*vm;
        u32 offb=(u32)rl*256+(((u32)(c0*2))^((u32)(rl&7)<<4));
        *(uint2*)((char*)Tst+offb)=pk4(ov);
      }
    }
  } else if(MODE==3){
    int nb=rowW>>6;
    #pragma unroll
    for(int n=0;n<8;n++){
      int c0=n*16+lk*4;
      float4 b4=*(const float4*)(bias+c0);
      float vb[4]={b4.x,b4.y,b4.z,b4.w};
      float rb[4];
      unp4(*(const uint2*)(rowbias+(size_t)nb*H+c0),rb);
      float v0[4],v1[4];
      #pragma unroll
      for(int j=0;j<4;j++){
        float x0=acc[0][n][j]+vb[j]+rb[j];
        float x1=acc[1][n][j]+vb[j]+rb[j];
        v0[j]=0.5f*x0*(1.f+erff(x0*0.70710678118654752f));
        v1[j]=0.5f*x1*(1.f+erff(x1*0.70710678118654752f));
      }
      int rl0=wave*32+lr, rl1=rl0+16;
      u32 o0=(u32)rl0*256+(((u32)(c0*2))^((u32)(rl0&7)<<4));
      u32 o1=(u32)rl1*256+(((u32)(c0*2))^((u32)(rl1&7)<<4));
      *(uint2*)((char*)Tst+o0)=pk4(v0);
      *(uint2*)((char*)Tst+o1)=pk4(v1);
    }
  } else {
    int row0=rowW+lr, row1=rowW+16+lr;
    #pragma unroll
    for(int n=0;n<8;n++){
      int c0=n*16+lk*4;
      float vb[4]={0.f,0.f,0.f,0.f};
      if(bias){
        float4 b4=*(const float4*)(bias+c0);
        vb[0]=b4.x; vb[1]=b4.y; vb[2]=b4.z; vb[3]=b4.w;
      }
      float v0[4],v1[4];
      #pragma unroll
      for(int j=0;j<4;j++){ v0[j]=acc[0][n][j]+vb[j]; v1[j]=acc[1][n][j]+vb[j]; }
      if(MODE==1||MODE==2){
        #pragma unroll
        for(int j=0;j<4;j++){ v0[j]=fmaxf(v0[j],0.f); v1[j]=fmaxf(v1[j],0.f); }
      }
      *(uint2*)(out+(size_t)row0*H+c0)=pk4(v0);
      *(uint2*)(out+(size_t)row1*H+c0)=pk4(v1);
      if(MODE==2){
        float s[4],q[4];
        #pragma unroll
        for(int j=0;j<4;j++){
          s[j]=v0[j]+v1[j];
          q[j]=v0[j]*v0[j]+v1[j]*v1[j];
        }
        #pragma unroll
        for(int j=0;j<4;j++){
          #pragma unroll
          for(int d=1;d<16;d<<=1){
            s[j]+=__shfl_xor(s[j],d);
            q[j]+=__shfl_xor(q[j],d);
          }
        }
        if(lr==0){
          #pragma unroll
          for(int j=0;j<4;j++){
            atomicAdd(&sst[c0+j],s[j]);
            atomicAdd(&sst[128+c0+j],q[j]);
          }
        }
      }
    }
  }
  if(MODE>=3){
    __syncthreads();
    #pragma unroll
    for(int p=0;p<8;p++){
      u32 flat=(u32)p*4096+(u32)t*16;
      u32 row=flat>>8, colb=flat&255;
      uint4 v=*(const uint4*)((const char*)Tst+row*256+(colb^((row&7)<<4)));
      *(uint4*)(out+(size_t)(blockIdx.x*128+row)*H+(colb>>1))=v;
    }
  }
  if(MODE==2){
    __syncthreads();
    if(t<256) atomicAdd(&stats[t],sst[t]);
  }
}

// ==== fused MLP: out = relu( relu(A@W1+b1) @ W2 + b2 ), optional col stats
template<int STATS>
__global__ __launch_bounds__(256) void k_mlp2(
    const u16* __restrict__ A, const u16* __restrict__ W1t, const float* __restrict__ b1,
    const u16* __restrict__ W2t, const float* __restrict__ b2,
    u16* __restrict__ out, float* __restrict__ stats)
{
  __shared__ u16 T[128*128];
  __shared__ float sst[256];
  int t=threadIdx.x;
  if(STATS){ if(t<256) sst[t]=0.f; __syncthreads(); }
  int wave=t>>6, lane=t&63;
  int lr=lane&15, lk=lane>>4;
  int rowW=blockIdx.x*128+wave*32;

  f32x4 acc[2][8];
  #pragma unroll
  for(int m=0;m<2;m++)
    #pragma unroll
    for(int n=0;n<8;n++) acc[m][n]=(f32x4){0.f,0.f,0.f,0.f};

  const s16x8* B0=(const s16x8*)(A+(size_t)(rowW+lr)*H);
  const s16x8* B1=(const s16x8*)(A+(size_t)(rowW+16+lr)*H);
  #pragma unroll
  for(int kc=0;kc<4;kc++){
    s16x8 bf0=B0[kc*4+lk];
    s16x8 bf1=B1[kc*4+lk];
    #pragma unroll
    for(int n=0;n<8;n++){
      s16x8 af=*(const s16x8*)(W1t+(size_t)(n*16+lr)*H+kc*32+lk*8);
      acc[0][n]=__builtin_amdgcn_mfma_f32_16x16x32_bf16(af,bf0,acc[0][n],0,0,0);
      acc[1][n]=__builtin_amdgcn_mfma_f32_16x16x32_bf16(af,bf1,acc[1][n],0,0,0);
    }
  }
  // relu(.+b1) -> swizzled LDS (wave-local rows)
  #pragma unroll
  for(int m=0;m<2;m++){
    int rl=wave*32+m*16+lr;
    u32 rb=(u32)rl*256;
    #pragma unroll
    for(int n=0;n<8;n++){
      int c0=n*16+lk*4;
      float4 b4=*(const float4*)(b1+c0);
      float vb[4]={b4.x,b4.y,b4.z,b4.w};
      float v[4];
      #pragma unroll
      for(int j=0;j<4;j++) v[j]=fmaxf(acc[m][n][j]+vb[j],0.f);
      u32 off=rb+(((u32)(c0*2))^((u32)(rl&7)<<4));
      *(uint2*)((char*)T+off)=pk4(v);
    }
  }
  // phase 2
  #pragma unroll
  for(int m=0;m<2;m++)
    #pragma unroll
    for(int n=0;n<8;n++) acc[m][n]=(f32x4){0.f,0.f,0.f,0.f};
  int rl0=wave*32+lr, rl1=rl0+16;
  #pragma unroll
  for(int kc=0;kc<4;kc++){
    u32 cbyte=(u32)((kc*32+lk*8)*2);
    u32 o0=(u32)rl0*256+(cbyte^((u32)(rl0&7)<<4));
    u32 o1=(u32)rl1*256+(cbyte^((u32)(rl1&7)<<4));
    s16x8 bf0=*(const s16x8*)((char*)T+o0);
    s16x8 bf1=*(const s16x8*)((char*)T+o1);
    #pragma unroll
    for(int n=0;n<8;n++){
      s16x8 af=*(const s16x8*)(W2t+(size_t)(n*16+lr)*H+kc*32+lk*8);
      acc[0][n]=__builtin_amdgcn_mfma_f32_16x16x32_bf16(af,bf0,acc[0][n],0,0,0);
      acc[1][n]=__builtin_amdgcn_mfma_f32_16x16x32_bf16(af,bf1,acc[1][n],0,0,0);
    }
  }
  // epilogue -> stage into own rows of T (after own phase-2 reads), then coalesced flush
  #pragma unroll
  for(int n=0;n<8;n++){
    int c0=n*16+lk*4;
    float4 b4=*(const float4*)(b2+c0);
    float vb[4]={b4.x,b4.y,b4.z,b4.w};
    float v0[4],v1[4];
    #pragma unroll
    for(int j=0;j<4;j++){
      v0[j]=fmaxf(acc[0][n][j]+vb[j],0.f);
      v1[j]=fmaxf(acc[1][n][j]+vb[j],0.f);
    }
    u32 o0=(u32)rl0*256+(((u32)(c0*2))^((u32)(rl0&7)<<4));
    u32 o1=(u32)rl1*256+(((u32)(c0*2))^((u32)(rl1&7)<<4));
    *(uint2*)((char*)T+o0)=pk4(v0);
    *(uint2*)((char*)T+o1)=pk4(v1);
    if(STATS){
      float s[4],q[4];
      #pragma unroll
      for(int j=0;j<4;j++){
        s[j]=v0[j]+v1[j];
        q[j]=v0[j]*v0[j]+v1[j]*v1[j];
      }
      #pragma unroll
      for(int j=0;j<4;j++){
        #pragma unroll
        for(int d=1;d<16;d<<=1){
          s[j]+=__shfl_xor(s[j],d);
          q[j]+=__shfl_xor(q[j],d);
        }
      }
      if(lr==0){
        #pragma unroll
        for(int j=0;j<4;j++){
          atomicAdd(&sst[c0+j],s[j]);
          atomicAdd(&sst[128+c0+j],q[j]);
        }
      }
    }
  }
  __syncthreads();
  #pragma unroll
  for(int p=0;p<8;p++){
    u32 flat=(u32)p*4096+(u32)t*16;
    u32 row=flat>>8, colb=flat&255;
    uint4 v=*(const uint4*)((const char*)T+row*256+(colb^((row&7)<<4)));
    *(uint4*)(out+(size_t)(blockIdx.x*128+row)*H+(colb>>1))=v;
  }
  if(STATS){
    if(t<256) atomicAdd(&stats[t],sst[t]);
  }
}

// ---- BN stats -> per-column affine
__global__ void k_bnfin(const float* __restrict__ stl, const float* __restrict__ stg,
                        const float* __restrict__ gl, const float* __restrict__ bl,
                        const float* __restrict__ gg, const float* __restrict__ bg,
                        float* __restrict__ bnl, float* __restrict__ bnG){
  int c=threadIdx.x;
  {
    float mu=stl[c]*(1.f/262144.f);
    float var=stl[128+c]*(1.f/262144.f)-mu*mu;
    float s=gl[c]*rsqrtf(var+1e-5f);
    bnl[c]=s; bnl[128+c]=bl[c]-mu*s;
  }
  {
    float mu=stg[c]*(1.f/4096.f);
    float var=stg[128+c]*(1.f/4096.f)-mu*mu;
    float s=gg[c]*rsqrtf(var+1e-5f);
    bnG[c]=s; bnG[128+c]=bg[c]-mu*s;
  }
}

// ---- h_node = mean of two root rows
__global__ void k_npool(const u16* __restrict__ h, u16* __restrict__ hn){
  int i=blockIdx.x*blockDim.x+threadIdx.x;
  if(i>=NN*16) return;
  int n=i>>4, q=i&15;
  const uint4* hp=(const uint4*)h;
  float a[8],b[8],o[8];
  unp8(hp[(size_t)n*1024+q],a);
  unp8(hp[(size_t)n*1024+512+q],b);
  #pragma unroll
  for(int e=0;e<8;e++) o[e]=(a[e]+b[e])*0.5f;
  ((uint4*)hn)[i]=pk8(o);
}

// ---- global GINE aggregation per node
__global__ __launch_bounds__(128) void k_gagg(const u16* __restrict__ hn, const float* __restrict__ be,
                      const int* __restrict__ goff, const int* __restrict__ gcnt,
                      const int* __restrict__ gpack, const float* __restrict__ epsp, int layer,
                      u16* __restrict__ hhg){
  __shared__ float bes[16][128];
  int n=blockIdx.x, c=threadIdx.x;
  for(int i=0;i<16;i++) bes[i][c]=be[i*128+c];
  __syncthreads();
  float acc=0.f;
  int o=goff[n], e=o+gcnt[n];
  for(;o<e;o++){
    int p=gpack[o];
    acc+=fmaxf(b2f(hn[(size_t)(p>>4)*H+c])+bes[p&15][c],0.f);
  }
  hhg[(size_t)n*H+c]=f2b(fmaf(1.f+epsp[layer],b2f(hn[(size_t)n*H+c]),acc));
}

// ---- h_node' = h_node + BN_affine(a_g)
__global__ void k_bnadd(const u16* __restrict__ hn, const u16* __restrict__ ag,
                        const float* __restrict__ bnG, u16* __restrict__ hn2){
  int i=blockIdx.x*blockDim.x+threadIdx.x;
  if(i>=NN*H) return;
  int c=i&127;
  hn2[i]=f2b(b2f(hn[i])+fmaf(b2f(ag[i]),bnG[c],bnG[128+c]));
}

// ---- final pooling
__global__ __launch_bounds__(128) void k_pool(const u16* __restrict__ h, const int* __restrict__ valid,
                      const int* __restrict__ batch, float* __restrict__ oacc){
  __shared__ float cs[2];
  int n=blockIdx.x, c=threadIdx.x;
  if(c<2){
    int s=0;
    for(int j=0;j<32;j++) s+=valid[n*64+c*32+j];
    cs[c]=fmaxf((float)s,1.f);
  }
  __syncthreads();
  size_t base=(size_t)n*64*H;
  float a0=0.f,a1=0.f;
  for(int j=0;j<32;j++){
    a0+=b2f(h[base+(size_t)j*H+c]);
    a1+=b2f(h[base+(size_t)(32+j)*H+c]);
  }
  float nodef=0.5f*(a0/cs[0]+a1/cs[1]);
  atomicAdd(&oacc[batch[n]*H+c],nodef);
}

__global__ void k_out(const float* __restrict__ acc, const int* __restrict__ flag, void* __restrict__ out){
  int i=blockIdx.x*blockDim.x+threadIdx.x;
  if(i>=NGRAPH*H) return;
  if(*flag) ((__hip_bfloat16*)out)[i]=__float2bfloat16(acc[i]);
  else ((float*)out)[i]=acc[i];
}

extern "C" void kernel_launch(void* const* d_in, const int* in_sizes, int n_in,
                              void* d_out, int out_size, void* d_ws, size_t ws_size,
                              hipStream_t stream){
  (void)n_in; (void)out_size;
  int pofs[27]; pofs[0]=0;
  for(int i=0;i<26;i++) pofs[i+1]=pofs[i]+in_sizes[i];
  int ptot=pofs[26];

  char* wsb=(char*)d_ws;
  size_t off=0;
  auto alloc=[&](size_t bytes)->char*{ char* p=wsb+off; off+=(bytes+255)&~(size_t)255; return p; };
  int*   flag =(int*)  alloc(4);
  float* par  =(float*)alloc((size_t)ptot*4);
  u16*   h    =(u16*)  alloc((size_t)SKK*H*2);
  u16*   X    =(u16*)  alloc((size_t)SKK*H*2);
  u16*   wt   =(u16*)  alloc((size_t)28*HH*2);
  u16*   wt3  =(u16*)  alloc((size_t)HH*2);
  float* bias3=(float*)alloc(H*4);
  float* rf   =(float*)alloc((size_t)NN*H*4);
  u16*   bondb=(u16*)  alloc((size_t)16*H*2);
  u16*   hn   =(u16*)  alloc((size_t)NN*H*2);
  u16*   hhg  =(u16*)  alloc((size_t)NN*H*2);
  u16*   ag   =(u16*)  alloc((size_t)NN*H*2);
  u16*   hn2  =(u16*)  alloc((size_t)NN*H*2);
  u16*   bno  =(u16*)  alloc((size_t)NN*H*2);
  u16*   bb   =(u16*)  alloc((size_t)NN*H*2);
  float* stl  =(float*)alloc(256*4);
  float* stg  =(float*)alloc(256*4);
  float* bnl  =(float*)alloc(256*4);
  float* bnG  =(float*)alloc(256*4);
  float* oacc =(float*)alloc((size_t)NGRAPH*H*4);
  int* ecnt =(int*)alloc(SS*4);
  int* eoff =(int*)alloc(SS*4);
  int* ecur =(int*)alloc(SS*4);
  int* epack=(int*)alloc((size_t)EI*4);
  int* gcnt =(int*)alloc(NN*4);
  int* goff =(int*)alloc(NN*4);
  int* gcur =(int*)alloc(NN*4);
  int* gpack=(int*)alloc((size_t)EG*4);

  if(off>ws_size) return;

  const int* xids =(const int*)d_in[26];
  const int* iei  =(const int*)d_in[27];
  const int* iea  =(const int*)d_in[28];
  const int* gei  =(const int*)d_in[29];
  const int* gea  =(const int*)d_in[30];
  const int* nids =(const int*)d_in[31];
  const int* valid=(const int*)d_in[32];
  const int* batch=(const int*)d_in[33];

  const float* atom=par+pofs[0];
  const float* bond=par+pofs[1];
  const float* rw_w=par+pofs[2];
  const float* rw_b=par+pofs[3];
  const float* rwse=par+pofs[4];
  const float* leps=par+pofs[5];
  const float* lb1 =par+pofs[7];
  const float* lb2 =par+pofs[9];
  const float* lbng=par+pofs[10];
  const float* lbnb=par+pofs[11];
  const float* geps=par+pofs[12];
  const float* gb1 =par+pofs[14];
  const float* gb2 =par+pofs[16];
  const float* gbng=par+pofs[17];
  const float* gbnb=par+pofs[18];
  const float* cw1 =par+pofs[20];
  const float* cb1 =par+pofs[21];
  const float* cb2 =par+pofs[23];
  const float* lngp=par+pofs[24];
  const float* lnbp=par+pofs[25];

  k_sniff<<<1,256,0,stream>>>((const u16*)d_in[0], flag);
  CvtArgs ca;
  for(int i=0;i<26;i++){ ca.p[i]=d_in[i]; ca.start[i]=pofs[i]; }
  ca.start[26]=ptot;
  k_convert<<<1024,256,0,stream>>>(ca, flag, par);

  TransArgs ta;
  for(int l=0;l<LNUM;l++){
    ta.src[l*7+0]=pofs[6]+l*HH;           // lw1
    ta.src[l*7+1]=pofs[8]+l*HH;           // lw2
    ta.src[l*7+2]=pofs[13]+l*HH;          // gw1
    ta.src[l*7+3]=pofs[15]+l*HH;          // gw2
    ta.src[l*7+4]=pofs[19]+l*HH;          // bcw
    ta.src[l*7+5]=pofs[20]+l*2*HH+HH;     // cw1 bottom half
    ta.src[l*7+6]=pofs[22]+l*HH;          // cw2
  }
  k_trans<<<28,256,0,stream>>>(par, ta, wt);
  k_cvtbond<<<8,256,0,stream>>>(bond, bondb);

  (void)hipMemsetAsync(ecnt,0,SS*4,stream);
  (void)hipMemsetAsync(ecur,0,SS*4,stream);
  (void)hipMemsetAsync(gcnt,0,NN*4,stream);
  (void)hipMemsetAsync(gcur,0,NN*4,stream);
  (void)hipMemsetAsync(oacc,0,NGRAPH*H*4,stream);

  k_hist<<<2048,256,0,stream>>>(iei+EI, EI, 5, ecnt);
  k_scan<<<1,1024,0,stream>>>(ecnt, eoff, SS);
  k_scatter_i<<<2048,256,0,stream>>>(iei, iea, eoff, ecur, epack);
  k_sortsub<<<SS,128,0,stream>>>(eoff, ecnt, epack);
  k_hist<<<512,256,0,stream>>>(gei+EG, EG, 0, gcnt);
  k_scan<<<1,1024,0,stream>>>(gcnt, goff, NN);
  k_scatter_g<<<512,256,0,stream>>>(gei, gea, goff, gcur, gpack);

  k_rwse<<<NN,128,0,stream>>>(rwse, rw_w, rw_b, rf);
  k_h0<<<(SKK*16)/256,256,0,stream>>>(atom, rf, xids, nids, valid, h);

  for(int l=0;l<LNUM;l++){
    (void)hipMemsetAsync(stl,0,256*4,stream);
    (void)hipMemsetAsync(stg,0,256*4,stream);
    k_local_agg<<<SS,128,0,stream>>>(h, bondb, eoff, ecnt, epack, leps, l, X);
    k_mlp2<1><<<SKK/128,256,0,stream>>>(X, wt+(size_t)(l*7+0)*HH, lb1+l*H,
        wt+(size_t)(l*7+1)*HH, lb2+l*H, X, stl);
    k_npool<<<(NN*16)/256,256,0,stream>>>(h, hn);
    k_gagg<<<NN,128,0,stream>>>(hn, bond, goff, gcnt, gpack, geps, l, hhg);
    k_mlp2<1><<<NN/128,256,0,stream>>>(hhg, wt+(size_t)(l*7+2)*HH, gb1+l*H,
        wt+(size_t)(l*7+3)*HH, gb2+l*H, ag, stg);
    k_bnfin<<<1,128,0,stream>>>(stl, stg, lbng+l*H, lbnb+l*H, gbng+l*H, gbnb+l*H, bnl, bnG);
    k_bnadd<<<(NN*H+255)/256,256,0,stream>>>(hn, ag, bnG, hn2);
    k_mgemm<0><<<NN/128,256,0,stream>>>(hn2, wt+(size_t)(l*7+4)*HH, nullptr, bno,
        nullptr,nullptr,nullptr,nullptr,nullptr,nullptr);
    k_mgemm<0><<<NN/128,256,0,stream>>>(bno, wt+(size_t)(l*7+5)*HH, nullptr, bb,
        nullptr,nullptr,nullptr,nullptr,nullptr,nullptr);
    k_prepw3<<<128,128,0,stream>>>(cw1+(size_t)l*2*HH, cb1+l*H, bnl, wt3, bias3);
    k_mgemm<3><<<SKK/128,256,0,stream>>>(X, wt3, bias3, X,
        bb,nullptr,nullptr,nullptr,nullptr,nullptr);
    k_mgemm<4><<<SKK/128,256,0,stream>>>(X, wt+(size_t)(l*7+6)*HH, cb2+l*H, h,
        nullptr,nullptr, h, valid, lngp+l*H, lnbp+l*H);
  }
  k_pool<<<NN,128,0,stream>>>(h, valid, batch, oacc);
  k_out<<<(NGRAPH*H+255)/256,256,0,stream>>>(oacc, flag, d_out);
}

// Round 7
// 1822.423 us; speedup vs baseline: 2.3791x; 1.0769x over previous
//
#include <hip/hip_runtime.h>
#include <hip/hip_bf16.h>

#define H 128
#define HH 16384
#define LNUM 4
#define NN 4096
#define SS 8192
#define SKK 262144
#define EI 1048576
#define EG 65536
#define NGRAPH 64

typedef unsigned short u16;
typedef unsigned int u32;
typedef __attribute__((ext_vector_type(8))) short s16x8;
typedef __attribute__((ext_vector_type(4))) float f32x4;

__device__ __forceinline__ float b2f(u32 u){ return __uint_as_float(u<<16); }
__device__ __forceinline__ u16 f2b(float f){
  union { __hip_bfloat16 b; u16 u; } x;
  x.b=__float2bfloat16(f);
  return x.u;
}
__device__ __forceinline__ void unp8(uint4 v, float* f){
  f[0]=b2f(v.x&0xFFFF); f[1]=b2f(v.x>>16);
  f[2]=b2f(v.y&0xFFFF); f[3]=b2f(v.y>>16);
  f[4]=b2f(v.z&0xFFFF); f[5]=b2f(v.z>>16);
  f[6]=b2f(v.w&0xFFFF); f[7]=b2f(v.w>>16);
}
__device__ __forceinline__ void unp4(uint2 v, float* f){
  f[0]=b2f(v.x&0xFFFF); f[1]=b2f(v.x>>16);
  f[2]=b2f(v.y&0xFFFF); f[3]=b2f(v.y>>16);
}
__device__ __forceinline__ uint4 pk8(const float* f){
  uint4 r;
  r.x=(u32)f2b(f[0])|((u32)f2b(f[1])<<16);
  r.y=(u32)f2b(f[2])|((u32)f2b(f[3])<<16);
  r.z=(u32)f2b(f[4])|((u32)f2b(f[5])<<16);
  r.w=(u32)f2b(f[6])|((u32)f2b(f[7])<<16);
  return r;
}
__device__ __forceinline__ uint2 pk4(const float* f){
  uint2 r;
  r.x=(u32)f2b(f[0])|((u32)f2b(f[1])<<16);
  r.y=(u32)f2b(f[2])|((u32)f2b(f[3])<<16);
  return r;
}

struct CvtArgs {
  const void* p[26];
  int start[27];
};
struct TransArgs { int src[28]; };

// ---- dtype sniff
__global__ void k_sniff(const u16* __restrict__ a, int* __restrict__ flag){
  __shared__ int cnt;
  if(threadIdx.x==0) cnt=0;
  __syncthreads();
  int big=0;
  for(int i=threadIdx.x;i<2048;i+=256){
    int e=(a[i]>>7)&0xFF;
    if(e>=127) big++;
  }
  atomicAdd(&cnt,big);
  __syncthreads();
  if(threadIdx.x==0) *flag=(cnt<16)?1:0;
}

__global__ void k_convert(CvtArgs args, const int* __restrict__ flag, float* __restrict__ dst){
  int fl=*flag;
  int total=args.start[26];
  for(int i=blockIdx.x*blockDim.x+threadIdx.x;i<total;i+=gridDim.x*blockDim.x){
    int a=0;
    while(args.start[a+1]<=i) a++;
    int j=i-args.start[a];
    float v;
    if(fl) v=b2f(((const u16*)args.p[a])[j]);
    else   v=((const float*)args.p[a])[j];
    dst[i]=v;
  }
}

// ---- static weights: f32 [K][N] -> bf16 fragment-major packed
// packed idx: fc=(n*4+kc) in 0..31; element ((fc*64 + lane)*8 + j) holds
// W^T[n*16+(lane&15)][kc*32+(lane>>4)*8+j] = src[k*H + outcol]
__global__ __launch_bounds__(256) void k_trans(const float* __restrict__ par, TransArgs ta, u16* __restrict__ wt){
  const float* s=par+ta.src[blockIdx.x];
  u16* d=wt+(size_t)blockIdx.x*HH;
  for(int i=threadIdx.x;i<HH;i+=256){
    int j=i&7, lane=(i>>3)&63, fc=i>>9;
    int n=fc>>2, kc=fc&3, lr=lane&15, lk=lane>>4;
    int outc=n*16+lr, k=kc*32+lk*8+j;
    d[i]=f2b(s[(size_t)k*H+outc]);
  }
}

// ---- bond emb f32 -> bf16
__global__ void k_cvtbond(const float* __restrict__ b, u16* __restrict__ bb){
  int i=blockIdx.x*blockDim.x+threadIdx.x;
  if(i<16*H) bb[i]=f2b(b[i]);
}

// ---- fold local-BN affine into cw1_top, packed output; bnl computed inline from stats
__global__ __launch_bounds__(128) void k_prepw3(const float* __restrict__ w, const float* __restrict__ cb1,
                        const float* __restrict__ stl, const float* __restrict__ gl, const float* __restrict__ bl,
                        u16* __restrict__ wt3p, float* __restrict__ bias3){
  __shared__ float red[128];
  int c=blockIdx.x, k=threadIdx.x;
  float mu=stl[k]*(1.f/262144.f);
  float var=stl[128+k]*(1.f/262144.f)-mu*mu;
  float s=gl[k]*rsqrtf(var+1e-5f);
  float tt=bl[k]-mu*s;
  float wv=w[(size_t)k*H+c];
  int idx=(((c>>4)*4+(k>>5))*64+((k>>3)&3)*16+(c&15))*8+(k&7);
  wt3p[idx]=f2b(s*wv);
  red[k]=tt*wv;
  __syncthreads();
  for(int d=64;d>0;d>>=1){ if(k<d) red[k]+=red[k+d]; __syncthreads(); }
  if(k==0) bias3[c]=cb1[c]+red[0];
}

// ---- edge bucketing
__global__ void k_hist(const int* __restrict__ idx, int n, int shift, int* __restrict__ cnt){
  for(int i=blockIdx.x*blockDim.x+threadIdx.x;i<n;i+=gridDim.x*blockDim.x)
    atomicAdd(&cnt[idx[i]>>shift],1);
}

__global__ void k_scan(const int* __restrict__ cnt, int* __restrict__ off, int nbins){
  __shared__ int ts[1024];
  int t=threadIdx.x;
  int per=nbins>>10;
  int base=t*per;
  int s=0;
  for(int j=0;j<per;j++) s+=cnt[base+j];
  ts[t]=s;
  __syncthreads();
  for(int d=1;d<1024;d<<=1){
    int v=(t>=d)?ts[t-d]:0;
    __syncthreads();
    ts[t]+=v;
    __syncthreads();
  }
  int ex=(t==0)?0:ts[t-1];
  for(int j=0;j<per;j++){ off[base+j]=ex; ex+=cnt[base+j]; }
}

__global__ void k_scatter_i(const int* __restrict__ ei, const int* __restrict__ ea,
                            const int* __restrict__ off, int* __restrict__ cur, int* __restrict__ pack){
  for(int i=blockIdx.x*blockDim.x+threadIdx.x;i<EI;i+=gridDim.x*blockDim.x){
    int s=ei[i], d=ei[EI+i];
    int sub=d>>5;
    int pos=off[sub]+atomicAdd(&cur[sub],1);
    pack[pos]=((s&31)<<9)|((d&31)<<4)|(ea[i]&15);
  }
}

// ---- sort each subgraph's edges by dst-lane (in-LDS counting sort)
__global__ __launch_bounds__(128) void k_sortsub(const int* __restrict__ eoff, const int* __restrict__ ecnt,
                                                 int* __restrict__ epack){
  __shared__ int ein[512];
  __shared__ int eout[512];
  __shared__ int bcnt[32];
  __shared__ int bpos[32];
  int sub=blockIdx.x, t=threadIdx.x;
  int o=eoff[sub];
  int n=ecnt[sub]; if(n>512) n=512;
  for(int i=t;i<n;i+=128) ein[i]=epack[o+i];
  if(t<32) bcnt[t]=0;
  __syncthreads();
  for(int i=t;i<n;i+=128) atomicAdd(&bcnt[(ein[i]>>4)&31],1);
  __syncthreads();
  if(t==0){
    int s=0;
    for(int b=0;b<32;b++){ bpos[b]=s; s+=bcnt[b]; }
  }
  __syncthreads();
  for(int i=t;i<n;i+=128){
    int p=ein[i];
    int pos=atomicAdd(&bpos[(p>>4)&31],1);
    eout[pos]=p;
  }
  __syncthreads();
  for(int i=t;i<n;i+=128) epack[o+i]=eout[i];
}

__global__ void k_scatter_g(const int* __restrict__ ei, const int* __restrict__ ea,
                            const int* __restrict__ off, int* __restrict__ cur, int* __restrict__ pack){
  for(int i=blockIdx.x*blockDim.x+threadIdx.x;i<EG;i+=gridDim.x*blockDim.x){
    int s=ei[i], d=ei[EG+i];
    int pos=off[d]+atomicAdd(&cur[d],1);
    pack[pos]=(s<<4)|(ea[i]&15);
  }
}

// ---- rf = relu(rwse @ rwse_w + rwse_b)
__global__ __launch_bounds__(128) void k_rwse(const float* __restrict__ rwse, const float* __restrict__ w,
                      const float* __restrict__ b, float* __restrict__ rf){
  __shared__ float ws[16*128];
  __shared__ float rv[16];
  int n=blockIdx.x, c=threadIdx.x;
  for(int i=c;i<2048;i+=128) ws[i]=w[i];
  if(c<16) rv[c]=rwse[n*16+c];
  __syncthreads();
  float acc=b[c];
  for(int j=0;j<16;j++) acc=fmaf(rv[j],ws[j*128+c],acc);
  rf[(size_t)n*H+c]=fmaxf(acc,0.f);
}

// ---- h0
__global__ void k_h0(const float* __restrict__ atom, const float* __restrict__ rf,
                     const int* __restrict__ xids, const int* __restrict__ nids,
                     const int* __restrict__ valid, u16* __restrict__ h){
  int i=blockIdx.x*blockDim.x+threadIdx.x;
  if(i>=SKK*16) return;
  int r=i>>4, q=i&15;
  const float4* ap=(const float4*)(atom+(size_t)xids[r]*H)+q*2;
  const float4* bp=(const float4*)(rf+(size_t)nids[r]*H)+q*2;
  float4 a0=ap[0],a1=ap[1],b0=bp[0],b1=bp[1];
  float vm=valid[r]?1.f:0.f;
  float f[8]={(a0.x+b0.x)*vm,(a0.y+b0.y)*vm,(a0.z+b0.z)*vm,(a0.w+b0.w)*vm,
              (a1.x+b1.x)*vm,(a1.y+b1.y)*vm,(a1.z+b1.z)*vm,(a1.w+b1.w)*vm};
  ((uint4*)h)[i]=pk8(f);
}

// ---- local GINE aggregation: thread=channel, register acc over dst-sorted edges
__global__ __launch_bounds__(128) void k_local_agg(const u16* __restrict__ h, const u16* __restrict__ beb,
                           const int* __restrict__ eoff, const int* __restrict__ ecnt,
                           const int* __restrict__ epack, const float* __restrict__ epsp, int layer,
                           u16* __restrict__ hh){
  __shared__ u16 hs[32*128];
  __shared__ u16 bes[16*128];
  __shared__ float ag[32*128];
  __shared__ int epk[128];
  int sub=blockIdx.x, c=threadIdx.x;
  size_t base=(size_t)sub*32*H;
  {
    const uint4* src=(const uint4*)(h+base);
    uint4* dst=(uint4*)hs;
    for(int i=c;i<512;i+=128) dst[i]=src[i];
    const uint4* bsrc=(const uint4*)beb;
    uint4* bdst=(uint4*)bes;
    for(int i=c;i<256;i+=128) bdst[i]=bsrc[i];
    float4* az=(float4*)ag;
    for(int i=c;i<1024;i+=128) az[i]=make_float4(0,0,0,0);
  }
  int o=eoff[sub], n=ecnt[sub];
  float acc=0.f;
  int cur=-1;
  for(int b0=0;b0<n;b0+=128){
    __syncthreads();
    if(b0+c<n) epk[c]=epack[o+b0+c];
    __syncthreads();
    int lim=n-b0; if(lim>128) lim=128;
    #pragma unroll 4
    for(int i=0;i<lim;i++){
      int p=epk[i];
      int dl=(p>>4)&31;
      if(dl!=cur){
        if(cur>=0) ag[cur*128+c]=acc;
        acc=0.f; cur=dl;
      }
      acc+=fmaxf(b2f(hs[(p>>9)*128+c])+b2f(bes[(p&15)*128+c]),0.f);
    }
  }
  if(cur>=0) ag[cur*128+c]=acc;
  __syncthreads();
  float ep=1.f+epsp[layer];
  for(int idx=c;idx<512;idx+=128){
    int r=idx>>4, ch=(idx&15)*8;
    float hv[8],o8[8];
    unp8(*(const uint4*)(hs+r*128+ch),hv);
    const float* ar=ag+r*128+ch;
    #pragma unroll
    for(int j=0;j<8;j++) o8[j]=fmaf(ep,hv[j],ar[j]);
    ((uint4*)(hh+base))[idx]=pk8(o8);
  }
}

// ==== plain MFMA GEMM (node path): out = A@W, packed weights
__global__ __launch_bounds__(256) void k_mgemm0(const u16* __restrict__ A, const u16* __restrict__ Wp,
                                                u16* __restrict__ out){
  int t=threadIdx.x;
  int wave=t>>6, lane=t&63;
  int lr=lane&15, lk=lane>>4;
  int rowW=blockIdx.x*128+wave*32;
  f32x4 acc[2][8];
  #pragma unroll
  for(int m=0;m<2;m++)
    #pragma unroll
    for(int n=0;n<8;n++) acc[m][n]=(f32x4){0.f,0.f,0.f,0.f};
  const s16x8* B0=(const s16x8*)(A+(size_t)(rowW+lr)*H);
  const s16x8* B1=(const s16x8*)(A+(size_t)(rowW+16+lr)*H);
  #pragma unroll
  for(int kc=0;kc<4;kc++){
    s16x8 bf0=B0[kc*4+lk];
    s16x8 bf1=B1[kc*4+lk];
    #pragma unroll
    for(int n=0;n<8;n++){
      s16x8 af=*(const s16x8*)(Wp+((n*4+kc)<<9)+lane*8);
      acc[0][n]=__builtin_amdgcn_mfma_f32_16x16x32_bf16(af,bf0,acc[0][n],0,0,0);
      acc[1][n]=__builtin_amdgcn_mfma_f32_16x16x32_bf16(af,bf1,acc[1][n],0,0,0);
    }
  }
  int row0=rowW+lr, row1=rowW+16+lr;
  #pragma unroll
  for(int n=0;n<8;n++){
    int c0=n*16+lk*4;
    float v0[4]={acc[0][n][0],acc[0][n][1],acc[0][n][2],acc[0][n][3]};
    float v1[4]={acc[1][n][0],acc[1][n][1],acc[1][n][2],acc[1][n][3]};
    *(uint2*)(out+(size_t)row0*H+c0)=pk4(v0);
    *(uint2*)(out+(size_t)row1*H+c0)=pk4(v1);
  }
}

// ==== fused MLP: out = relu( relu(A@W1+b1) @ W2 + b2 ), optional col stats
template<int STATS>
__global__ __launch_bounds__(256) void k_mlp2(
    const u16* __restrict__ A, const u16* __restrict__ W1p, const float* __restrict__ b1,
    const u16* __restrict__ W2p, const float* __restrict__ b2,
    u16* __restrict__ out, float* __restrict__ stats)
{
  __shared__ u16 T[128*128];
  __shared__ float sst[256];
  int t=threadIdx.x;
  if(STATS){ if(t<256) sst[t]=0.f; __syncthreads(); }
  int wave=t>>6, lane=t&63;
  int lr=lane&15, lk=lane>>4;
  int rowW=blockIdx.x*128+wave*32;

  f32x4 acc[2][8];
  #pragma unroll
  for(int m=0;m<2;m++)
    #pragma unroll
    for(int n=0;n<8;n++) acc[m][n]=(f32x4){0.f,0.f,0.f,0.f};

  const s16x8* B0=(const s16x8*)(A+(size_t)(rowW+lr)*H);
  const s16x8* B1=(const s16x8*)(A+(size_t)(rowW+16+lr)*H);
  #pragma unroll
  for(int kc=0;kc<4;kc++){
    s16x8 bf0=B0[kc*4+lk];
    s16x8 bf1=B1[kc*4+lk];
    #pragma unroll
    for(int n=0;n<8;n++){
      s16x8 af=*(const s16x8*)(W1p+((n*4+kc)<<9)+lane*8);
      acc[0][n]=__builtin_amdgcn_mfma_f32_16x16x32_bf16(af,bf0,acc[0][n],0,0,0);
      acc[1][n]=__builtin_amdgcn_mfma_f32_16x16x32_bf16(af,bf1,acc[1][n],0,0,0);
    }
  }
  // relu(.+b1) -> swizzled LDS (wave-local rows)
  #pragma unroll
  for(int m=0;m<2;m++){
    int rl=wave*32+m*16+lr;
    u32 rb=(u32)rl*256;
    #pragma unroll
    for(int n=0;n<8;n++){
      int c0=n*16+lk*4;
      float4 b4=*(const float4*)(b1+c0);
      float vb[4]={b4.x,b4.y,b4.z,b4.w};
      float v[4];
      #pragma unroll
      for(int j=0;j<4;j++) v[j]=fmaxf(acc[m][n][j]+vb[j],0.f);
      u32 off=rb+(((u32)(c0*2))^((u32)(rl&7)<<4));
      *(uint2*)((char*)T+off)=pk4(v);
    }
  }
  // phase 2
  #pragma unroll
  for(int m=0;m<2;m++)
    #pragma unroll
    for(int n=0;n<8;n++) acc[m][n]=(f32x4){0.f,0.f,0.f,0.f};
  int rl0=wave*32+lr, rl1=rl0+16;
  #pragma unroll
  for(int kc=0;kc<4;kc++){
    u32 cbyte=(u32)((kc*32+lk*8)*2);
    u32 o0=(u32)rl0*256+(cbyte^((u32)(rl0&7)<<4));
    u32 o1=(u32)rl1*256+(cbyte^((u32)(rl1&7)<<4));
    s16x8 bf0=*(const s16x8*)((char*)T+o0);
    s16x8 bf1=*(const s16x8*)((char*)T+o1);
    #pragma unroll
    for(int n=0;n<8;n++){
      s16x8 af=*(const s16x8*)(W2p+((n*4+kc)<<9)+lane*8);
      acc[0][n]=__builtin_amdgcn_mfma_f32_16x16x32_bf16(af,bf0,acc[0][n],0,0,0);
      acc[1][n]=__builtin_amdgcn_mfma_f32_16x16x32_bf16(af,bf1,acc[1][n],0,0,0);
    }
  }
  // epilogue -> stage into own rows of T, then coalesced flush
  #pragma unroll
  for(int n=0;n<8;n++){
    int c0=n*16+lk*4;
    float4 b4=*(const float4*)(b2+c0);
    float vb[4]={b4.x,b4.y,b4.z,b4.w};
    float v0[4],v1[4];
    #pragma unroll
    for(int j=0;j<4;j++){
      v0[j]=fmaxf(acc[0][n][j]+vb[j],0.f);
      v1[j]=fmaxf(acc[1][n][j]+vb[j],0.f);
    }
    u32 o0=(u32)rl0*256+(((u32)(c0*2))^((u32)(rl0&7)<<4));
    u32 o1=(u32)rl1*256+(((u32)(c0*2))^((u32)(rl1&7)<<4));
    *(uint2*)((char*)T+o0)=pk4(v0);
    *(uint2*)((char*)T+o1)=pk4(v1);
    if(STATS){
      float s[4],q[4];
      #pragma unroll
      for(int j=0;j<4;j++){
        s[j]=v0[j]+v1[j];
        q[j]=v0[j]*v0[j]+v1[j]*v1[j];
      }
      #pragma unroll
      for(int j=0;j<4;j++){
        #pragma unroll
        for(int d=1;d<16;d<<=1){
          s[j]+=__shfl_xor(s[j],d);
          q[j]+=__shfl_xor(q[j],d);
        }
      }
      if(lr==0){
        #pragma unroll
        for(int j=0;j<4;j++){
          atomicAdd(&sst[c0+j],s[j]);
          atomicAdd(&sst[128+c0+j],q[j]);
        }
      }
    }
  }
  __syncthreads();
  #pragma unroll
  for(int p=0;p<8;p++){
    u32 flat=(u32)p*4096+(u32)t*16;
    u32 row=flat>>8, colb=flat&255;
    uint4 v=*(const uint4*)((const char*)T+row*256+(colb^((row&7)<<4)));
    *(uint4*)(out+(size_t)(blockIdx.x*128+row)*H+(colb>>1))=v;
  }
  if(STATS){
    if(t<256) atomicAdd(&stats[t],sst[t]);
  }
}

// ==== fused tail: h = (res + LN( gelu(X@W3+bias3+bb[node]) @ W2 + cb2 )) * valid
__global__ __launch_bounds__(256) void k_tail(
    const u16* __restrict__ X, const u16* __restrict__ W3p, const float* __restrict__ bias3,
    const u16* __restrict__ bb,
    const u16* __restrict__ W2p, const float* __restrict__ cb2,
    const float* __restrict__ lng, const float* __restrict__ lnb,
    const int* __restrict__ validv, u16* __restrict__ hio)
{
  __shared__ u16 T[128*128];
  int t=threadIdx.x;
  int wave=t>>6, lane=t&63;
  int lr=lane&15, lk=lane>>4;
  int rowW=blockIdx.x*128+wave*32;

  f32x4 acc[2][8];
  #pragma unroll
  for(int m=0;m<2;m++)
    #pragma unroll
    for(int n=0;n<8;n++) acc[m][n]=(f32x4){0.f,0.f,0.f,0.f};

  const s16x8* B0=(const s16x8*)(X+(size_t)(rowW+lr)*H);
  const s16x8* B1=(const s16x8*)(X+(size_t)(rowW+16+lr)*H);
  #pragma unroll
  for(int kc=0;kc<4;kc++){
    s16x8 bf0=B0[kc*4+lk];
    s16x8 bf1=B1[kc*4+lk];
    #pragma unroll
    for(int n=0;n<8;n++){
      s16x8 af=*(const s16x8*)(W3p+((n*4+kc)<<9)+lane*8);
      acc[0][n]=__builtin_amdgcn_mfma_f32_16x16x32_bf16(af,bf0,acc[0][n],0,0,0);
      acc[1][n]=__builtin_amdgcn_mfma_f32_16x16x32_bf16(af,bf1,acc[1][n],0,0,0);
    }
  }
  // epilogue1: gelu(acc + bias3 + bb[node]) -> T swizzled
  int nb=rowW>>6;
  int rl0=wave*32+lr, rl1=rl0+16;
  #pragma unroll
  for(int n=0;n<8;n++){
    int c0=n*16+lk*4;
    float4 b4=*(const float4*)(bias3+c0);
    float vb[4]={b4.x,b4.y,b4.z,b4.w};
    float rb[4];
    unp4(*(const uint2*)(bb+(size_t)nb*H+c0),rb);
    float v0[4],v1[4];
    #pragma unroll
    for(int j=0;j<4;j++){
      float x0=acc[0][n][j]+vb[j]+rb[j];
      float x1=acc[1][n][j]+vb[j]+rb[j];
      v0[j]=0.5f*x0*(1.f+erff(x0*0.70710678118654752f));
      v1[j]=0.5f*x1*(1.f+erff(x1*0.70710678118654752f));
    }
    u32 o0=(u32)rl0*256+(((u32)(c0*2))^((u32)(rl0&7)<<4));
    u32 o1=(u32)rl1*256+(((u32)(c0*2))^((u32)(rl1&7)<<4));
    *(uint2*)((char*)T+o0)=pk4(v0);
    *(uint2*)((char*)T+o1)=pk4(v1);
  }
  // phase 2
  #pragma unroll
  for(int m=0;m<2;m++)
    #pragma unroll
    for(int n=0;n<8;n++) acc[m][n]=(f32x4){0.f,0.f,0.f,0.f};
  #pragma unroll
  for(int kc=0;kc<4;kc++){
    u32 cbyte=(u32)((kc*32+lk*8)*2);
    u32 o0=(u32)rl0*256+(cbyte^((u32)(rl0&7)<<4));
    u32 o1=(u32)rl1*256+(cbyte^((u32)(rl1&7)<<4));
    s16x8 bf0=*(const s16x8*)((char*)T+o0);
    s16x8 bf1=*(const s16x8*)((char*)T+o1);
    #pragma unroll
    for(int n=0;n<8;n++){
      s16x8 af=*(const s16x8*)(W2p+((n*4+kc)<<9)+lane*8);
      acc[0][n]=__builtin_amdgcn_mfma_f32_16x16x32_bf16(af,bf0,acc[0][n],0,0,0);
      acc[1][n]=__builtin_amdgcn_mfma_f32_16x16x32_bf16(af,bf1,acc[1][n],0,0,0);
    }
  }
  // epilogue2: LN value only (residual+valid applied in flush)
  #pragma unroll
  for(int m=0;m<2;m++){
    int rl=wave*32+m*16+lr;
    float s=0.f,q=0.f;
    #pragma unroll
    for(int n=0;n<8;n++){
      int c0=n*16+lk*4;
      float4 b4=*(const float4*)(cb2+c0);
      float vb[4]={b4.x,b4.y,b4.z,b4.w};
      #pragma unroll
      for(int j=0;j<4;j++){
        float v=acc[m][n][j]+vb[j];
        acc[m][n][j]=v;
        s+=v; q+=v*v;
      }
    }
    s+=__shfl_xor(s,16); s+=__shfl_xor(s,32);
    q+=__shfl_xor(q,16); q+=__shfl_xor(q,32);
    float mu=s*(1.f/128.f);
    float rsig=rsqrtf(q*(1.f/128.f)-mu*mu+1e-5f);
    #pragma unroll
    for(int n=0;n<8;n++){
      int c0=n*16+lk*4;
      float4 g4=*(const float4*)(lng+c0);
      float4 e4=*(const float4*)(lnb+c0);
      float ov[4];
      #pragma unroll
      for(int j=0;j<4;j++){
        float g=(j==0)?g4.x:(j==1)?g4.y:(j==2)?g4.z:g4.w;
        float e=(j==0)?e4.x:(j==1)?e4.y:(j==2)?e4.z:e4.w;
        ov[j]=(acc[m][n][j]-mu)*rsig*g+e;
      }
      u32 off=(u32)rl*256+(((u32)(c0*2))^((u32)(rl&7)<<4));
      *(uint2*)((char*)T+off)=pk4(ov);
    }
  }
  __syncthreads();
  // coalesced flush with residual + valid mask (in-place on h)
  #pragma unroll
  for(int p=0;p<8;p++){
    u32 flat=(u32)p*4096+(u32)t*16;
    u32 row=flat>>8, colb=flat&255;
    int grow=blockIdx.x*128+(int)row;
    uint4 v=*(const uint4*)((const char*)T+row*256+(colb^((row&7)<<4)));
    uint4 r=((const uint4*)hio)[(size_t)grow*16+(colb>>4)];
    float vv[8],rv[8],o8[8];
    unp8(v,vv); unp8(r,rv);
    float vm=validv[grow]?1.f:0.f;
    #pragma unroll
    for(int j=0;j<8;j++) o8[j]=(rv[j]+vv[j])*vm;
    ((uint4*)hio)[(size_t)grow*16+(colb>>4)]=pk8(o8);
  }
}

// ---- h_node = mean of two root rows
__global__ void k_npool(const u16* __restrict__ h, u16* __restrict__ hn){
  int i=blockIdx.x*blockDim.x+threadIdx.x;
  if(i>=NN*16) return;
  int n=i>>4, q=i&15;
  const uint4* hp=(const uint4*)h;
  float a[8],b[8],o[8];
  unp8(hp[(size_t)n*1024+q],a);
  unp8(hp[(size_t)n*1024+512+q],b);
  #pragma unroll
  for(int e=0;e<8;e++) o[e]=(a[e]+b[e])*0.5f;
  ((uint4*)hn)[i]=pk8(o);
}

// ---- global GINE aggregation per node
__global__ __launch_bounds__(128) void k_gagg(const u16* __restrict__ hn, const float* __restrict__ be,
                      const int* __restrict__ goff, const int* __restrict__ gcnt,
                      const int* __restrict__ gpack, const float* __restrict__ epsp, int layer,
                      u16* __restrict__ hhg){
  __shared__ float bes[16][128];
  int n=blockIdx.x, c=threadIdx.x;
  for(int i=0;i<16;i++) bes[i][c]=be[i*128+c];
  __syncthreads();
  float acc=0.f;
  int o=goff[n], e=o+gcnt[n];
  for(;o<e;o++){
    int p=gpack[o];
    acc+=fmaxf(b2f(hn[(size_t)(p>>4)*H+c])+bes[p&15][c],0.f);
  }
  hhg[(size_t)n*H+c]=f2b(fmaf(1.f+epsp[layer],b2f(hn[(size_t)n*H+c]),acc));
}

// ---- h_node' = h_node + BN_affine(a_g), BN affine computed inline from stats
__global__ void k_bnadd(const u16* __restrict__ hn, const u16* __restrict__ ag,
                        const float* __restrict__ stg, const float* __restrict__ gg,
                        const float* __restrict__ bg, u16* __restrict__ hn2){
  int i=blockIdx.x*blockDim.x+threadIdx.x;
  if(i>=NN*H) return;
  int c=i&127;
  float mu=stg[c]*(1.f/4096.f);
  float var=stg[128+c]*(1.f/4096.f)-mu*mu;
  float s=gg[c]*rsqrtf(var+1e-5f);
  float tt=bg[c]-mu*s;
  hn2[i]=f2b(b2f(hn[i])+fmaf(b2f(ag[i]),s,tt));
}

// ---- final pooling
__global__ __launch_bounds__(128) void k_pool(const u16* __restrict__ h, const int* __restrict__ valid,
                      const int* __restrict__ batch, float* __restrict__ oacc){
  __shared__ float cs[2];
  int n=blockIdx.x, c=threadIdx.x;
  if(c<2){
    int s=0;
    for(int j=0;j<32;j++) s+=valid[n*64+c*32+j];
    cs[c]=fmaxf((float)s,1.f);
  }
  __syncthreads();
  size_t base=(size_t)n*64*H;
  float a0=0.f,a1=0.f;
  for(int j=0;j<32;j++){
    a0+=b2f(h[base+(size_t)j*H+c]);
    a1+=b2f(h[base+(size_t)(32+j)*H+c]);
  }
  float nodef=0.5f*(a0/cs[0]+a1/cs[1]);
  atomicAdd(&oacc[batch[n]*H+c],nodef);
}

__global__ void k_out(const float* __restrict__ acc, const int* __restrict__ flag, void* __restrict__ out){
  int i=blockIdx.x*blockDim.x+threadIdx.x;
  if(i>=NGRAPH*H) return;
  if(*flag) ((__hip_bfloat16*)out)[i]=__float2bfloat16(acc[i]);
  else ((float*)out)[i]=acc[i];
}

extern "C" void kernel_launch(void* const* d_in, const int* in_sizes, int n_in,
                              void* d_out, int out_size, void* d_ws, size_t ws_size,
                              hipStream_t stream){
  (void)n_in; (void)out_size;
  int pofs[27]; pofs[0]=0;
  for(int i=0;i<26;i++) pofs[i+1]=pofs[i]+in_sizes[i];
  int ptot=pofs[26];

  char* wsb=(char*)d_ws;
  size_t off=0;
  auto alloc=[&](size_t bytes)->char*{ char* p=wsb+off; off+=(bytes+255)&~(size_t)255; return p; };
  int*   flag =(int*)  alloc(4);
  float* par  =(float*)alloc((size_t)ptot*4);
  u16*   h    =(u16*)  alloc((size_t)SKK*H*2);
  u16*   X    =(u16*)  alloc((size_t)SKK*H*2);
  u16*   wt   =(u16*)  alloc((size_t)28*HH*2);
  u16*   wt3  =(u16*)  alloc((size_t)HH*2);
  float* bias3=(float*)alloc(H*4);
  float* rf   =(float*)alloc((size_t)NN*H*4);
  u16*   bondb=(u16*)  alloc((size_t)16*H*2);
  u16*   hn   =(u16*)  alloc((size_t)NN*H*2);
  u16*   hhg  =(u16*)  alloc((size_t)NN*H*2);
  u16*   ag   =(u16*)  alloc((size_t)NN*H*2);
  u16*   hn2  =(u16*)  alloc((size_t)NN*H*2);
  u16*   bno  =(u16*)  alloc((size_t)NN*H*2);
  u16*   bb   =(u16*)  alloc((size_t)NN*H*2);
  // ---- contiguous zero-init region (one memset) ----
  int*   ecnt =(int*)  alloc(SS*4);          // 32768
  int*   ecur =(int*)  alloc(SS*4);          // 32768
  int*   gcnt =(int*)  alloc(NN*4);          // 16384
  int*   gcur =(int*)  alloc(NN*4);          // 16384
  float* stats=(float*)alloc(LNUM*512*4);    // 8192
  float* oacc =(float*)alloc((size_t)NGRAPH*H*4); // 32768
  size_t zbytes=(size_t)SS*4+SS*4+NN*4+NN*4+LNUM*512*4+(size_t)NGRAPH*H*4;
  // ---- rest ----
  int* eoff =(int*)alloc(SS*4);
  int* epack=(int*)alloc((size_t)EI*4);
  int* goff =(int*)alloc(NN*4);
  int* gpack=(int*)alloc((size_t)EG*4);

  if(off>ws_size) return;

  const int* xids =(const int*)d_in[26];
  const int* iei  =(const int*)d_in[27];
  const int* iea  =(const int*)d_in[28];
  const int* gei  =(const int*)d_in[29];
  const int* gea  =(const int*)d_in[30];
  const int* nids =(const int*)d_in[31];
  const int* valid=(const int*)d_in[32];
  const int* batch=(const int*)d_in[33];

  const float* atom=par+pofs[0];
  const float* bond=par+pofs[1];
  const float* rw_w=par+pofs[2];
  const float* rw_b=par+pofs[3];
  const float* rwse=par+pofs[4];
  const float* leps=par+pofs[5];
  const float* lb1 =par+pofs[7];
  const float* lb2 =par+pofs[9];
  const float* lbng=par+pofs[10];
  const float* lbnb=par+pofs[11];
  const float* geps=par+pofs[12];
  const float* gb1 =par+pofs[14];
  const float* gb2 =par+pofs[16];
  const float* gbng=par+pofs[17];
  const float* gbnb=par+pofs[18];
  const float* cw1 =par+pofs[20];
  const float* cb1 =par+pofs[21];
  const float* cb2 =par+pofs[23];
  const float* lngp=par+pofs[24];
  const float* lnbp=par+pofs[25];

  k_sniff<<<1,256,0,stream>>>((const u16*)d_in[0], flag);
  CvtArgs ca;
  for(int i=0;i<26;i++){ ca.p[i]=d_in[i]; ca.start[i]=pofs[i]; }
  ca.start[26]=ptot;
  k_convert<<<1024,256,0,stream>>>(ca, flag, par);

  TransArgs ta;
  for(int l=0;l<LNUM;l++){
    ta.src[l*7+0]=pofs[6]+l*HH;           // lw1
    ta.src[l*7+1]=pofs[8]+l*HH;           // lw2
    ta.src[l*7+2]=pofs[13]+l*HH;          // gw1
    ta.src[l*7+3]=pofs[15]+l*HH;          // gw2
    ta.src[l*7+4]=pofs[19]+l*HH;          // bcw
    ta.src[l*7+5]=pofs[20]+l*2*HH+HH;     // cw1 bottom half
    ta.src[l*7+6]=pofs[22]+l*HH;          // cw2
  }
  k_trans<<<28,256,0,stream>>>(par, ta, wt);
  k_cvtbond<<<8,256,0,stream>>>(bond, bondb);

  (void)hipMemsetAsync(ecnt,0,zbytes,stream);

  k_hist<<<2048,256,0,stream>>>(iei+EI, EI, 5, ecnt);
  k_scan<<<1,1024,0,stream>>>(ecnt, eoff, SS);
  k_scatter_i<<<2048,256,0,stream>>>(iei, iea, eoff, ecur, epack);
  k_sortsub<<<SS,128,0,stream>>>(eoff, ecnt, epack);
  k_hist<<<512,256,0,stream>>>(gei+EG, EG, 0, gcnt);
  k_scan<<<1,1024,0,stream>>>(gcnt, goff, NN);
  k_scatter_g<<<512,256,0,stream>>>(gei, gea, goff, gcur, gpack);

  k_rwse<<<NN,128,0,stream>>>(rwse, rw_w, rw_b, rf);
  k_h0<<<(SKK*16)/256,256,0,stream>>>(atom, rf, xids, nids, valid, h);

  for(int l=0;l<LNUM;l++){
    float* stl_l=stats+l*512;
    float* stg_l=stats+l*512+256;
    k_local_agg<<<SS,128,0,stream>>>(h, bondb, eoff, ecnt, epack, leps, l, X);
    k_mlp2<1><<<SKK/128,256,0,stream>>>(X, wt+(size_t)(l*7+0)*HH, lb1+l*H,
        wt+(size_t)(l*7+1)*HH, lb2+l*H, X, stl_l);
    k_npool<<<(NN*16)/256,256,0,stream>>>(h, hn);
    k_gagg<<<NN,128,0,stream>>>(hn, bond, goff, gcnt, gpack, geps, l, hhg);
    k_mlp2<1><<<NN/128,256,0,stream>>>(hhg, wt+(size_t)(l*7+2)*HH, gb1+l*H,
        wt+(size_t)(l*7+3)*HH, gb2+l*H, ag, stg_l);
    k_bnadd<<<(NN*H+255)/256,256,0,stream>>>(hn, ag, stg_l, gbng+l*H, gbnb+l*H, hn2);
    k_mgemm0<<<NN/128,256,0,stream>>>(hn2, wt+(size_t)(l*7+4)*HH, bno);
    k_mgemm0<<<NN/128,256,0,stream>>>(bno, wt+(size_t)(l*7+5)*HH, bb);
    k_prepw3<<<128,128,0,stream>>>(cw1+(size_t)l*2*HH, cb1+l*H, stl_l, lbng+l*H, lbnb+l*H, wt3, bias3);
    k_tail<<<SKK/128,256,0,stream>>>(X, wt3, bias3, bb,
        wt+(size_t)(l*7+6)*HH, cb2+l*H, lngp+l*H, lnbp+l*H, valid, h);
  }
  k_pool<<<NN,128,0,stream>>>(h, valid, batch, oacc);
  k_out<<<(NGRAPH*H+255)/256,256,0,stream>>>(oacc, flag, d_out);
}

// Round 8
// 1488.503 us; speedup vs baseline: 2.9129x; 1.2243x over previous
//
#include <hip/hip_runtime.h>
#include <hip/hip_bf16.h>

#define H 128
#define HH 16384
#define LNUM 4
#define NN 4096
#define SS 8192
#define SKK 262144
#define EI 1048576
#define EG 65536
#define NGRAPH 64

typedef unsigned short u16;
typedef unsigned int u32;
typedef __attribute__((ext_vector_type(8))) short s16x8;
typedef __attribute__((ext_vector_type(4))) float f32x4;

__device__ __forceinline__ float b2f(u32 u){ return __uint_as_float(u<<16); }
__device__ __forceinline__ u16 f2b(float f){
  union { __hip_bfloat16 b; u16 u; } x;
  x.b=__float2bfloat16(f);
  return x.u;
}
__device__ __forceinline__ void unp8(uint4 v, float* f){
  f[0]=b2f(v.x&0xFFFF); f[1]=b2f(v.x>>16);
  f[2]=b2f(v.y&0xFFFF); f[3]=b2f(v.y>>16);
  f[4]=b2f(v.z&0xFFFF); f[5]=b2f(v.z>>16);
  f[6]=b2f(v.w&0xFFFF); f[7]=b2f(v.w>>16);
}
__device__ __forceinline__ void unp4(uint2 v, float* f){
  f[0]=b2f(v.x&0xFFFF); f[1]=b2f(v.x>>16);
  f[2]=b2f(v.y&0xFFFF); f[3]=b2f(v.y>>16);
}
__device__ __forceinline__ uint4 pk8(const float* f){
  uint4 r;
  r.x=(u32)f2b(f[0])|((u32)f2b(f[1])<<16);
  r.y=(u32)f2b(f[2])|((u32)f2b(f[3])<<16);
  r.z=(u32)f2b(f[4])|((u32)f2b(f[5])<<16);
  r.w=(u32)f2b(f[6])|((u32)f2b(f[7])<<16);
  return r;
}
__device__ __forceinline__ uint2 pk4(const float* f){
  uint2 r;
  r.x=(u32)f2b(f[0])|((u32)f2b(f[1])<<16);
  r.y=(u32)f2b(f[2])|((u32)f2b(f[3])<<16);
  return r;
}

struct CvtArgs {
  const void* p[26];
  int start[27];
};
struct TransArgs { int src[28]; };

// ---- dtype sniff
__global__ void k_sniff(const u16* __restrict__ a, int* __restrict__ flag){
  __shared__ int cnt;
  if(threadIdx.x==0) cnt=0;
  __syncthreads();
  int big=0;
  for(int i=threadIdx.x;i<2048;i+=256){
    int e=(a[i]>>7)&0xFF;
    if(e>=127) big++;
  }
  atomicAdd(&cnt,big);
  __syncthreads();
  if(threadIdx.x==0) *flag=(cnt<16)?1:0;
}

__global__ void k_convert(CvtArgs args, const int* __restrict__ flag, float* __restrict__ dst){
  int fl=*flag;
  int total=args.start[26];
  for(int i=blockIdx.x*blockDim.x+threadIdx.x;i<total;i+=gridDim.x*blockDim.x){
    int a=0;
    while(args.start[a+1]<=i) a++;
    int j=i-args.start[a];
    float v;
    if(fl) v=b2f(((const u16*)args.p[a])[j]);
    else   v=((const float*)args.p[a])[j];
    dst[i]=v;
  }
}

// ---- static weights: f32 [K][N] -> bf16 fragment-major packed
__global__ __launch_bounds__(256) void k_trans(const float* __restrict__ par, TransArgs ta, u16* __restrict__ wt){
  const float* s=par+ta.src[blockIdx.x];
  u16* d=wt+(size_t)blockIdx.x*HH;
  for(int i=threadIdx.x;i<HH;i+=256){
    int j=i&7, lane=(i>>3)&63, fc=i>>9;
    int n=fc>>2, kc=fc&3, lr=lane&15, lk=lane>>4;
    int outc=n*16+lr, k=kc*32+lk*8+j;
    d[i]=f2b(s[(size_t)k*H+outc]);
  }
}

// ---- bond emb f32 -> bf16
__global__ void k_cvtbond(const float* __restrict__ b, u16* __restrict__ bb){
  int i=blockIdx.x*blockDim.x+threadIdx.x;
  if(i<16*H) bb[i]=f2b(b[i]);
}

// ---- fold local-BN affine into cw1_top, packed output
__global__ __launch_bounds__(128) void k_prepw3(const float* __restrict__ w, const float* __restrict__ cb1,
                        const float* __restrict__ stl, const float* __restrict__ gl, const float* __restrict__ bl,
                        u16* __restrict__ wt3p, float* __restrict__ bias3){
  __shared__ float red[128];
  int c=blockIdx.x, k=threadIdx.x;
  float mu=stl[k]*(1.f/262144.f);
  float var=stl[128+k]*(1.f/262144.f)-mu*mu;
  float s=gl[k]*rsqrtf(var+1e-5f);
  float tt=bl[k]-mu*s;
  float wv=w[(size_t)k*H+c];
  int idx=(((c>>4)*4+(k>>5))*64+((k>>3)&3)*16+(c&15))*8+(k&7);
  wt3p[idx]=f2b(s*wv);
  red[k]=tt*wv;
  __syncthreads();
  for(int d=64;d>0;d>>=1){ if(k<d) red[k]+=red[k+d]; __syncthreads(); }
  if(k==0) bias3[c]=cb1[c]+red[0];
}

// ---- edge bucketing
__global__ void k_hist(const int* __restrict__ idx, int n, int shift, int* __restrict__ cnt){
  for(int i=blockIdx.x*blockDim.x+threadIdx.x;i<n;i+=gridDim.x*blockDim.x)
    atomicAdd(&cnt[idx[i]>>shift],1);
}

__global__ void k_scan(const int* __restrict__ cnt, int* __restrict__ off, int nbins){
  __shared__ int ts[1024];
  int t=threadIdx.x;
  int per=nbins>>10;
  int base=t*per;
  int s=0;
  for(int j=0;j<per;j++) s+=cnt[base+j];
  ts[t]=s;
  __syncthreads();
  for(int d=1;d<1024;d<<=1){
    int v=(t>=d)?ts[t-d]:0;
    __syncthreads();
    ts[t]+=v;
    __syncthreads();
  }
  int ex=(t==0)?0:ts[t-1];
  for(int j=0;j<per;j++){ off[base+j]=ex; ex+=cnt[base+j]; }
}

__global__ void k_scatter_i(const int* __restrict__ ei, const int* __restrict__ ea,
                            const int* __restrict__ off, int* __restrict__ cur, int* __restrict__ pack){
  for(int i=blockIdx.x*blockDim.x+threadIdx.x;i<EI;i+=gridDim.x*blockDim.x){
    int s=ei[i], d=ei[EI+i];
    int sub=d>>5;
    int pos=off[sub]+atomicAdd(&cur[sub],1);
    pack[pos]=((s&31)<<9)|((d&31)<<4)|(ea[i]&15);
  }
}

// ---- sort each subgraph's edges by dst-lane
__global__ __launch_bounds__(128) void k_sortsub(const int* __restrict__ eoff, const int* __restrict__ ecnt,
                                                 int* __restrict__ epack){
  __shared__ int ein[512];
  __shared__ int eout[512];
  __shared__ int bcnt[32];
  __shared__ int bpos[32];
  int sub=blockIdx.x, t=threadIdx.x;
  int o=eoff[sub];
  int n=ecnt[sub]; if(n>512) n=512;
  for(int i=t;i<n;i+=128) ein[i]=epack[o+i];
  if(t<32) bcnt[t]=0;
  __syncthreads();
  for(int i=t;i<n;i+=128) atomicAdd(&bcnt[(ein[i]>>4)&31],1);
  __syncthreads();
  if(t==0){
    int s=0;
    for(int b=0;b<32;b++){ bpos[b]=s; s+=bcnt[b]; }
  }
  __syncthreads();
  for(int i=t;i<n;i+=128){
    int p=ein[i];
    int pos=atomicAdd(&bpos[(p>>4)&31],1);
    eout[pos]=p;
  }
  __syncthreads();
  for(int i=t;i<n;i+=128) epack[o+i]=eout[i];
}

__global__ void k_scatter_g(const int* __restrict__ ei, const int* __restrict__ ea,
                            const int* __restrict__ off, int* __restrict__ cur, int* __restrict__ pack){
  for(int i=blockIdx.x*blockDim.x+threadIdx.x;i<EG;i+=gridDim.x*blockDim.x){
    int s=ei[i], d=ei[EG+i];
    int pos=off[d]+atomicAdd(&cur[d],1);
    pack[pos]=(s<<4)|(ea[i]&15);
  }
}

// ---- rf = relu(rwse @ rwse_w + rwse_b)
__global__ __launch_bounds__(128) void k_rwse(const float* __restrict__ rwse, const float* __restrict__ w,
                      const float* __restrict__ b, float* __restrict__ rf){
  __shared__ float ws[16*128];
  __shared__ float rv[16];
  int n=blockIdx.x, c=threadIdx.x;
  for(int i=c;i<2048;i+=128) ws[i]=w[i];
  if(c<16) rv[c]=rwse[n*16+c];
  __syncthreads();
  float acc=b[c];
  for(int j=0;j<16;j++) acc=fmaf(rv[j],ws[j*128+c],acc);
  rf[(size_t)n*H+c]=fmaxf(acc,0.f);
}

// ---- h0
__global__ void k_h0(const float* __restrict__ atom, const float* __restrict__ rf,
                     const int* __restrict__ xids, const int* __restrict__ nids,
                     const int* __restrict__ valid, u16* __restrict__ h){
  int i=blockIdx.x*blockDim.x+threadIdx.x;
  if(i>=SKK*16) return;
  int r=i>>4, q=i&15;
  const float4* ap=(const float4*)(atom+(size_t)xids[r]*H)+q*2;
  const float4* bp=(const float4*)(rf+(size_t)nids[r]*H)+q*2;
  float4 a0=ap[0],a1=ap[1],b0=bp[0],b1=bp[1];
  float vm=valid[r]?1.f:0.f;
  float f[8]={(a0.x+b0.x)*vm,(a0.y+b0.y)*vm,(a0.z+b0.z)*vm,(a0.w+b0.w)*vm,
              (a1.x+b1.x)*vm,(a1.y+b1.y)*vm,(a1.z+b1.z)*vm,(a1.w+b1.w)*vm};
  ((uint4*)h)[i]=pk8(f);
}

// ==== FUSED: local GINE aggregation (2 subgraphs = 64 rows) + 2-GEMM MLP + stats
__global__ __launch_bounds__(256) void k_fused1(
    const u16* __restrict__ h, const u16* __restrict__ beb,
    const int* __restrict__ eoff, const int* __restrict__ ecnt, const int* __restrict__ epack,
    const float* __restrict__ epsp, int layer,
    const u16* __restrict__ W1p, const float* __restrict__ b1,
    const u16* __restrict__ W2p, const float* __restrict__ b2,
    u16* __restrict__ Xg, float* __restrict__ stats)
{
  __shared__ u16 hs[64*128];      // h rows, later reused as MLP intermediate T
  __shared__ u16 agx[64*128];     // swizzled: X_in, later final output staging
  __shared__ u16 bes[16*128];
  __shared__ int epk[2][128];
  __shared__ int nsh[2];
  __shared__ float sst[256];

  int t=threadIdx.x;
  int grp=t>>7, c=t&127;
  size_t hbase=(size_t)blockIdx.x*64*H;
  {
    const uint4* src=(const uint4*)(h+hbase);
    uint4* dst=(uint4*)hs;
    uint4 z=make_uint4(0,0,0,0);
    uint4* az=(uint4*)agx;
    #pragma unroll
    for(int i=0;i<4;i++){ dst[t+i*256]=src[t+i*256]; az[t+i*256]=z; }
    ((uint4*)bes)[t]=((const uint4*)beb)[t];
    sst[t]=0.f;
  }
  int sub=blockIdx.x*2+grp;
  int o=eoff[sub], n=ecnt[sub];
  if(c==0) nsh[grp]=n;
  __syncthreads();
  int nmax=max(nsh[0],nsh[1]);
  float acc=0.f; int cur=-1;
  for(int b0=0;b0<nmax;b0+=128){
    __syncthreads();
    if(b0+c<n) epk[grp][c]=epack[o+b0+c];
    __syncthreads();
    int lim=n-b0; if(lim>128) lim=128;
    for(int i=0;i<lim;i++){
      int p=epk[grp][i];
      int dl=(p>>4)&31;
      if(dl!=cur){
        if(cur>=0){
          int row=grp*32+cur;
          *(u16*)((char*)agx+(u32)row*256+(((u32)(2*c))^((u32)(row&7)<<4)))=f2b(acc);
        }
        acc=0.f; cur=dl;
      }
      acc+=fmaxf(b2f(hs[(grp*32+(p>>9))*128+c])+b2f(bes[(p&15)*128+c]),0.f);
    }
  }
  if(cur>=0){
    int row=grp*32+cur;
    *(u16*)((char*)agx+(u32)row*256+(((u32)(2*c))^((u32)(row&7)<<4)))=f2b(acc);
  }
  __syncthreads();
  // X_in = (1+eps)*h + agg  (in place in agx, swizzled)
  float ep=1.f+epsp[layer];
  #pragma unroll
  for(int r=0;r<32;r++){
    int row=grp*32+r;
    u16* ax=(u16*)((char*)agx+(u32)row*256+(((u32)(2*c))^((u32)(row&7)<<4)));
    *ax=f2b(fmaf(ep,b2f(hs[row*128+c]),b2f(*ax)));
  }
  __syncthreads();
  // ---- MLP: wave owns 16 rows
  int wave=t>>6, lane=t&63, lr=lane&15, lk=lane>>4;
  int rl=wave*16+lr;
  u32 rsw=((u32)(rl&7))<<4;
  f32x4 a1[8];
  #pragma unroll
  for(int n8=0;n8<8;n8++) a1[n8]=(f32x4){0.f,0.f,0.f,0.f};
  #pragma unroll
  for(int kc=0;kc<4;kc++){
    u32 cb=(u32)((kc*32+lk*8)*2);
    s16x8 bf=*(const s16x8*)((char*)agx+(u32)rl*256+(cb^rsw));
    #pragma unroll
    for(int n8=0;n8<8;n8++){
      s16x8 af=*(const s16x8*)(W1p+((n8*4+kc)<<9)+lane*8);
      a1[n8]=__builtin_amdgcn_mfma_f32_16x16x32_bf16(af,bf,a1[n8],0,0,0);
    }
  }
  // relu(+b1) -> hs (as T), wave-local rows
  #pragma unroll
  for(int n8=0;n8<8;n8++){
    int c0=n8*16+lk*4;
    float4 b4=*(const float4*)(b1+c0);
    float v[4]={fmaxf(a1[n8][0]+b4.x,0.f),fmaxf(a1[n8][1]+b4.y,0.f),
                fmaxf(a1[n8][2]+b4.z,0.f),fmaxf(a1[n8][3]+b4.w,0.f)};
    *(uint2*)((char*)hs+(u32)rl*256+(((u32)(2*c0))^rsw))=pk4(v);
  }
  // phase 2
  f32x4 a2[8];
  #pragma unroll
  for(int n8=0;n8<8;n8++) a2[n8]=(f32x4){0.f,0.f,0.f,0.f};
  #pragma unroll
  for(int kc=0;kc<4;kc++){
    u32 cb=(u32)((kc*32+lk*8)*2);
    s16x8 bf=*(const s16x8*)((char*)hs+(u32)rl*256+(cb^rsw));
    #pragma unroll
    for(int n8=0;n8<8;n8++){
      s16x8 af=*(const s16x8*)(W2p+((n8*4+kc)<<9)+lane*8);
      a2[n8]=__builtin_amdgcn_mfma_f32_16x16x32_bf16(af,bf,a2[n8],0,0,0);
    }
  }
  // epilogue: relu(+b2) -> agx (wave-local rows) + stats
  #pragma unroll
  for(int n8=0;n8<8;n8++){
    int c0=n8*16+lk*4;
    float4 b4=*(const float4*)(b2+c0);
    float v[4]={fmaxf(a2[n8][0]+b4.x,0.f),fmaxf(a2[n8][1]+b4.y,0.f),
                fmaxf(a2[n8][2]+b4.z,0.f),fmaxf(a2[n8][3]+b4.w,0.f)};
    *(uint2*)((char*)agx+(u32)rl*256+(((u32)(2*c0))^rsw))=pk4(v);
    float s[4],q[4];
    #pragma unroll
    for(int j=0;j<4;j++){ s[j]=v[j]; q[j]=v[j]*v[j]; }
    #pragma unroll
    for(int j=0;j<4;j++){
      #pragma unroll
      for(int d=1;d<16;d<<=1){
        s[j]+=__shfl_xor(s[j],d);
        q[j]+=__shfl_xor(q[j],d);
      }
    }
    if(lr==0){
      #pragma unroll
      for(int j=0;j<4;j++){
        atomicAdd(&sst[c0+j],s[j]);
        atomicAdd(&sst[128+c0+j],q[j]);
      }
    }
  }
  __syncthreads();
  // coalesced flush agx -> X
  uint4* out4=(uint4*)(Xg+hbase);
  #pragma unroll
  for(int p=0;p<4;p++){
    int i=t+p*256;
    u32 row=(u32)(i>>4), colb=(u32)((i&15)*16);
    out4[i]=*(const uint4*)((const char*)agx+row*256+(colb^((row&7)<<4)));
  }
  atomicAdd(&stats[t],sst[t]);
}

// ==== node-path MLP (64-row tile): out = relu(relu(A@W1+b1)@W2+b2) + stats
__global__ __launch_bounds__(256) void k_mlp2n(
    const u16* __restrict__ A, const u16* __restrict__ W1p, const float* __restrict__ b1,
    const u16* __restrict__ W2p, const float* __restrict__ b2,
    u16* __restrict__ out, float* __restrict__ stats)
{
  __shared__ u16 T[64*128];
  __shared__ float sst[256];
  int t=threadIdx.x;
  sst[t]=0.f;
  int wave=t>>6, lane=t&63, lr=lane&15, lk=lane>>4;
  int rl=wave*16+lr;
  u32 rsw=((u32)(rl&7))<<4;
  int row0=blockIdx.x*64;
  f32x4 a1[8];
  #pragma unroll
  for(int n8=0;n8<8;n8++) a1[n8]=(f32x4){0.f,0.f,0.f,0.f};
  const s16x8* B0=(const s16x8*)(A+(size_t)(row0+rl)*H);
  #pragma unroll
  for(int kc=0;kc<4;kc++){
    s16x8 bf=B0[kc*4+lk];
    #pragma unroll
    for(int n8=0;n8<8;n8++){
      s16x8 af=*(const s16x8*)(W1p+((n8*4+kc)<<9)+lane*8);
      a1[n8]=__builtin_amdgcn_mfma_f32_16x16x32_bf16(af,bf,a1[n8],0,0,0);
    }
  }
  #pragma unroll
  for(int n8=0;n8<8;n8++){
    int c0=n8*16+lk*4;
    float4 b4=*(const float4*)(b1+c0);
    float v[4]={fmaxf(a1[n8][0]+b4.x,0.f),fmaxf(a1[n8][1]+b4.y,0.f),
                fmaxf(a1[n8][2]+b4.z,0.f),fmaxf(a1[n8][3]+b4.w,0.f)};
    *(uint2*)((char*)T+(u32)rl*256+(((u32)(2*c0))^rsw))=pk4(v);
  }
  f32x4 a2[8];
  #pragma unroll
  for(int n8=0;n8<8;n8++) a2[n8]=(f32x4){0.f,0.f,0.f,0.f};
  #pragma unroll
  for(int kc=0;kc<4;kc++){
    u32 cb=(u32)((kc*32+lk*8)*2);
    s16x8 bf=*(const s16x8*)((char*)T+(u32)rl*256+(cb^rsw));
    #pragma unroll
    for(int n8=0;n8<8;n8++){
      s16x8 af=*(const s16x8*)(W2p+((n8*4+kc)<<9)+lane*8);
      a2[n8]=__builtin_amdgcn_mfma_f32_16x16x32_bf16(af,bf,a2[n8],0,0,0);
    }
  }
  #pragma unroll
  for(int n8=0;n8<8;n8++){
    int c0=n8*16+lk*4;
    float4 b4=*(const float4*)(b2+c0);
    float v[4]={fmaxf(a2[n8][0]+b4.x,0.f),fmaxf(a2[n8][1]+b4.y,0.f),
                fmaxf(a2[n8][2]+b4.z,0.f),fmaxf(a2[n8][3]+b4.w,0.f)};
    *(uint2*)((char*)T+(u32)rl*256+(((u32)(2*c0))^rsw))=pk4(v);
    float s[4],q[4];
    #pragma unroll
    for(int j=0;j<4;j++){ s[j]=v[j]; q[j]=v[j]*v[j]; }
    #pragma unroll
    for(int j=0;j<4;j++){
      #pragma unroll
      for(int d=1;d<16;d<<=1){
        s[j]+=__shfl_xor(s[j],d);
        q[j]+=__shfl_xor(q[j],d);
      }
    }
    if(lr==0){
      #pragma unroll
      for(int j=0;j<4;j++){
        atomicAdd(&sst[c0+j],s[j]);
        atomicAdd(&sst[128+c0+j],q[j]);
      }
    }
  }
  __syncthreads();
  uint4* out4=(uint4*)(out+(size_t)row0*H);
  #pragma unroll
  for(int p=0;p<4;p++){
    int i=t+p*256;
    u32 row=(u32)(i>>4), colb=(u32)((i&15)*16);
    out4[i]=*(const uint4*)((const char*)T+row*256+(colb^((row&7)<<4)));
  }
  atomicAdd(&stats[t],sst[t]);
}

// ==== plain MFMA GEMM (node path, 64-row tile): out = A@W
__global__ __launch_bounds__(256) void k_mgemm0(const u16* __restrict__ A, const u16* __restrict__ Wp,
                                                u16* __restrict__ out){
  int t=threadIdx.x;
  int wave=t>>6, lane=t&63, lr=lane&15, lk=lane>>4;
  int rl=wave*16+lr;
  int row0=blockIdx.x*64;
  f32x4 acc[8];
  #pragma unroll
  for(int n8=0;n8<8;n8++) acc[n8]=(f32x4){0.f,0.f,0.f,0.f};
  const s16x8* B0=(const s16x8*)(A+(size_t)(row0+rl)*H);
  #pragma unroll
  for(int kc=0;kc<4;kc++){
    s16x8 bf=B0[kc*4+lk];
    #pragma unroll
    for(int n8=0;n8<8;n8++){
      s16x8 af=*(const s16x8*)(Wp+((n8*4+kc)<<9)+lane*8);
      acc[n8]=__builtin_amdgcn_mfma_f32_16x16x32_bf16(af,bf,acc[n8],0,0,0);
    }
  }
  #pragma unroll
  for(int n8=0;n8<8;n8++){
    int c0=n8*16+lk*4;
    float v[4]={acc[n8][0],acc[n8][1],acc[n8][2],acc[n8][3]};
    *(uint2*)(out+(size_t)(row0+rl)*H+c0)=pk4(v);
  }
}

// ==== fused tail (64-row tile): h = (res + LN( gelu(X@W3+bias3+bb[node]) @ W2 + cb2 )) * valid
__global__ __launch_bounds__(256) void k_tail(
    const u16* __restrict__ X, const u16* __restrict__ W3p, const float* __restrict__ bias3,
    const u16* __restrict__ bb,
    const u16* __restrict__ W2p, const float* __restrict__ cb2,
    const float* __restrict__ lng, const float* __restrict__ lnb,
    const int* __restrict__ validv, u16* __restrict__ hio)
{
  __shared__ u16 T[64*128];
  int t=threadIdx.x;
  int wave=t>>6, lane=t&63, lr=lane&15, lk=lane>>4;
  int rl=wave*16+lr;
  u32 rsw=((u32)(rl&7))<<4;
  int row0=blockIdx.x*64;
  f32x4 acc[8];
  #pragma unroll
  for(int n8=0;n8<8;n8++) acc[n8]=(f32x4){0.f,0.f,0.f,0.f};
  const s16x8* B0=(const s16x8*)(X+(size_t)(row0+rl)*H);
  #pragma unroll
  for(int kc=0;kc<4;kc++){
    s16x8 bf=B0[kc*4+lk];
    #pragma unroll
    for(int n8=0;n8<8;n8++){
      s16x8 af=*(const s16x8*)(W3p+((n8*4+kc)<<9)+lane*8);
      acc[n8]=__builtin_amdgcn_mfma_f32_16x16x32_bf16(af,bf,acc[n8],0,0,0);
    }
  }
  // gelu(acc + bias3 + bb[node]) -> T  (node == blockIdx.x: 64 rows per node)
  #pragma unroll
  for(int n8=0;n8<8;n8++){
    int c0=n8*16+lk*4;
    float4 b4=*(const float4*)(bias3+c0);
    float rb[4];
    unp4(*(const uint2*)(bb+(size_t)blockIdx.x*H+c0),rb);
    float vb[4]={b4.x,b4.y,b4.z,b4.w};
    float v[4];
    #pragma unroll
    for(int j=0;j<4;j++){
      float x=acc[n8][j]+vb[j]+rb[j];
      v[j]=0.5f*x*(1.f+erff(x*0.70710678118654752f));
    }
    *(uint2*)((char*)T+(u32)rl*256+(((u32)(2*c0))^rsw))=pk4(v);
  }
  f32x4 a2[8];
  #pragma unroll
  for(int n8=0;n8<8;n8++) a2[n8]=(f32x4){0.f,0.f,0.f,0.f};
  #pragma unroll
  for(int kc=0;kc<4;kc++){
    u32 cb=(u32)((kc*32+lk*8)*2);
    s16x8 bf=*(const s16x8*)((char*)T+(u32)rl*256+(cb^rsw));
    #pragma unroll
    for(int n8=0;n8<8;n8++){
      s16x8 af=*(const s16x8*)(W2p+((n8*4+kc)<<9)+lane*8);
      a2[n8]=__builtin_amdgcn_mfma_f32_16x16x32_bf16(af,bf,a2[n8],0,0,0);
    }
  }
  // LN per row (sum over 4 lanes lk=0..3 via shfl 16,32)
  {
    float s=0.f,q=0.f;
    #pragma unroll
    for(int n8=0;n8<8;n8++){
      int c0=n8*16+lk*4;
      float4 b4=*(const float4*)(cb2+c0);
      float vb[4]={b4.x,b4.y,b4.z,b4.w};
      #pragma unroll
      for(int j=0;j<4;j++){
        float v=a2[n8][j]+vb[j];
        a2[n8][j]=v;
        s+=v; q+=v*v;
      }
    }
    s+=__shfl_xor(s,16); s+=__shfl_xor(s,32);
    q+=__shfl_xor(q,16); q+=__shfl_xor(q,32);
    float mu=s*(1.f/128.f);
    float rsig=rsqrtf(q*(1.f/128.f)-mu*mu+1e-5f);
    #pragma unroll
    for(int n8=0;n8<8;n8++){
      int c0=n8*16+lk*4;
      float4 g4=*(const float4*)(lng+c0);
      float4 e4=*(const float4*)(lnb+c0);
      float g[4]={g4.x,g4.y,g4.z,g4.w}, e[4]={e4.x,e4.y,e4.z,e4.w};
      float ov[4];
      #pragma unroll
      for(int j=0;j<4;j++) ov[j]=(a2[n8][j]-mu)*rsig*g[j]+e[j];
      *(uint2*)((char*)T+(u32)rl*256+(((u32)(2*c0))^rsw))=pk4(ov);
    }
  }
  __syncthreads();
  // coalesced flush with residual + valid (in-place h)
  uint4* hp=(uint4*)(hio+(size_t)row0*H);
  #pragma unroll
  for(int p=0;p<4;p++){
    int i=t+p*256;
    u32 row=(u32)(i>>4), colb=(u32)((i&15)*16);
    int grow=row0+(int)row;
    uint4 v=*(const uint4*)((const char*)T+row*256+(colb^((row&7)<<4)));
    uint4 r=hp[i];
    float vv[8],rv[8],o8[8];
    unp8(v,vv); unp8(r,rv);
    float vm=validv[grow]?1.f:0.f;
    #pragma unroll
    for(int j=0;j<8;j++) o8[j]=(rv[j]+vv[j])*vm;
    hp[i]=pk8(o8);
  }
}

// ---- h_node = mean of two root rows
__global__ void k_npool(const u16* __restrict__ h, u16* __restrict__ hn){
  int i=blockIdx.x*blockDim.x+threadIdx.x;
  if(i>=NN*16) return;
  int n=i>>4, q=i&15;
  const uint4* hp=(const uint4*)h;
  float a[8],b[8],o[8];
  unp8(hp[(size_t)n*1024+q],a);
  unp8(hp[(size_t)n*1024+512+q],b);
  #pragma unroll
  for(int e=0;e<8;e++) o[e]=(a[e]+b[e])*0.5f;
  ((uint4*)hn)[i]=pk8(o);
}

// ---- global GINE aggregation per node
__global__ __launch_bounds__(128) void k_gagg(const u16* __restrict__ hn, const float* __restrict__ be,
                      const int* __restrict__ goff, const int* __restrict__ gcnt,
                      const int* __restrict__ gpack, const float* __restrict__ epsp, int layer,
                      u16* __restrict__ hhg){
  __shared__ float bes[16][128];
  int n=blockIdx.x, c=threadIdx.x;
  for(int i=0;i<16;i++) bes[i][c]=be[i*128+c];
  __syncthreads();
  float acc=0.f;
  int o=goff[n], e=o+gcnt[n];
  for(;o<e;o++){
    int p=gpack[o];
    acc+=fmaxf(b2f(hn[(size_t)(p>>4)*H+c])+bes[p&15][c],0.f);
  }
  hhg[(size_t)n*H+c]=f2b(fmaf(1.f+epsp[layer],b2f(hn[(size_t)n*H+c]),acc));
}

// ---- h_node' = h_node + BN_affine(a_g)
__global__ void k_bnadd(const u16* __restrict__ hn, const u16* __restrict__ ag,
                        const float* __restrict__ stg, const float* __restrict__ gg,
                        const float* __restrict__ bg, u16* __restrict__ hn2){
  int i=blockIdx.x*blockDim.x+threadIdx.x;
  if(i>=NN*H) return;
  int c=i&127;
  float mu=stg[c]*(1.f/4096.f);
  float var=stg[128+c]*(1.f/4096.f)-mu*mu;
  float s=gg[c]*rsqrtf(var+1e-5f);
  float tt=bg[c]-mu*s;
  hn2[i]=f2b(b2f(hn[i])+fmaf(b2f(ag[i]),s,tt));
}

// ---- final pooling
__global__ __launch_bounds__(128) void k_pool(const u16* __restrict__ h, const int* __restrict__ valid,
                      const int* __restrict__ batch, float* __restrict__ oacc){
  __shared__ float cs[2];
  int n=blockIdx.x, c=threadIdx.x;
  if(c<2){
    int s=0;
    for(int j=0;j<32;j++) s+=valid[n*64+c*32+j];
    cs[c]=fmaxf((float)s,1.f);
  }
  __syncthreads();
  size_t base=(size_t)n*64*H;
  float a0=0.f,a1=0.f;
  for(int j=0;j<32;j++){
    a0+=b2f(h[base+(size_t)j*H+c]);
    a1+=b2f(h[base+(size_t)(32+j)*H+c]);
  }
  float nodef=0.5f*(a0/cs[0]+a1/cs[1]);
  atomicAdd(&oacc[batch[n]*H+c],nodef);
}

__global__ void k_out(const float* __restrict__ acc, const int* __restrict__ flag, void* __restrict__ out){
  int i=blockIdx.x*blockDim.x+threadIdx.x;
  if(i>=NGRAPH*H) return;
  if(*flag) ((__hip_bfloat16*)out)[i]=__float2bfloat16(acc[i]);
  else ((float*)out)[i]=acc[i];
}

extern "C" void kernel_launch(void* const* d_in, const int* in_sizes, int n_in,
                              void* d_out, int out_size, void* d_ws, size_t ws_size,
                              hipStream_t stream){
  (void)n_in; (void)out_size;
  int pofs[27]; pofs[0]=0;
  for(int i=0;i<26;i++) pofs[i+1]=pofs[i]+in_sizes[i];
  int ptot=pofs[26];

  char* wsb=(char*)d_ws;
  size_t off=0;
  auto alloc=[&](size_t bytes)->char*{ char* p=wsb+off; off+=(bytes+255)&~(size_t)255; return p; };
  int*   flag =(int*)  alloc(4);
  float* par  =(float*)alloc((size_t)ptot*4);
  u16*   h    =(u16*)  alloc((size_t)SKK*H*2);
  u16*   X    =(u16*)  alloc((size_t)SKK*H*2);
  u16*   wt   =(u16*)  alloc((size_t)28*HH*2);
  u16*   wt3  =(u16*)  alloc((size_t)HH*2);
  float* bias3=(float*)alloc(H*4);
  float* rf   =(float*)alloc((size_t)NN*H*4);
  u16*   bondb=(u16*)  alloc((size_t)16*H*2);
  u16*   hn   =(u16*)  alloc((size_t)NN*H*2);
  u16*   hhg  =(u16*)  alloc((size_t)NN*H*2);
  u16*   ag   =(u16*)  alloc((size_t)NN*H*2);
  u16*   hn2  =(u16*)  alloc((size_t)NN*H*2);
  u16*   bno  =(u16*)  alloc((size_t)NN*H*2);
  u16*   bb   =(u16*)  alloc((size_t)NN*H*2);
  // ---- contiguous zero-init region (one memset) ----
  int*   ecnt =(int*)  alloc(SS*4);
  int*   ecur =(int*)  alloc(SS*4);
  int*   gcnt =(int*)  alloc(NN*4);
  int*   gcur =(int*)  alloc(NN*4);
  float* stats=(float*)alloc(LNUM*512*4);
  float* oacc =(float*)alloc((size_t)NGRAPH*H*4);
  size_t zbytes=(size_t)SS*4+SS*4+NN*4+NN*4+LNUM*512*4+(size_t)NGRAPH*H*4;
  // ---- rest ----
  int* eoff =(int*)alloc(SS*4);
  int* epack=(int*)alloc((size_t)EI*4);
  int* goff =(int*)alloc(NN*4);
  int* gpack=(int*)alloc((size_t)EG*4);

  if(off>ws_size) return;

  const int* xids =(const int*)d_in[26];
  const int* iei  =(const int*)d_in[27];
  const int* iea  =(const int*)d_in[28];
  const int* gei  =(const int*)d_in[29];
  const int* gea  =(const int*)d_in[30];
  const int* nids =(const int*)d_in[31];
  const int* valid=(const int*)d_in[32];
  const int* batch=(const int*)d_in[33];

  const float* atom=par+pofs[0];
  const float* bond=par+pofs[1];
  const float* rw_w=par+pofs[2];
  const float* rw_b=par+pofs[3];
  const float* rwse=par+pofs[4];
  const float* leps=par+pofs[5];
  const float* lb1 =par+pofs[7];
  const float* lb2 =par+pofs[9];
  const float* lbng=par+pofs[10];
  const float* lbnb=par+pofs[11];
  const float* geps=par+pofs[12];
  const float* gb1 =par+pofs[14];
  const float* gb2 =par+pofs[16];
  const float* gbng=par+pofs[17];
  const float* gbnb=par+pofs[18];
  const float* cw1 =par+pofs[20];
  const float* cb1 =par+pofs[21];
  const float* cb2 =par+pofs[23];
  const float* lngp=par+pofs[24];
  const float* lnbp=par+pofs[25];

  k_sniff<<<1,256,0,stream>>>((const u16*)d_in[0], flag);
  CvtArgs ca;
  for(int i=0;i<26;i++){ ca.p[i]=d_in[i]; ca.start[i]=pofs[i]; }
  ca.start[26]=ptot;
  k_convert<<<1024,256,0,stream>>>(ca, flag, par);

  TransArgs ta;
  for(int l=0;l<LNUM;l++){
    ta.src[l*7+0]=pofs[6]+l*HH;           // lw1
    ta.src[l*7+1]=pofs[8]+l*HH;           // lw2
    ta.src[l*7+2]=pofs[13]+l*HH;          // gw1
    ta.src[l*7+3]=pofs[15]+l*HH;          // gw2
    ta.src[l*7+4]=pofs[19]+l*HH;          // bcw
    ta.src[l*7+5]=pofs[20]+l*2*HH+HH;     // cw1 bottom half
    ta.src[l*7+6]=pofs[22]+l*HH;          // cw2
  }
  k_trans<<<28,256,0,stream>>>(par, ta, wt);
  k_cvtbond<<<8,256,0,stream>>>(bond, bondb);

  (void)hipMemsetAsync(ecnt,0,zbytes,stream);

  k_hist<<<2048,256,0,stream>>>(iei+EI, EI, 5, ecnt);
  k_scan<<<1,1024,0,stream>>>(ecnt, eoff, SS);
  k_scatter_i<<<2048,256,0,stream>>>(iei, iea, eoff, ecur, epack);
  k_sortsub<<<SS,128,0,stream>>>(eoff, ecnt, epack);
  k_hist<<<512,256,0,stream>>>(gei+EG, EG, 0, gcnt);
  k_scan<<<1,1024,0,stream>>>(gcnt, goff, NN);
  k_scatter_g<<<512,256,0,stream>>>(gei, gea, goff, gcur, gpack);

  k_rwse<<<NN,128,0,stream>>>(rwse, rw_w, rw_b, rf);
  k_h0<<<(SKK*16)/256,256,0,stream>>>(atom, rf, xids, nids, valid, h);

  for(int l=0;l<LNUM;l++){
    float* stl_l=stats+l*512;
    float* stg_l=stats+l*512+256;
    k_fused1<<<SS/2,256,0,stream>>>(h, bondb, eoff, ecnt, epack, leps, l,
        wt+(size_t)(l*7+0)*HH, lb1+l*H, wt+(size_t)(l*7+1)*HH, lb2+l*H, X, stl_l);
    k_npool<<<(NN*16)/256,256,0,stream>>>(h, hn);
    k_gagg<<<NN,128,0,stream>>>(hn, bond, goff, gcnt, gpack, geps, l, hhg);
    k_mlp2n<<<NN/64,256,0,stream>>>(hhg, wt+(size_t)(l*7+2)*HH, gb1+l*H,
        wt+(size_t)(l*7+3)*HH, gb2+l*H, ag, stg_l);
    k_bnadd<<<(NN*H+255)/256,256,0,stream>>>(hn, ag, stg_l, gbng+l*H, gbnb+l*H, hn2);
    k_mgemm0<<<NN/64,256,0,stream>>>(hn2, wt+(size_t)(l*7+4)*HH, bno);
    k_mgemm0<<<NN/64,256,0,stream>>>(bno, wt+(size_t)(l*7+5)*HH, bb);
    k_prepw3<<<128,128,0,stream>>>(cw1+(size_t)l*2*HH, cb1+l*H, stl_l, lbng+l*H, lbnb+l*H, wt3, bias3);
    k_tail<<<SKK/64,256,0,stream>>>(X, wt3, bias3, bb,
        wt+(size_t)(l*7+6)*HH, cb2+l*H, lngp+l*H, lnbp+l*H, valid, h);
  }
  k_pool<<<NN,128,0,stream>>>(h, valid, batch, oacc);
  k_out<<<(NGRAPH*H+255)/256,256,0,stream>>>(oacc, flag, d_out);
}

// Round 9
// 1281.825 us; speedup vs baseline: 3.3825x; 1.1612x over previous
//
#include <hip/hip_runtime.h>
#include <hip/hip_bf16.h>

#define H 128
#define HH 16384
#define LNUM 4
#define NN 4096
#define SS 8192
#define SKK 262144
#define EI 1048576
#define EG 65536
#define NGRAPH 64

typedef unsigned short u16;
typedef unsigned int u32;
typedef __attribute__((ext_vector_type(8))) short s16x8;
typedef __attribute__((ext_vector_type(4))) float f32x4;

__device__ __forceinline__ float b2f(u32 u){ return __uint_as_float(u<<16); }
__device__ __forceinline__ u16 f2b(float f){
  union { __hip_bfloat16 b; u16 u; } x;
  x.b=__float2bfloat16(f);
  return x.u;
}
__device__ __forceinline__ void unp8(uint4 v, float* f){
  f[0]=b2f(v.x&0xFFFF); f[1]=b2f(v.x>>16);
  f[2]=b2f(v.y&0xFFFF); f[3]=b2f(v.y>>16);
  f[4]=b2f(v.z&0xFFFF); f[5]=b2f(v.z>>16);
  f[6]=b2f(v.w&0xFFFF); f[7]=b2f(v.w>>16);
}
__device__ __forceinline__ void unp4(uint2 v, float* f){
  f[0]=b2f(v.x&0xFFFF); f[1]=b2f(v.x>>16);
  f[2]=b2f(v.y&0xFFFF); f[3]=b2f(v.y>>16);
}
__device__ __forceinline__ uint4 pk8(const float* f){
  uint4 r;
  r.x=(u32)f2b(f[0])|((u32)f2b(f[1])<<16);
  r.y=(u32)f2b(f[2])|((u32)f2b(f[3])<<16);
  r.z=(u32)f2b(f[4])|((u32)f2b(f[5])<<16);
  r.w=(u32)f2b(f[6])|((u32)f2b(f[7])<<16);
  return r;
}
__device__ __forceinline__ uint2 pk4(const float* f){
  uint2 r;
  r.x=(u32)f2b(f[0])|((u32)f2b(f[1])<<16);
  r.y=(u32)f2b(f[2])|((u32)f2b(f[3])<<16);
  return r;
}

struct CvtArgs {
  const void* p[26];
  int start[27];
};
struct TransArgs { int src[28]; };

// ---- dtype sniff
__global__ void k_sniff(const u16* __restrict__ a, int* __restrict__ flag){
  __shared__ int cnt;
  if(threadIdx.x==0) cnt=0;
  __syncthreads();
  int big=0;
  for(int i=threadIdx.x;i<2048;i+=256){
    int e=(a[i]>>7)&0xFF;
    if(e>=127) big++;
  }
  atomicAdd(&cnt,big);
  __syncthreads();
  if(threadIdx.x==0) *flag=(cnt<16)?1:0;
}

__global__ void k_convert(CvtArgs args, const int* __restrict__ flag, float* __restrict__ dst){
  int fl=*flag;
  int total=args.start[26];
  for(int i=blockIdx.x*blockDim.x+threadIdx.x;i<total;i+=gridDim.x*blockDim.x){
    int a=0;
    while(args.start[a+1]<=i) a++;
    int j=i-args.start[a];
    float v;
    if(fl) v=b2f(((const u16*)args.p[a])[j]);
    else   v=((const float*)args.p[a])[j];
    dst[i]=v;
  }
}

// ---- static weights: f32 [K][N] -> bf16 fragment-major packed
__global__ __launch_bounds__(256) void k_trans(const float* __restrict__ par, TransArgs ta, u16* __restrict__ wt){
  const float* s=par+ta.src[blockIdx.x];
  u16* d=wt+(size_t)blockIdx.x*HH;
  for(int i=threadIdx.x;i<HH;i+=256){
    int j=i&7, lane=(i>>3)&63, fc=i>>9;
    int n=fc>>2, kc=fc&3, lr=lane&15, lk=lane>>4;
    int outc=n*16+lr, k=kc*32+lk*8+j;
    d[i]=f2b(s[(size_t)k*H+outc]);
  }
}

// ---- bond emb f32 -> bf16
__global__ void k_cvtbond(const float* __restrict__ b, u16* __restrict__ bb){
  int i=blockIdx.x*blockDim.x+threadIdx.x;
  if(i<16*H) bb[i]=f2b(b[i]);
}

// ---- fold local-BN affine into cw1_top, packed output
__global__ __launch_bounds__(128) void k_prepw3(const float* __restrict__ w, const float* __restrict__ cb1,
                        const float* __restrict__ stl, const float* __restrict__ gl, const float* __restrict__ bl,
                        u16* __restrict__ wt3p, float* __restrict__ bias3){
  __shared__ float red[128];
  int c=blockIdx.x, k=threadIdx.x;
  float mu=stl[k]*(1.f/262144.f);
  float var=stl[128+k]*(1.f/262144.f)-mu*mu;
  float s=gl[k]*rsqrtf(var+1e-5f);
  float tt=bl[k]-mu*s;
  float wv=w[(size_t)k*H+c];
  int idx=(((c>>4)*4+(k>>5))*64+((k>>3)&3)*16+(c&15))*8+(k&7);
  wt3p[idx]=f2b(s*wv);
  red[k]=tt*wv;
  __syncthreads();
  for(int d=64;d>0;d>>=1){ if(k<d) red[k]+=red[k+d]; __syncthreads(); }
  if(k==0) bias3[c]=cb1[c]+red[0];
}

// ---- edge bucketing
__global__ void k_hist(const int* __restrict__ idx, int n, int shift, int* __restrict__ cnt){
  for(int i=blockIdx.x*blockDim.x+threadIdx.x;i<n;i+=gridDim.x*blockDim.x)
    atomicAdd(&cnt[idx[i]>>shift],1);
}

__global__ void k_scan(const int* __restrict__ cnt, int* __restrict__ off, int nbins){
  __shared__ int ts[1024];
  int t=threadIdx.x;
  int per=nbins>>10;
  int base=t*per;
  int s=0;
  for(int j=0;j<per;j++) s+=cnt[base+j];
  ts[t]=s;
  __syncthreads();
  for(int d=1;d<1024;d<<=1){
    int v=(t>=d)?ts[t-d]:0;
    __syncthreads();
    ts[t]+=v;
    __syncthreads();
  }
  int ex=(t==0)?0:ts[t-1];
  for(int j=0;j<per;j++){ off[base+j]=ex; ex+=cnt[base+j]; }
}

__global__ void k_scatter_i(const int* __restrict__ ei, const int* __restrict__ ea,
                            const int* __restrict__ off, int* __restrict__ cur, int* __restrict__ pack){
  for(int i=blockIdx.x*blockDim.x+threadIdx.x;i<EI;i+=gridDim.x*blockDim.x){
    int s=ei[i], d=ei[EI+i];
    int sub=d>>5;
    int pos=off[sub]+atomicAdd(&cur[sub],1);
    pack[pos]=((s&31)<<9)|((d&31)<<4)|(ea[i]&15);
  }
}

// ---- sort each subgraph's edges by dst-lane; persist per-dst segment starts
__global__ __launch_bounds__(128) void k_sortsub(const int* __restrict__ eoff, const int* __restrict__ ecnt,
                                                 int* __restrict__ epack, int* __restrict__ dstoff){
  __shared__ int ein[512];
  __shared__ int eout[512];
  __shared__ int bcnt[32];
  __shared__ int bpos[32];
  int sub=blockIdx.x, t=threadIdx.x;
  int o=eoff[sub];
  int n=ecnt[sub]; if(n>512) n=512;
  for(int i=t;i<n;i+=128) ein[i]=epack[o+i];
  if(t<32) bcnt[t]=0;
  __syncthreads();
  for(int i=t;i<n;i+=128) atomicAdd(&bcnt[(ein[i]>>4)&31],1);
  __syncthreads();
  if(t==0){
    int s=0;
    for(int b=0;b<32;b++){ bpos[b]=s; s+=bcnt[b]; }
  }
  __syncthreads();
  if(t<32) dstoff[sub*32+t]=bpos[t];
  __syncthreads();
  for(int i=t;i<n;i+=128){
    int p=ein[i];
    int pos=atomicAdd(&bpos[(p>>4)&31],1);
    eout[pos]=p;
  }
  __syncthreads();
  for(int i=t;i<n;i+=128) epack[o+i]=eout[i];
}

__global__ void k_scatter_g(const int* __restrict__ ei, const int* __restrict__ ea,
                            const int* __restrict__ off, int* __restrict__ cur, int* __restrict__ pack){
  for(int i=blockIdx.x*blockDim.x+threadIdx.x;i<EG;i+=gridDim.x*blockDim.x){
    int s=ei[i], d=ei[EG+i];
    int pos=off[d]+atomicAdd(&cur[d],1);
    pack[pos]=(s<<4)|(ea[i]&15);
  }
}

// ---- rf = relu(rwse @ rwse_w + rwse_b)
__global__ __launch_bounds__(128) void k_rwse(const float* __restrict__ rwse, const float* __restrict__ w,
                      const float* __restrict__ b, float* __restrict__ rf){
  __shared__ float ws[16*128];
  __shared__ float rv[16];
  int n=blockIdx.x, c=threadIdx.x;
  for(int i=c;i<2048;i+=128) ws[i]=w[i];
  if(c<16) rv[c]=rwse[n*16+c];
  __syncthreads();
  float acc=b[c];
  for(int j=0;j<16;j++) acc=fmaf(rv[j],ws[j*128+c],acc);
  rf[(size_t)n*H+c]=fmaxf(acc,0.f);
}

// ---- h0
__global__ void k_h0(const float* __restrict__ atom, const float* __restrict__ rf,
                     const int* __restrict__ xids, const int* __restrict__ nids,
                     const int* __restrict__ valid, u16* __restrict__ h){
  int i=blockIdx.x*blockDim.x+threadIdx.x;
  if(i>=SKK*16) return;
  int r=i>>4, q=i&15;
  const float4* ap=(const float4*)(atom+(size_t)xids[r]*H)+q*2;
  const float4* bp=(const float4*)(rf+(size_t)nids[r]*H)+q*2;
  float4 a0=ap[0],a1=ap[1],b0=bp[0],b1=bp[1];
  float vm=valid[r]?1.f:0.f;
  float f[8]={(a0.x+b0.x)*vm,(a0.y+b0.y)*vm,(a0.z+b0.z)*vm,(a0.w+b0.w)*vm,
              (a1.x+b1.x)*vm,(a1.y+b1.y)*vm,(a1.z+b1.z)*vm,(a1.w+b1.w)*vm};
  ((uint4*)h)[i]=pk8(f);
}

// ==== FUSED: segment-parallel local GINE agg (2 subgraphs) + 2-GEMM MLP + stats
__global__ __launch_bounds__(256) void k_fused1(
    const u16* __restrict__ h, const u16* __restrict__ beb,
    const int* __restrict__ eoff, const int* __restrict__ ecnt, const int* __restrict__ epack,
    const int* __restrict__ dstoff,
    const float* __restrict__ epsp, int layer,
    const u16* __restrict__ W1p, const float* __restrict__ b1,
    const u16* __restrict__ W2p, const float* __restrict__ b2,
    u16* __restrict__ Xg, float* __restrict__ stats)
{
  __shared__ u16 hs[64*128];      // swizzled h; reused as MLP intermediate T
  __shared__ u16 agx[64*128];     // swizzled X_in / output staging
  __shared__ u16 bes[16*128];     // swizzled bond emb
  __shared__ int epk[2][512];
  __shared__ int doff[2][32];
  __shared__ int nsh[2];
  __shared__ float sst[256];

  int t=threadIdx.x;
  int grp=t>>7, c=t&127;
  size_t hbase=(size_t)blockIdx.x*64*H;
  {
    const uint4* src=(const uint4*)(h+hbase);
    #pragma unroll
    for(int i0=0;i0<4;i0++){
      int i=t+i0*256;
      u32 row=(u32)(i>>4), colb=(u32)((i&15)*16);
      *(uint4*)((char*)hs+row*256+(colb^((row&7)<<4)))=src[i];
    }
    u32 row=(u32)(t>>4), colb=(u32)((t&15)*16);
    *(uint4*)((char*)bes+row*256+(colb^((row&7)<<4)))=((const uint4*)beb)[t];
    sst[t]=0.f;
  }
  int sub=blockIdx.x*2+grp;
  if(c==0) nsh[grp]=min(ecnt[sub],512);
  if(c<32) doff[grp][c]=dstoff[sub*32+c];
  __syncthreads();
  int n=nsh[grp];
  int o=eoff[sub];
  for(int i=c;i<n;i+=128) epk[grp][i]=epack[o+i];
  __syncthreads();
  // slot=c>>4 owns dst rows slot*4..+3; chg=c&15 owns channels chg*8..+7
  int slot=c>>4, chg=c&15;
  u32 cbyte=(u32)chg*16;
  float ep=1.f+epsp[layer];
  #pragma unroll
  for(int k=0;k<4;k++){
    int d=slot*4+k;
    int s0=doff[grp][d];
    int s1=(d==31)?n:doff[grp][d+1];
    float acc[8]={0.f,0.f,0.f,0.f,0.f,0.f,0.f,0.f};
    for(int i=s0;i<s1;i++){
      int p=epk[grp][i];
      u32 srow=(u32)(grp*32+(p>>9));
      u32 erow=(u32)(p&15);
      float hf[8],bf8[8];
      unp8(*(const uint4*)((const char*)hs+srow*256+(cbyte^((srow&7)<<4))),hf);
      unp8(*(const uint4*)((const char*)bes+erow*256+(cbyte^((erow&7)<<4))),bf8);
      #pragma unroll
      for(int j=0;j<8;j++) acc[j]+=fmaxf(hf[j]+bf8[j],0.f);
    }
    u32 drow=(u32)(grp*32+d);
    float hf[8],o8[8];
    unp8(*(const uint4*)((const char*)hs+drow*256+(cbyte^((drow&7)<<4))),hf);
    #pragma unroll
    for(int j=0;j<8;j++) o8[j]=fmaf(ep,hf[j],acc[j]);
    *(uint4*)((char*)agx+drow*256+(cbyte^((drow&7)<<4)))=pk8(o8);
  }
  __syncthreads();
  // ---- MLP: wave owns 16 rows
  int wave=t>>6, lane=t&63, lr=lane&15, lk=lane>>4;
  int rl=wave*16+lr;
  u32 rsw=((u32)(rl&7))<<4;
  f32x4 a1[8];
  #pragma unroll
  for(int n8=0;n8<8;n8++) a1[n8]=(f32x4){0.f,0.f,0.f,0.f};
  #pragma unroll
  for(int kc=0;kc<4;kc++){
    u32 cb=(u32)((kc*32+lk*8)*2);
    s16x8 bf=*(const s16x8*)((char*)agx+(u32)rl*256+(cb^rsw));
    #pragma unroll
    for(int n8=0;n8<8;n8++){
      s16x8 af=*(const s16x8*)(W1p+((n8*4+kc)<<9)+lane*8);
      a1[n8]=__builtin_amdgcn_mfma_f32_16x16x32_bf16(af,bf,a1[n8],0,0,0);
    }
  }
  #pragma unroll
  for(int n8=0;n8<8;n8++){
    int c0=n8*16+lk*4;
    float4 b4=*(const float4*)(b1+c0);
    float v[4]={fmaxf(a1[n8][0]+b4.x,0.f),fmaxf(a1[n8][1]+b4.y,0.f),
                fmaxf(a1[n8][2]+b4.z,0.f),fmaxf(a1[n8][3]+b4.w,0.f)};
    *(uint2*)((char*)hs+(u32)rl*256+(((u32)(2*c0))^rsw))=pk4(v);
  }
  f32x4 a2[8];
  #pragma unroll
  for(int n8=0;n8<8;n8++) a2[n8]=(f32x4){0.f,0.f,0.f,0.f};
  #pragma unroll
  for(int kc=0;kc<4;kc++){
    u32 cb=(u32)((kc*32+lk*8)*2);
    s16x8 bf=*(const s16x8*)((char*)hs+(u32)rl*256+(cb^rsw));
    #pragma unroll
    for(int n8=0;n8<8;n8++){
      s16x8 af=*(const s16x8*)(W2p+((n8*4+kc)<<9)+lane*8);
      a2[n8]=__builtin_amdgcn_mfma_f32_16x16x32_bf16(af,bf,a2[n8],0,0,0);
    }
  }
  #pragma unroll
  for(int n8=0;n8<8;n8++){
    int c0=n8*16+lk*4;
    float4 b4=*(const float4*)(b2+c0);
    float v[4]={fmaxf(a2[n8][0]+b4.x,0.f),fmaxf(a2[n8][1]+b4.y,0.f),
                fmaxf(a2[n8][2]+b4.z,0.f),fmaxf(a2[n8][3]+b4.w,0.f)};
    *(uint2*)((char*)agx+(u32)rl*256+(((u32)(2*c0))^rsw))=pk4(v);
    float s[4],q[4];
    #pragma unroll
    for(int j=0;j<4;j++){ s[j]=v[j]; q[j]=v[j]*v[j]; }
    #pragma unroll
    for(int j=0;j<4;j++){
      #pragma unroll
      for(int d=1;d<16;d<<=1){
        s[j]+=__shfl_xor(s[j],d);
        q[j]+=__shfl_xor(q[j],d);
      }
    }
    if(lr==0){
      #pragma unroll
      for(int j=0;j<4;j++){
        atomicAdd(&sst[c0+j],s[j]);
        atomicAdd(&sst[128+c0+j],q[j]);
      }
    }
  }
  __syncthreads();
  uint4* out4=(uint4*)(Xg+hbase);
  #pragma unroll
  for(int p=0;p<4;p++){
    int i=t+p*256;
    u32 row=(u32)(i>>4), colb=(u32)((i&15)*16);
    out4[i]=*(const uint4*)((const char*)agx+row*256+(colb^((row&7)<<4)));
  }
  atomicAdd(&stats[t],sst[t]);
}

// ==== node-path MLP (64-row tile): out = relu(relu(A@W1+b1)@W2+b2) + stats
__global__ __launch_bounds__(256) void k_mlp2n(
    const u16* __restrict__ A, const u16* __restrict__ W1p, const float* __restrict__ b1,
    const u16* __restrict__ W2p, const float* __restrict__ b2,
    u16* __restrict__ out, float* __restrict__ stats)
{
  __shared__ u16 T[64*128];
  __shared__ float sst[256];
  int t=threadIdx.x;
  sst[t]=0.f;
  int wave=t>>6, lane=t&63, lr=lane&15, lk=lane>>4;
  int rl=wave*16+lr;
  u32 rsw=((u32)(rl&7))<<4;
  int row0=blockIdx.x*64;
  f32x4 a1[8];
  #pragma unroll
  for(int n8=0;n8<8;n8++) a1[n8]=(f32x4){0.f,0.f,0.f,0.f};
  const s16x8* B0=(const s16x8*)(A+(size_t)(row0+rl)*H);
  #pragma unroll
  for(int kc=0;kc<4;kc++){
    s16x8 bf=B0[kc*4+lk];
    #pragma unroll
    for(int n8=0;n8<8;n8++){
      s16x8 af=*(const s16x8*)(W1p+((n8*4+kc)<<9)+lane*8);
      a1[n8]=__builtin_amdgcn_mfma_f32_16x16x32_bf16(af,bf,a1[n8],0,0,0);
    }
  }
  #pragma unroll
  for(int n8=0;n8<8;n8++){
    int c0=n8*16+lk*4;
    float4 b4=*(const float4*)(b1+c0);
    float v[4]={fmaxf(a1[n8][0]+b4.x,0.f),fmaxf(a1[n8][1]+b4.y,0.f),
                fmaxf(a1[n8][2]+b4.z,0.f),fmaxf(a1[n8][3]+b4.w,0.f)};
    *(uint2*)((char*)T+(u32)rl*256+(((u32)(2*c0))^rsw))=pk4(v);
  }
  f32x4 a2[8];
  #pragma unroll
  for(int n8=0;n8<8;n8++) a2[n8]=(f32x4){0.f,0.f,0.f,0.f};
  #pragma unroll
  for(int kc=0;kc<4;kc++){
    u32 cb=(u32)((kc*32+lk*8)*2);
    s16x8 bf=*(const s16x8*)((char*)T+(u32)rl*256+(cb^rsw));
    #pragma unroll
    for(int n8=0;n8<8;n8++){
      s16x8 af=*(const s16x8*)(W2p+((n8*4+kc)<<9)+lane*8);
      a2[n8]=__builtin_amdgcn_mfma_f32_16x16x32_bf16(af,bf,a2[n8],0,0,0);
    }
  }
  #pragma unroll
  for(int n8=0;n8<8;n8++){
    int c0=n8*16+lk*4;
    float4 b4=*(const float4*)(b2+c0);
    float v[4]={fmaxf(a2[n8][0]+b4.x,0.f),fmaxf(a2[n8][1]+b4.y,0.f),
                fmaxf(a2[n8][2]+b4.z,0.f),fmaxf(a2[n8][3]+b4.w,0.f)};
    *(uint2*)((char*)T+(u32)rl*256+(((u32)(2*c0))^rsw))=pk4(v);
    float s[4],q[4];
    #pragma unroll
    for(int j=0;j<4;j++){ s[j]=v[j]; q[j]=v[j]*v[j]; }
    #pragma unroll
    for(int j=0;j<4;j++){
      #pragma unroll
      for(int d=1;d<16;d<<=1){
        s[j]+=__shfl_xor(s[j],d);
        q[j]+=__shfl_xor(q[j],d);
      }
    }
    if(lr==0){
      #pragma unroll
      for(int j=0;j<4;j++){
        atomicAdd(&sst[c0+j],s[j]);
        atomicAdd(&sst[128+c0+j],q[j]);
      }
    }
  }
  __syncthreads();
  uint4* out4=(uint4*)(out+(size_t)row0*H);
  #pragma unroll
  for(int p=0;p<4;p++){
    int i=t+p*256;
    u32 row=(u32)(i>>4), colb=(u32)((i&15)*16);
    out4[i]=*(const uint4*)((const char*)T+row*256+(colb^((row&7)<<4)));
  }
  atomicAdd(&stats[t],sst[t]);
}

// ==== fused node broadcast: bb = ((hn + BN(ag)) @ bcw) @ cw1_bot
__global__ __launch_bounds__(256) void k_bcast(
    const u16* __restrict__ hn, const u16* __restrict__ ag,
    const float* __restrict__ stg, const float* __restrict__ gg, const float* __restrict__ bg,
    const u16* __restrict__ Wbcp, const u16* __restrict__ Wc1p,
    u16* __restrict__ bb)
{
  __shared__ u16 T[64*128];
  __shared__ u16 T2[64*128];
  __shared__ float ssh[128], tsh[128];
  int t=threadIdx.x;
  int row0=blockIdx.x*64;
  if(t<128){
    float mu=stg[t]*(1.f/4096.f);
    float var=stg[128+t]*(1.f/4096.f)-mu*mu;
    float s=gg[t]*rsqrtf(var+1e-5f);
    ssh[t]=s; tsh[t]=bg[t]-mu*s;
  }
  __syncthreads();
  #pragma unroll
  for(int i0=0;i0<4;i0++){
    int i=t+i0*256;
    u32 row=(u32)(i>>4);
    int cb8=(i&15)*8;
    float hv[8],av[8],o8[8];
    unp8(((const uint4*)(hn+(size_t)row0*H))[i],hv);
    unp8(((const uint4*)(ag+(size_t)row0*H))[i],av);
    #pragma unroll
    for(int j=0;j<8;j++) o8[j]=hv[j]+fmaf(av[j],ssh[cb8+j],tsh[cb8+j]);
    *(uint4*)((char*)T+row*256+(((u32)(cb8*2))^((row&7)<<4)))=pk8(o8);
  }
  __syncthreads();
  int wave=t>>6, lane=t&63, lr=lane&15, lk=lane>>4;
  int rl=wave*16+lr;
  u32 rsw=((u32)(rl&7))<<4;
  f32x4 a1[8];
  #pragma unroll
  for(int n8=0;n8<8;n8++) a1[n8]=(f32x4){0.f,0.f,0.f,0.f};
  #pragma unroll
  for(int kc=0;kc<4;kc++){
    u32 cb=(u32)((kc*32+lk*8)*2);
    s16x8 bf=*(const s16x8*)((char*)T+(u32)rl*256+(cb^rsw));
    #pragma unroll
    for(int n8=0;n8<8;n8++){
      s16x8 af=*(const s16x8*)(Wbcp+((n8*4+kc)<<9)+lane*8);
      a1[n8]=__builtin_amdgcn_mfma_f32_16x16x32_bf16(af,bf,a1[n8],0,0,0);
    }
  }
  #pragma unroll
  for(int n8=0;n8<8;n8++){
    int c0=n8*16+lk*4;
    float v[4]={a1[n8][0],a1[n8][1],a1[n8][2],a1[n8][3]};
    *(uint2*)((char*)T2+(u32)rl*256+(((u32)(2*c0))^rsw))=pk4(v);
  }
  f32x4 a2[8];
  #pragma unroll
  for(int n8=0;n8<8;n8++) a2[n8]=(f32x4){0.f,0.f,0.f,0.f};
  #pragma unroll
  for(int kc=0;kc<4;kc++){
    u32 cb=(u32)((kc*32+lk*8)*2);
    s16x8 bf=*(const s16x8*)((char*)T2+(u32)rl*256+(cb^rsw));
    #pragma unroll
    for(int n8=0;n8<8;n8++){
      s16x8 af=*(const s16x8*)(Wc1p+((n8*4+kc)<<9)+lane*8);
      a2[n8]=__builtin_amdgcn_mfma_f32_16x16x32_bf16(af,bf,a2[n8],0,0,0);
    }
  }
  #pragma unroll
  for(int n8=0;n8<8;n8++){
    int c0=n8*16+lk*4;
    float v[4]={a2[n8][0],a2[n8][1],a2[n8][2],a2[n8][3]};
    *(uint2*)((char*)T+(u32)rl*256+(((u32)(2*c0))^rsw))=pk4(v);
  }
  __syncthreads();
  uint4* out4=(uint4*)(bb+(size_t)row0*H);
  #pragma unroll
  for(int p=0;p<4;p++){
    int i=t+p*256;
    u32 row=(u32)(i>>4), colb=(u32)((i&15)*16);
    out4[i]=*(const uint4*)((const char*)T+row*256+(colb^((row&7)<<4)));
  }
}

// ==== fused tail (64-row tile): h = (res + LN( gelu(X@W3+bias3+bb[node]) @ W2 + cb2 )) * valid
__global__ __launch_bounds__(256) void k_tail(
    const u16* __restrict__ X, const u16* __restrict__ W3p, const float* __restrict__ bias3,
    const u16* __restrict__ bb,
    const u16* __restrict__ W2p, const float* __restrict__ cb2,
    const float* __restrict__ lng, const float* __restrict__ lnb,
    const int* __restrict__ validv, u16* __restrict__ hio)
{
  __shared__ u16 T[64*128];
  int t=threadIdx.x;
  int wave=t>>6, lane=t&63, lr=lane&15, lk=lane>>4;
  int rl=wave*16+lr;
  u32 rsw=((u32)(rl&7))<<4;
  int row0=blockIdx.x*64;
  f32x4 acc[8];
  #pragma unroll
  for(int n8=0;n8<8;n8++) acc[n8]=(f32x4){0.f,0.f,0.f,0.f};
  const s16x8* B0=(const s16x8*)(X+(size_t)(row0+rl)*H);
  #pragma unroll
  for(int kc=0;kc<4;kc++){
    s16x8 bf=B0[kc*4+lk];
    #pragma unroll
    for(int n8=0;n8<8;n8++){
      s16x8 af=*(const s16x8*)(W3p+((n8*4+kc)<<9)+lane*8);
      acc[n8]=__builtin_amdgcn_mfma_f32_16x16x32_bf16(af,bf,acc[n8],0,0,0);
    }
  }
  #pragma unroll
  for(int n8=0;n8<8;n8++){
    int c0=n8*16+lk*4;
    float4 b4=*(const float4*)(bias3+c0);
    float rb[4];
    unp4(*(const uint2*)(bb+(size_t)blockIdx.x*H+c0),rb);
    float vb[4]={b4.x,b4.y,b4.z,b4.w};
    float v[4];
    #pragma unroll
    for(int j=0;j<4;j++){
      float x=acc[n8][j]+vb[j]+rb[j];
      v[j]=0.5f*x*(1.f+erff(x*0.70710678118654752f));
    }
    *(uint2*)((char*)T+(u32)rl*256+(((u32)(2*c0))^rsw))=pk4(v);
  }
  f32x4 a2[8];
  #pragma unroll
  for(int n8=0;n8<8;n8++) a2[n8]=(f32x4){0.f,0.f,0.f,0.f};
  #pragma unroll
  for(int kc=0;kc<4;kc++){
    u32 cb=(u32)((kc*32+lk*8)*2);
    s16x8 bf=*(const s16x8*)((char*)T+(u32)rl*256+(cb^rsw));
    #pragma unroll
    for(int n8=0;n8<8;n8++){
      s16x8 af=*(const s16x8*)(W2p+((n8*4+kc)<<9)+lane*8);
      a2[n8]=__builtin_amdgcn_mfma_f32_16x16x32_bf16(af,bf,a2[n8],0,0,0);
    }
  }
  {
    float s=0.f,q=0.f;
    #pragma unroll
    for(int n8=0;n8<8;n8++){
      int c0=n8*16+lk*4;
      float4 b4=*(const float4*)(cb2+c0);
      float vb[4]={b4.x,b4.y,b4.z,b4.w};
      #pragma unroll
      for(int j=0;j<4;j++){
        float v=a2[n8][j]+vb[j];
        a2[n8][j]=v;
        s+=v; q+=v*v;
      }
    }
    s+=__shfl_xor(s,16); s+=__shfl_xor(s,32);
    q+=__shfl_xor(q,16); q+=__shfl_xor(q,32);
    float mu=s*(1.f/128.f);
    float rsig=rsqrtf(q*(1.f/128.f)-mu*mu+1e-5f);
    #pragma unroll
    for(int n8=0;n8<8;n8++){
      int c0=n8*16+lk*4;
      float4 g4=*(const float4*)(lng+c0);
      float4 e4=*(const float4*)(lnb+c0);
      float g[4]={g4.x,g4.y,g4.z,g4.w}, e[4]={e4.x,e4.y,e4.z,e4.w};
      float ov[4];
      #pragma unroll
      for(int j=0;j<4;j++) ov[j]=(a2[n8][j]-mu)*rsig*g[j]+e[j];
      *(uint2*)((char*)T+(u32)rl*256+(((u32)(2*c0))^rsw))=pk4(ov);
    }
  }
  __syncthreads();
  uint4* hp=(uint4*)(hio+(size_t)row0*H);
  #pragma unroll
  for(int p=0;p<4;p++){
    int i=t+p*256;
    u32 row=(u32)(i>>4), colb=(u32)((i&15)*16);
    int grow=row0+(int)row;
    uint4 v=*(const uint4*)((const char*)T+row*256+(colb^((row&7)<<4)));
    uint4 r=hp[i];
    float vv[8],rv[8],o8[8];
    unp8(v,vv); unp8(r,rv);
    float vm=validv[grow]?1.f:0.f;
    #pragma unroll
    for(int j=0;j<8;j++) o8[j]=(rv[j]+vv[j])*vm;
    hp[i]=pk8(o8);
  }
}

// ---- h_node = mean of two root rows
__global__ void k_npool(const u16* __restrict__ h, u16* __restrict__ hn){
  int i=blockIdx.x*blockDim.x+threadIdx.x;
  if(i>=NN*16) return;
  int n=i>>4, q=i&15;
  const uint4* hp=(const uint4*)h;
  float a[8],b[8],o[8];
  unp8(hp[(size_t)n*1024+q],a);
  unp8(hp[(size_t)n*1024+512+q],b);
  #pragma unroll
  for(int e=0;e<8;e++) o[e]=(a[e]+b[e])*0.5f;
  ((uint4*)hn)[i]=pk8(o);
}

// ---- global GINE aggregation per node
__global__ __launch_bounds__(128) void k_gagg(const u16* __restrict__ hn, const float* __restrict__ be,
                      const int* __restrict__ goff, const int* __restrict__ gcnt,
                      const int* __restrict__ gpack, const float* __restrict__ epsp, int layer,
                      u16* __restrict__ hhg){
  __shared__ float bes[16][128];
  int n=blockIdx.x, c=threadIdx.x;
  for(int i=0;i<16;i++) bes[i][c]=be[i*128+c];
  __syncthreads();
  float acc=0.f;
  int o=goff[n], e=o+gcnt[n];
  for(;o<e;o++){
    int p=gpack[o];
    acc+=fmaxf(b2f(hn[(size_t)(p>>4)*H+c])+bes[p&15][c],0.f);
  }
  hhg[(size_t)n*H+c]=f2b(fmaf(1.f+epsp[layer],b2f(hn[(size_t)n*H+c]),acc));
}

// ---- final pooling
__global__ __launch_bounds__(128) void k_pool(const u16* __restrict__ h, const int* __restrict__ valid,
                      const int* __restrict__ batch, float* __restrict__ oacc){
  __shared__ float cs[2];
  int n=blockIdx.x, c=threadIdx.x;
  if(c<2){
    int s=0;
    for(int j=0;j<32;j++) s+=valid[n*64+c*32+j];
    cs[c]=fmaxf((float)s,1.f);
  }
  __syncthreads();
  size_t base=(size_t)n*64*H;
  float a0=0.f,a1=0.f;
  for(int j=0;j<32;j++){
    a0+=b2f(h[base+(size_t)j*H+c]);
    a1+=b2f(h[base+(size_t)(32+j)*H+c]);
  }
  float nodef=0.5f*(a0/cs[0]+a1/cs[1]);
  atomicAdd(&oacc[batch[n]*H+c],nodef);
}

__global__ void k_out(const float* __restrict__ acc, const int* __restrict__ flag, void* __restrict__ out){
  int i=blockIdx.x*blockDim.x+threadIdx.x;
  if(i>=NGRAPH*H) return;
  if(*flag) ((__hip_bfloat16*)out)[i]=__float2bfloat16(acc[i]);
  else ((float*)out)[i]=acc[i];
}

extern "C" void kernel_launch(void* const* d_in, const int* in_sizes, int n_in,
                              void* d_out, int out_size, void* d_ws, size_t ws_size,
                              hipStream_t stream){
  (void)n_in; (void)out_size;
  int pofs[27]; pofs[0]=0;
  for(int i=0;i<26;i++) pofs[i+1]=pofs[i]+in_sizes[i];
  int ptot=pofs[26];

  char* wsb=(char*)d_ws;
  size_t off=0;
  auto alloc=[&](size_t bytes)->char*{ char* p=wsb+off; off+=(bytes+255)&~(size_t)255; return p; };
  int*   flag =(int*)  alloc(4);
  float* par  =(float*)alloc((size_t)ptot*4);
  u16*   h    =(u16*)  alloc((size_t)SKK*H*2);
  u16*   X    =(u16*)  alloc((size_t)SKK*H*2);
  u16*   wt   =(u16*)  alloc((size_t)28*HH*2);
  u16*   wt3  =(u16*)  alloc((size_t)HH*2);
  float* bias3=(float*)alloc(H*4);
  float* rf   =(float*)alloc((size_t)NN*H*4);
  u16*   bondb=(u16*)  alloc((size_t)16*H*2);
  u16*   hn   =(u16*)  alloc((size_t)NN*H*2);
  u16*   hhg  =(u16*)  alloc((size_t)NN*H*2);
  u16*   ag   =(u16*)  alloc((size_t)NN*H*2);
  u16*   bb   =(u16*)  alloc((size_t)NN*H*2);
  // ---- contiguous zero-init region (one memset) ----
  int*   ecnt =(int*)  alloc(SS*4);
  int*   ecur =(int*)  alloc(SS*4);
  int*   gcnt =(int*)  alloc(NN*4);
  int*   gcur =(int*)  alloc(NN*4);
  float* stats=(float*)alloc(LNUM*512*4);
  float* oacc =(float*)alloc((size_t)NGRAPH*H*4);
  size_t zbytes=(size_t)SS*4+SS*4+NN*4+NN*4+LNUM*512*4+(size_t)NGRAPH*H*4;
  // ---- rest ----
  int* eoff  =(int*)alloc(SS*4);
  int* epack =(int*)alloc((size_t)EI*4);
  int* dstoff=(int*)alloc((size_t)SS*32*4);
  int* goff  =(int*)alloc(NN*4);
  int* gpack =(int*)alloc((size_t)EG*4);

  if(off>ws_size) return;

  const int* xids =(const int*)d_in[26];
  const int* iei  =(const int*)d_in[27];
  const int* iea  =(const int*)d_in[28];
  const int* gei  =(const int*)d_in[29];
  const int* gea  =(const int*)d_in[30];
  const int* nids =(const int*)d_in[31];
  const int* valid=(const int*)d_in[32];
  const int* batch=(const int*)d_in[33];

  const float* atom=par+pofs[0];
  const float* bond=par+pofs[1];
  const float* rw_w=par+pofs[2];
  const float* rw_b=par+pofs[3];
  const float* rwse=par+pofs[4];
  const float* leps=par+pofs[5];
  const float* lb1 =par+pofs[7];
  const float* lb2 =par+pofs[9];
  const float* lbng=par+pofs[10];
  const float* lbnb=par+pofs[11];
  const float* geps=par+pofs[12];
  const float* gb1 =par+pofs[14];
  const float* gb2 =par+pofs[16];
  const float* gbng=par+pofs[17];
  const float* gbnb=par+pofs[18];
  const float* cw1 =par+pofs[20];
  const float* cb1 =par+pofs[21];
  const float* cb2 =par+pofs[23];
  const float* lngp=par+pofs[24];
  const float* lnbp=par+pofs[25];

  k_sniff<<<1,256,0,stream>>>((const u16*)d_in[0], flag);
  CvtArgs ca;
  for(int i=0;i<26;i++){ ca.p[i]=d_in[i]; ca.start[i]=pofs[i]; }
  ca.start[26]=ptot;
  k_convert<<<1024,256,0,stream>>>(ca, flag, par);

  TransArgs ta;
  for(int l=0;l<LNUM;l++){
    ta.src[l*7+0]=pofs[6]+l*HH;           // lw1
    ta.src[l*7+1]=pofs[8]+l*HH;           // lw2
    ta.src[l*7+2]=pofs[13]+l*HH;          // gw1
    ta.src[l*7+3]=pofs[15]+l*HH;          // gw2
    ta.src[l*7+4]=pofs[19]+l*HH;          // bcw
    ta.src[l*7+5]=pofs[20]+l*2*HH+HH;     // cw1 bottom half
    ta.src[l*7+6]=pofs[22]+l*HH;          // cw2
  }
  k_trans<<<28,256,0,stream>>>(par, ta, wt);
  k_cvtbond<<<8,256,0,stream>>>(bond, bondb);

  (void)hipMemsetAsync(ecnt,0,zbytes,stream);

  k_hist<<<2048,256,0,stream>>>(iei+EI, EI, 5, ecnt);
  k_scan<<<1,1024,0,stream>>>(ecnt, eoff, SS);
  k_scatter_i<<<2048,256,0,stream>>>(iei, iea, eoff, ecur, epack);
  k_sortsub<<<SS,128,0,stream>>>(eoff, ecnt, epack, dstoff);
  k_hist<<<512,256,0,stream>>>(gei+EG, EG, 0, gcnt);
  k_scan<<<1,1024,0,stream>>>(gcnt, goff, NN);
  k_scatter_g<<<512,256,0,stream>>>(gei, gea, goff, gcur, gpack);

  k_rwse<<<NN,128,0,stream>>>(rwse, rw_w, rw_b, rf);
  k_h0<<<(SKK*16)/256,256,0,stream>>>(atom, rf, xids, nids, valid, h);

  for(int l=0;l<LNUM;l++){
    float* stl_l=stats+l*512;
    float* stg_l=stats+l*512+256;
    k_fused1<<<SS/2,256,0,stream>>>(h, bondb, eoff, ecnt, epack, dstoff, leps, l,
        wt+(size_t)(l*7+0)*HH, lb1+l*H, wt+(size_t)(l*7+1)*HH, lb2+l*H, X, stl_l);
    k_npool<<<(NN*16)/256,256,0,stream>>>(h, hn);
    k_gagg<<<NN,128,0,stream>>>(hn, bond, goff, gcnt, gpack, geps, l, hhg);
    k_mlp2n<<<NN/64,256,0,stream>>>(hhg, wt+(size_t)(l*7+2)*HH, gb1+l*H,
        wt+(size_t)(l*7+3)*HH, gb2+l*H, ag, stg_l);
    k_bcast<<<NN/64,256,0,stream>>>(hn, ag, stg_l, gbng+l*H, gbnb+l*H,
        wt+(size_t)(l*7+4)*HH, wt+(size_t)(l*7+5)*HH, bb);
    k_prepw3<<<128,128,0,stream>>>(cw1+(size_t)l*2*HH, cb1+l*H, stl_l, lbng+l*H, lbnb+l*H, wt3, bias3);
    k_tail<<<SKK/64,256,0,stream>>>(X, wt3, bias3, bb,
        wt+(size_t)(l*7+6)*HH, cb2+l*H, lngp+l*H, lnbp+l*H, valid, h);
  }
  k_pool<<<NN,128,0,stream>>>(h, valid, batch, oacc);
  k_out<<<(NGRAPH*H+255)/256,256,0,stream>>>(oacc, flag, d_out);
}

// Round 10
// 1218.696 us; speedup vs baseline: 3.5577x; 1.0518x over previous
//
#include <hip/hip_runtime.h>
#include <hip/hip_bf16.h>

#define H 128
#define HH 16384
#define LNUM 4
#define NN 4096
#define SS 8192
#define SKK 262144
#define EI 1048576
#define EG 65536
#define NGRAPH 64

typedef unsigned short u16;
typedef unsigned int u32;
typedef __attribute__((ext_vector_type(8))) short s16x8;
typedef __attribute__((ext_vector_type(4))) float f32x4;

__device__ __forceinline__ float b2f(u32 u){ return __uint_as_float(u<<16); }
__device__ __forceinline__ u16 f2b(float f){
  union { __hip_bfloat16 b; u16 u; } x;
  x.b=__float2bfloat16(f);
  return x.u;
}
__device__ __forceinline__ void unp8(uint4 v, float* f){
  f[0]=b2f(v.x&0xFFFF); f[1]=b2f(v.x>>16);
  f[2]=b2f(v.y&0xFFFF); f[3]=b2f(v.y>>16);
  f[4]=b2f(v.z&0xFFFF); f[5]=b2f(v.z>>16);
  f[6]=b2f(v.w&0xFFFF); f[7]=b2f(v.w>>16);
}
__device__ __forceinline__ void unp4(uint2 v, float* f){
  f[0]=b2f(v.x&0xFFFF); f[1]=b2f(v.x>>16);
  f[2]=b2f(v.y&0xFFFF); f[3]=b2f(v.y>>16);
}
__device__ __forceinline__ uint4 pk8(const float* f){
  uint4 r;
  r.x=(u32)f2b(f[0])|((u32)f2b(f[1])<<16);
  r.y=(u32)f2b(f[2])|((u32)f2b(f[3])<<16);
  r.z=(u32)f2b(f[4])|((u32)f2b(f[5])<<16);
  r.w=(u32)f2b(f[6])|((u32)f2b(f[7])<<16);
  return r;
}
__device__ __forceinline__ uint2 pk4(const float* f){
  uint2 r;
  r.x=(u32)f2b(f[0])|((u32)f2b(f[1])<<16);
  r.y=(u32)f2b(f[2])|((u32)f2b(f[3])<<16);
  return r;
}

struct CvtArgs {
  const void* p[26];
  int start[27];
};
struct TransArgs { int src[28]; };

// ---- dtype sniff
__global__ void k_sniff(const u16* __restrict__ a, int* __restrict__ flag){
  __shared__ int cnt;
  if(threadIdx.x==0) cnt=0;
  __syncthreads();
  int big=0;
  for(int i=threadIdx.x;i<2048;i+=256){
    int e=(a[i]>>7)&0xFF;
    if(e>=127) big++;
  }
  atomicAdd(&cnt,big);
  __syncthreads();
  if(threadIdx.x==0) *flag=(cnt<16)?1:0;
}

__global__ void k_convert(CvtArgs args, const int* __restrict__ flag, float* __restrict__ dst){
  int fl=*flag;
  int total=args.start[26];
  for(int i=blockIdx.x*blockDim.x+threadIdx.x;i<total;i+=gridDim.x*blockDim.x){
    int a=0;
    while(args.start[a+1]<=i) a++;
    int j=i-args.start[a];
    float v;
    if(fl) v=b2f(((const u16*)args.p[a])[j]);
    else   v=((const float*)args.p[a])[j];
    dst[i]=v;
  }
}

// ---- static weights: f32 [K][N] -> bf16 fragment-major packed
__global__ __launch_bounds__(256) void k_trans(const float* __restrict__ par, TransArgs ta, u16* __restrict__ wt){
  const float* s=par+ta.src[blockIdx.x];
  u16* d=wt+(size_t)blockIdx.x*HH;
  for(int i=threadIdx.x;i<HH;i+=256){
    int j=i&7, lane=(i>>3)&63, fc=i>>9;
    int n=fc>>2, kc=fc&3, lr=lane&15, lk=lane>>4;
    int outc=n*16+lr, k=kc*32+lk*8+j;
    d[i]=f2b(s[(size_t)k*H+outc]);
  }
}

// ---- bond emb f32 -> bf16
__global__ void k_cvtbond(const float* __restrict__ b, u16* __restrict__ bb){
  int i=blockIdx.x*blockDim.x+threadIdx.x;
  if(i<16*H) bb[i]=f2b(b[i]);
}

// ---- fold local-BN affine into cw1_top, packed output
__global__ __launch_bounds__(128) void k_prepw3(const float* __restrict__ w, const float* __restrict__ cb1,
                        const float* __restrict__ stl, const float* __restrict__ gl, const float* __restrict__ bl,
                        u16* __restrict__ wt3p, float* __restrict__ bias3){
  __shared__ float red[128];
  int c=blockIdx.x, k=threadIdx.x;
  float mu=stl[k]*(1.f/262144.f);
  float var=stl[128+k]*(1.f/262144.f)-mu*mu;
  float s=gl[k]*rsqrtf(var+1e-5f);
  float tt=bl[k]-mu*s;
  float wv=w[(size_t)k*H+c];
  int idx=(((c>>4)*4+(k>>5))*64+((k>>3)&3)*16+(c&15))*8+(k&7);
  wt3p[idx]=f2b(s*wv);
  red[k]=tt*wv;
  __syncthreads();
  for(int d=64;d>0;d>>=1){ if(k<d) red[k]+=red[k+d]; __syncthreads(); }
  if(k==0) bias3[c]=cb1[c]+red[0];
}

// ---- edge bucketing
__global__ void k_hist(const int* __restrict__ idx, int n, int shift, int* __restrict__ cnt){
  for(int i=blockIdx.x*blockDim.x+threadIdx.x;i<n;i+=gridDim.x*blockDim.x)
    atomicAdd(&cnt[idx[i]>>shift],1);
}

__global__ void k_scan(const int* __restrict__ cnt, int* __restrict__ off, int nbins){
  __shared__ int ts[1024];
  int t=threadIdx.x;
  int per=nbins>>10;
  int base=t*per;
  int s=0;
  for(int j=0;j<per;j++) s+=cnt[base+j];
  ts[t]=s;
  __syncthreads();
  for(int d=1;d<1024;d<<=1){
    int v=(t>=d)?ts[t-d]:0;
    __syncthreads();
    ts[t]+=v;
    __syncthreads();
  }
  int ex=(t==0)?0:ts[t-1];
  for(int j=0;j<per;j++){ off[base+j]=ex; ex+=cnt[base+j]; }
}

__global__ void k_scatter_i(const int* __restrict__ ei, const int* __restrict__ ea,
                            const int* __restrict__ off, int* __restrict__ cur, int* __restrict__ pack){
  for(int i=blockIdx.x*blockDim.x+threadIdx.x;i<EI;i+=gridDim.x*blockDim.x){
    int s=ei[i], d=ei[EI+i];
    int sub=d>>5;
    int pos=off[sub]+atomicAdd(&cur[sub],1);
    pack[pos]=((s&31)<<9)|((d&31)<<4)|(ea[i]&15);
  }
}

// ---- sort each subgraph's edges by dst-lane; persist per-dst segment starts
__global__ __launch_bounds__(128) void k_sortsub(const int* __restrict__ eoff, const int* __restrict__ ecnt,
                                                 int* __restrict__ epack, int* __restrict__ dstoff){
  __shared__ int ein[512];
  __shared__ int eout[512];
  __shared__ int bcnt[32];
  __shared__ int bpos[32];
  int sub=blockIdx.x, t=threadIdx.x;
  int o=eoff[sub];
  int n=ecnt[sub]; if(n>512) n=512;
  for(int i=t;i<n;i+=128) ein[i]=epack[o+i];
  if(t<32) bcnt[t]=0;
  __syncthreads();
  for(int i=t;i<n;i+=128) atomicAdd(&bcnt[(ein[i]>>4)&31],1);
  __syncthreads();
  if(t==0){
    int s=0;
    for(int b=0;b<32;b++){ bpos[b]=s; s+=bcnt[b]; }
  }
  __syncthreads();
  if(t<32) dstoff[sub*32+t]=bpos[t];
  __syncthreads();
  for(int i=t;i<n;i+=128){
    int p=ein[i];
    int pos=atomicAdd(&bpos[(p>>4)&31],1);
    eout[pos]=p;
  }
  __syncthreads();
  for(int i=t;i<n;i+=128) epack[o+i]=eout[i];
}

__global__ void k_scatter_g(const int* __restrict__ ei, const int* __restrict__ ea,
                            const int* __restrict__ off, int* __restrict__ cur, int* __restrict__ pack){
  for(int i=blockIdx.x*blockDim.x+threadIdx.x;i<EG;i+=gridDim.x*blockDim.x){
    int s=ei[i], d=ei[EG+i];
    int pos=off[d]+atomicAdd(&cur[d],1);
    pack[pos]=(s<<4)|(ea[i]&15);
  }
}

// ---- rf = relu(rwse @ rwse_w + rwse_b)
__global__ __launch_bounds__(128) void k_rwse(const float* __restrict__ rwse, const float* __restrict__ w,
                      const float* __restrict__ b, float* __restrict__ rf){
  __shared__ float ws[16*128];
  __shared__ float rv[16];
  int n=blockIdx.x, c=threadIdx.x;
  for(int i=c;i<2048;i+=128) ws[i]=w[i];
  if(c<16) rv[c]=rwse[n*16+c];
  __syncthreads();
  float acc=b[c];
  for(int j=0;j<16;j++) acc=fmaf(rv[j],ws[j*128+c],acc);
  rf[(size_t)n*H+c]=fmaxf(acc,0.f);
}

// ---- h0
__global__ void k_h0(const float* __restrict__ atom, const float* __restrict__ rf,
                     const int* __restrict__ xids, const int* __restrict__ nids,
                     const int* __restrict__ valid, u16* __restrict__ h){
  int i=blockIdx.x*blockDim.x+threadIdx.x;
  if(i>=SKK*16) return;
  int r=i>>4, q=i&15;
  const float4* ap=(const float4*)(atom+(size_t)xids[r]*H)+q*2;
  const float4* bp=(const float4*)(rf+(size_t)nids[r]*H)+q*2;
  float4 a0=ap[0],a1=ap[1],b0=bp[0],b1=bp[1];
  float vm=valid[r]?1.f:0.f;
  float f[8]={(a0.x+b0.x)*vm,(a0.y+b0.y)*vm,(a0.z+b0.z)*vm,(a0.w+b0.w)*vm,
              (a1.x+b1.x)*vm,(a1.y+b1.y)*vm,(a1.z+b1.z)*vm,(a1.w+b1.w)*vm};
  ((uint4*)h)[i]=pk8(f);
}

// ==== FUSED mega-kernel:
//  TAIL=1: first apply prev-layer tail to this block's 64 rows:
//          h = (h + LN(gelu(X@W3+bias3+bbv[node]) @ Wc2 + cb2)) * valid   (h kept in LDS)
//  then: segment-parallel local GINE agg + 2-GEMM MLP + stats -> X (in-place)
template<int TAIL>
__global__ __launch_bounds__(256) void k_fused1(
    const u16* __restrict__ h, const u16* __restrict__ beb,
    const int* __restrict__ eoff, const int* __restrict__ ecnt, const int* __restrict__ epack,
    const int* __restrict__ dstoff,
    const float* __restrict__ epsp, int layer,
    const u16* __restrict__ W1p, const float* __restrict__ b1,
    const u16* __restrict__ W2p, const float* __restrict__ b2,
    u16* __restrict__ Xg, float* __restrict__ stats,
    const u16* __restrict__ W3p, const float* __restrict__ bias3,
    const u16* __restrict__ bbv,
    const u16* __restrict__ Wc2p, const float* __restrict__ cb2,
    const float* __restrict__ lng, const float* __restrict__ lnb,
    const int* __restrict__ validv, u16* __restrict__ hio)
{
  __shared__ u16 hs[64*128];      // swizzled h; later MLP intermediate
  __shared__ u16 agx[64*128];     // tail T / X_in / output staging
  __shared__ u16 bes[16*128];
  __shared__ int epk[2][512];
  __shared__ int doff[2][32];
  __shared__ float sst[256];

  int t=threadIdx.x;
  int grp=t>>7, c=t&127;
  size_t hbase=(size_t)blockIdx.x*64*H;
  int wave=t>>6, lane=t&63, lr=lane&15, lk=lane>>4;
  int rl=wave*16+lr;
  u32 rsw=((u32)(rl&7))<<4;
  int row0=blockIdx.x*64;

  // early staging: bond emb, edge metadata (global loads overlap tail compute)
  {
    u32 row=(u32)(t>>4), colb=(u32)((t&15)*16);
    *(uint4*)((char*)bes+row*256+(colb^((row&7)<<4)))=((const uint4*)beb)[t];
    sst[t]=0.f;
  }
  int sub=blockIdx.x*2+grp;
  int n=min(ecnt[sub],512);
  int o=eoff[sub];
  if(c<32) doff[grp][c]=dstoff[sub*32+c];
  for(int i=c;i<n;i+=128) epk[grp][i]=epack[o+i];

  if(TAIL){
    // ---- tail phase 1: gelu(X@W3 + bias3 + bbv[node]) -> agx
    f32x4 a1t[8];
    #pragma unroll
    for(int n8=0;n8<8;n8++) a1t[n8]=(f32x4){0.f,0.f,0.f,0.f};
    const s16x8* B0=(const s16x8*)(Xg+(size_t)(row0+rl)*H);
    #pragma unroll
    for(int kc=0;kc<4;kc++){
      s16x8 bf=B0[kc*4+lk];
      #pragma unroll
      for(int n8=0;n8<8;n8++){
        s16x8 af=*(const s16x8*)(W3p+((n8*4+kc)<<9)+lane*8);
        a1t[n8]=__builtin_amdgcn_mfma_f32_16x16x32_bf16(af,bf,a1t[n8],0,0,0);
      }
    }
    #pragma unroll
    for(int n8=0;n8<8;n8++){
      int c0=n8*16+lk*4;
      float4 b4=*(const float4*)(bias3+c0);
      float rb[4];
      unp4(*(const uint2*)(bbv+(size_t)blockIdx.x*H+c0),rb);
      float vb[4]={b4.x,b4.y,b4.z,b4.w};
      float v[4];
      #pragma unroll
      for(int j=0;j<4;j++){
        float x=a1t[n8][j]+vb[j]+rb[j];
        v[j]=0.5f*x*(1.f+erff(x*0.70710678118654752f));
      }
      *(uint2*)((char*)agx+(u32)rl*256+(((u32)(2*c0))^rsw))=pk4(v);
    }
    // ---- tail phase 2: @Wc2 + LN -> agx
    f32x4 a2t[8];
    #pragma unroll
    for(int n8=0;n8<8;n8++) a2t[n8]=(f32x4){0.f,0.f,0.f,0.f};
    #pragma unroll
    for(int kc=0;kc<4;kc++){
      u32 cb=(u32)((kc*32+lk*8)*2);
      s16x8 bf=*(const s16x8*)((char*)agx+(u32)rl*256+(cb^rsw));
      #pragma unroll
      for(int n8=0;n8<8;n8++){
        s16x8 af=*(const s16x8*)(Wc2p+((n8*4+kc)<<9)+lane*8);
        a2t[n8]=__builtin_amdgcn_mfma_f32_16x16x32_bf16(af,bf,a2t[n8],0,0,0);
      }
    }
    {
      float s=0.f,q=0.f;
      #pragma unroll
      for(int n8=0;n8<8;n8++){
        int c0=n8*16+lk*4;
        float4 b4=*(const float4*)(cb2+c0);
        float vb[4]={b4.x,b4.y,b4.z,b4.w};
        #pragma unroll
        for(int j=0;j<4;j++){
          float v=a2t[n8][j]+vb[j];
          a2t[n8][j]=v;
          s+=v; q+=v*v;
        }
      }
      s+=__shfl_xor(s,16); s+=__shfl_xor(s,32);
      q+=__shfl_xor(q,16); q+=__shfl_xor(q,32);
      float mu=s*(1.f/128.f);
      float rsig=rsqrtf(q*(1.f/128.f)-mu*mu+1e-5f);
      #pragma unroll
      for(int n8=0;n8<8;n8++){
        int c0=n8*16+lk*4;
        float4 g4=*(const float4*)(lng+c0);
        float4 e4=*(const float4*)(lnb+c0);
        float g[4]={g4.x,g4.y,g4.z,g4.w}, e[4]={e4.x,e4.y,e4.z,e4.w};
        float ov[4];
        #pragma unroll
        for(int j=0;j<4;j++) ov[j]=(a2t[n8][j]-mu)*rsig*g[j]+e[j];
        *(uint2*)((char*)agx+(u32)rl*256+(((u32)(2*c0))^rsw))=pk4(ov);
      }
    }
    __syncthreads();
    // ---- flush: h_new = (h_old + LN)*valid -> global h AND hs (swizzled)
    uint4* hp=(uint4*)(hio+hbase);
    #pragma unroll
    for(int p=0;p<4;p++){
      int i=t+p*256;
      u32 row=(u32)(i>>4), colb=(u32)((i&15)*16);
      int grow=row0+(int)row;
      uint4 v=*(const uint4*)((const char*)agx+row*256+(colb^((row&7)<<4)));
      uint4 r=hp[i];
      float vv[8],rv[8],o8[8];
      unp8(v,vv); unp8(r,rv);
      float vm=validv[grow]?1.f:0.f;
      #pragma unroll
      for(int j=0;j<8;j++) o8[j]=(rv[j]+vv[j])*vm;
      uint4 pk=pk8(o8);
      hp[i]=pk;
      *(uint4*)((char*)hs+row*256+(colb^((row&7)<<4)))=pk;
    }
  } else {
    const uint4* src=(const uint4*)(h+hbase);
    #pragma unroll
    for(int i0=0;i0<4;i0++){
      int i=t+i0*256;
      u32 row=(u32)(i>>4), colb=(u32)((i&15)*16);
      *(uint4*)((char*)hs+row*256+(colb^((row&7)<<4)))=src[i];
    }
  }
  __syncthreads();

  // ---- segment-parallel aggregation (1-deep software pipeline)
  {
    int slot=c>>4, chg=c&15;
    u32 cbyte=(u32)chg*16;
    float ep=1.f+epsp[layer];
    #pragma unroll
    for(int k=0;k<4;k++){
      int d=slot*4+k;
      int s0=doff[grp][d];
      int s1=(d==31)?n:doff[grp][d+1];
      float acc[8]={0.f,0.f,0.f,0.f,0.f,0.f,0.f,0.f};
      if(s0<s1){
        int p=epk[grp][s0];
        u32 srow=(u32)(grp*32+(p>>9));
        u32 erow=(u32)(p&15);
        uint4 hv=*(const uint4*)((const char*)hs+srow*256+(cbyte^((srow&7)<<4)));
        uint4 bv=*(const uint4*)((const char*)bes+erow*256+(cbyte^((erow&7)<<4)));
        for(int i=s0+1;i<s1;i++){
          int p2=epk[grp][i];
          u32 srow2=(u32)(grp*32+(p2>>9));
          u32 erow2=(u32)(p2&15);
          uint4 hv2=*(const uint4*)((const char*)hs+srow2*256+(cbyte^((srow2&7)<<4)));
          uint4 bv2=*(const uint4*)((const char*)bes+erow2*256+(cbyte^((erow2&7)<<4)));
          float hf[8],bf8[8];
          unp8(hv,hf); unp8(bv,bf8);
          #pragma unroll
          for(int j=0;j<8;j++) acc[j]+=fmaxf(hf[j]+bf8[j],0.f);
          hv=hv2; bv=bv2;
        }
        float hf[8],bf8[8];
        unp8(hv,hf); unp8(bv,bf8);
        #pragma unroll
        for(int j=0;j<8;j++) acc[j]+=fmaxf(hf[j]+bf8[j],0.f);
      }
      u32 drow=(u32)(grp*32+d);
      float hf[8],o8[8];
      unp8(*(const uint4*)((const char*)hs+drow*256+(cbyte^((drow&7)<<4))),hf);
      #pragma unroll
      for(int j=0;j<8;j++) o8[j]=fmaf(ep,hf[j],acc[j]);
      *(uint4*)((char*)agx+drow*256+(cbyte^((drow&7)<<4)))=pk8(o8);
    }
  }
  __syncthreads();

  // ---- MLP phase 1: relu(X_in@W1+b1) -> hs
  f32x4 a1[8];
  #pragma unroll
  for(int n8=0;n8<8;n8++) a1[n8]=(f32x4){0.f,0.f,0.f,0.f};
  #pragma unroll
  for(int kc=0;kc<4;kc++){
    u32 cb=(u32)((kc*32+lk*8)*2);
    s16x8 bf=*(const s16x8*)((char*)agx+(u32)rl*256+(cb^rsw));
    #pragma unroll
    for(int n8=0;n8<8;n8++){
      s16x8 af=*(const s16x8*)(W1p+((n8*4+kc)<<9)+lane*8);
      a1[n8]=__builtin_amdgcn_mfma_f32_16x16x32_bf16(af,bf,a1[n8],0,0,0);
    }
  }
  #pragma unroll
  for(int n8=0;n8<8;n8++){
    int c0=n8*16+lk*4;
    float4 b4=*(const float4*)(b1+c0);
    float v[4]={fmaxf(a1[n8][0]+b4.x,0.f),fmaxf(a1[n8][1]+b4.y,0.f),
                fmaxf(a1[n8][2]+b4.z,0.f),fmaxf(a1[n8][3]+b4.w,0.f)};
    *(uint2*)((char*)hs+(u32)rl*256+(((u32)(2*c0))^rsw))=pk4(v);
  }
  // ---- MLP phase 2: relu(.@W2+b2) -> agx + stats
  f32x4 a2[8];
  #pragma unroll
  for(int n8=0;n8<8;n8++) a2[n8]=(f32x4){0.f,0.f,0.f,0.f};
  #pragma unroll
  for(int kc=0;kc<4;kc++){
    u32 cb=(u32)((kc*32+lk*8)*2);
    s16x8 bf=*(const s16x8*)((char*)hs+(u32)rl*256+(cb^rsw));
    #pragma unroll
    for(int n8=0;n8<8;n8++){
      s16x8 af=*(const s16x8*)(W2p+((n8*4+kc)<<9)+lane*8);
      a2[n8]=__builtin_amdgcn_mfma_f32_16x16x32_bf16(af,bf,a2[n8],0,0,0);
    }
  }
  #pragma unroll
  for(int n8=0;n8<8;n8++){
    int c0=n8*16+lk*4;
    float4 b4=*(const float4*)(b2+c0);
    float v[4]={fmaxf(a2[n8][0]+b4.x,0.f),fmaxf(a2[n8][1]+b4.y,0.f),
                fmaxf(a2[n8][2]+b4.z,0.f),fmaxf(a2[n8][3]+b4.w,0.f)};
    *(uint2*)((char*)agx+(u32)rl*256+(((u32)(2*c0))^rsw))=pk4(v);
    float s[4],q[4];
    #pragma unroll
    for(int j=0;j<4;j++){ s[j]=v[j]; q[j]=v[j]*v[j]; }
    #pragma unroll
    for(int j=0;j<4;j++){
      #pragma unroll
      for(int d=1;d<16;d<<=1){
        s[j]+=__shfl_xor(s[j],d);
        q[j]+=__shfl_xor(q[j],d);
      }
    }
    if(lr==0){
      #pragma unroll
      for(int j=0;j<4;j++){
        atomicAdd(&sst[c0+j],s[j]);
        atomicAdd(&sst[128+c0+j],q[j]);
      }
    }
  }
  __syncthreads();
  uint4* out4=(uint4*)(Xg+hbase);
  #pragma unroll
  for(int p=0;p<4;p++){
    int i=t+p*256;
    u32 row=(u32)(i>>4), colb=(u32)((i&15)*16);
    out4[i]=*(const uint4*)((const char*)agx+row*256+(colb^((row&7)<<4)));
  }
  atomicAdd(&stats[t],sst[t]);
}

// ==== node-path MLP (64-row tile): out = relu(relu(A@W1+b1)@W2+b2) + stats
__global__ __launch_bounds__(256) void k_mlp2n(
    const u16* __restrict__ A, const u16* __restrict__ W1p, const float* __restrict__ b1,
    const u16* __restrict__ W2p, const float* __restrict__ b2,
    u16* __restrict__ out, float* __restrict__ stats)
{
  __shared__ u16 T[64*128];
  __shared__ float sst[256];
  int t=threadIdx.x;
  sst[t]=0.f;
  int wave=t>>6, lane=t&63, lr=lane&15, lk=lane>>4;
  int rl=wave*16+lr;
  u32 rsw=((u32)(rl&7))<<4;
  int row0=blockIdx.x*64;
  f32x4 a1[8];
  #pragma unroll
  for(int n8=0;n8<8;n8++) a1[n8]=(f32x4){0.f,0.f,0.f,0.f};
  const s16x8* B0=(const s16x8*)(A+(size_t)(row0+rl)*H);
  #pragma unroll
  for(int kc=0;kc<4;kc++){
    s16x8 bf=B0[kc*4+lk];
    #pragma unroll
    for(int n8=0;n8<8;n8++){
      s16x8 af=*(const s16x8*)(W1p+((n8*4+kc)<<9)+lane*8);
      a1[n8]=__builtin_amdgcn_mfma_f32_16x16x32_bf16(af,bf,a1[n8],0,0,0);
    }
  }
  #pragma unroll
  for(int n8=0;n8<8;n8++){
    int c0=n8*16+lk*4;
    float4 b4=*(const float4*)(b1+c0);
    float v[4]={fmaxf(a1[n8][0]+b4.x,0.f),fmaxf(a1[n8][1]+b4.y,0.f),
                fmaxf(a1[n8][2]+b4.z,0.f),fmaxf(a1[n8][3]+b4.w,0.f)};
    *(uint2*)((char*)T+(u32)rl*256+(((u32)(2*c0))^rsw))=pk4(v);
  }
  f32x4 a2[8];
  #pragma unroll
  for(int n8=0;n8<8;n8++) a2[n8]=(f32x4){0.f,0.f,0.f,0.f};
  #pragma unroll
  for(int kc=0;kc<4;kc++){
    u32 cb=(u32)((kc*32+lk*8)*2);
    s16x8 bf=*(const s16x8*)((char*)T+(u32)rl*256+(cb^rsw));
    #pragma unroll
    for(int n8=0;n8<8;n8++){
      s16x8 af=*(const s16x8*)(W2p+((n8*4+kc)<<9)+lane*8);
      a2[n8]=__builtin_amdgcn_mfma_f32_16x16x32_bf16(af,bf,a2[n8],0,0,0);
    }
  }
  #pragma unroll
  for(int n8=0;n8<8;n8++){
    int c0=n8*16+lk*4;
    float4 b4=*(const float4*)(b2+c0);
    float v[4]={fmaxf(a2[n8][0]+b4.x,0.f),fmaxf(a2[n8][1]+b4.y,0.f),
                fmaxf(a2[n8][2]+b4.z,0.f),fmaxf(a2[n8][3]+b4.w,0.f)};
    *(uint2*)((char*)T+(u32)rl*256+(((u32)(2*c0))^rsw))=pk4(v);
    float s[4],q[4];
    #pragma unroll
    for(int j=0;j<4;j++){ s[j]=v[j]; q[j]=v[j]*v[j]; }
    #pragma unroll
    for(int j=0;j<4;j++){
      #pragma unroll
      for(int d=1;d<16;d<<=1){
        s[j]+=__shfl_xor(s[j],d);
        q[j]+=__shfl_xor(q[j],d);
      }
    }
    if(lr==0){
      #pragma unroll
      for(int j=0;j<4;j++){
        atomicAdd(&sst[c0+j],s[j]);
        atomicAdd(&sst[128+c0+j],q[j]);
      }
    }
  }
  __syncthreads();
  uint4* out4=(uint4*)(out+(size_t)row0*H);
  #pragma unroll
  for(int p=0;p<4;p++){
    int i=t+p*256;
    u32 row=(u32)(i>>4), colb=(u32)((i&15)*16);
    out4[i]=*(const uint4*)((const char*)T+row*256+(colb^((row&7)<<4)));
  }
  atomicAdd(&stats[t],sst[t]);
}

// ==== fused node broadcast: bb = ((hn + BN(ag)) @ bcw) @ cw1_bot
__global__ __launch_bounds__(256) void k_bcast(
    const u16* __restrict__ hn, const u16* __restrict__ ag,
    const float* __restrict__ stg, const float* __restrict__ gg, const float* __restrict__ bg,
    const u16* __restrict__ Wbcp, const u16* __restrict__ Wc1p,
    u16* __restrict__ bb)
{
  __shared__ u16 T[64*128];
  __shared__ u16 T2[64*128];
  __shared__ float ssh[128], tsh[128];
  int t=threadIdx.x;
  int row0=blockIdx.x*64;
  if(t<128){
    float mu=stg[t]*(1.f/4096.f);
    float var=stg[128+t]*(1.f/4096.f)-mu*mu;
    float s=gg[t]*rsqrtf(var+1e-5f);
    ssh[t]=s; tsh[t]=bg[t]-mu*s;
  }
  __syncthreads();
  #pragma unroll
  for(int i0=0;i0<4;i0++){
    int i=t+i0*256;
    u32 row=(u32)(i>>4);
    int cb8=(i&15)*8;
    float hv[8],av[8],o8[8];
    unp8(((const uint4*)(hn+(size_t)row0*H))[i],hv);
    unp8(((const uint4*)(ag+(size_t)row0*H))[i],av);
    #pragma unroll
    for(int j=0;j<8;j++) o8[j]=hv[j]+fmaf(av[j],ssh[cb8+j],tsh[cb8+j]);
    *(uint4*)((char*)T+row*256+(((u32)(cb8*2))^((row&7)<<4)))=pk8(o8);
  }
  __syncthreads();
  int wave=t>>6, lane=t&63, lr=lane&15, lk=lane>>4;
  int rl=wave*16+lr;
  u32 rsw=((u32)(rl&7))<<4;
  f32x4 a1[8];
  #pragma unroll
  for(int n8=0;n8<8;n8++) a1[n8]=(f32x4){0.f,0.f,0.f,0.f};
  #pragma unroll
  for(int kc=0;kc<4;kc++){
    u32 cb=(u32)((kc*32+lk*8)*2);
    s16x8 bf=*(const s16x8*)((char*)T+(u32)rl*256+(cb^rsw));
    #pragma unroll
    for(int n8=0;n8<8;n8++){
      s16x8 af=*(const s16x8*)(Wbcp+((n8*4+kc)<<9)+lane*8);
      a1[n8]=__builtin_amdgcn_mfma_f32_16x16x32_bf16(af,bf,a1[n8],0,0,0);
    }
  }
  #pragma unroll
  for(int n8=0;n8<8;n8++){
    int c0=n8*16+lk*4;
    float v[4]={a1[n8][0],a1[n8][1],a1[n8][2],a1[n8][3]};
    *(uint2*)((char*)T2+(u32)rl*256+(((u32)(2*c0))^rsw))=pk4(v);
  }
  f32x4 a2[8];
  #pragma unroll
  for(int n8=0;n8<8;n8++) a2[n8]=(f32x4){0.f,0.f,0.f,0.f};
  #pragma unroll
  for(int kc=0;kc<4;kc++){
    u32 cb=(u32)((kc*32+lk*8)*2);
    s16x8 bf=*(const s16x8*)((char*)T2+(u32)rl*256+(cb^rsw));
    #pragma unroll
    for(int n8=0;n8<8;n8++){
      s16x8 af=*(const s16x8*)(Wc1p+((n8*4+kc)<<9)+lane*8);
      a2[n8]=__builtin_amdgcn_mfma_f32_16x16x32_bf16(af,bf,a2[n8],0,0,0);
    }
  }
  #pragma unroll
  for(int n8=0;n8<8;n8++){
    int c0=n8*16+lk*4;
    float v[4]={a2[n8][0],a2[n8][1],a2[n8][2],a2[n8][3]};
    *(uint2*)((char*)T+(u32)rl*256+(((u32)(2*c0))^rsw))=pk4(v);
  }
  __syncthreads();
  uint4* out4=(uint4*)(bb+(size_t)row0*H);
  #pragma unroll
  for(int p=0;p<4;p++){
    int i=t+p*256;
    u32 row=(u32)(i>>4), colb=(u32)((i&15)*16);
    out4[i]=*(const uint4*)((const char*)T+row*256+(colb^((row&7)<<4)));
  }
}

// ==== standalone tail (final layer): h = (res + LN( gelu(X@W3+bias3+bb[node]) @ W2 + cb2 )) * valid
__global__ __launch_bounds__(256) void k_tail(
    const u16* __restrict__ X, const u16* __restrict__ W3p, const float* __restrict__ bias3,
    const u16* __restrict__ bb,
    const u16* __restrict__ W2p, const float* __restrict__ cb2,
    const float* __restrict__ lng, const float* __restrict__ lnb,
    const int* __restrict__ validv, u16* __restrict__ hio)
{
  __shared__ u16 T[64*128];
  int t=threadIdx.x;
  int wave=t>>6, lane=t&63, lr=lane&15, lk=lane>>4;
  int rl=wave*16+lr;
  u32 rsw=((u32)(rl&7))<<4;
  int row0=blockIdx.x*64;
  f32x4 acc[8];
  #pragma unroll
  for(int n8=0;n8<8;n8++) acc[n8]=(f32x4){0.f,0.f,0.f,0.f};
  const s16x8* B0=(const s16x8*)(X+(size_t)(row0+rl)*H);
  #pragma unroll
  for(int kc=0;kc<4;kc++){
    s16x8 bf=B0[kc*4+lk];
    #pragma unroll
    for(int n8=0;n8<8;n8++){
      s16x8 af=*(const s16x8*)(W3p+((n8*4+kc)<<9)+lane*8);
      acc[n8]=__builtin_amdgcn_mfma_f32_16x16x32_bf16(af,bf,acc[n8],0,0,0);
    }
  }
  #pragma unroll
  for(int n8=0;n8<8;n8++){
    int c0=n8*16+lk*4;
    float4 b4=*(const float4*)(bias3+c0);
    float rb[4];
    unp4(*(const uint2*)(bb+(size_t)blockIdx.x*H+c0),rb);
    float vb[4]={b4.x,b4.y,b4.z,b4.w};
    float v[4];
    #pragma unroll
    for(int j=0;j<4;j++){
      float x=acc[n8][j]+vb[j]+rb[j];
      v[j]=0.5f*x*(1.f+erff(x*0.70710678118654752f));
    }
    *(uint2*)((char*)T+(u32)rl*256+(((u32)(2*c0))^rsw))=pk4(v);
  }
  f32x4 a2[8];
  #pragma unroll
  for(int n8=0;n8<8;n8++) a2[n8]=(f32x4){0.f,0.f,0.f,0.f};
  #pragma unroll
  for(int kc=0;kc<4;kc++){
    u32 cb=(u32)((kc*32+lk*8)*2);
    s16x8 bf=*(const s16x8*)((char*)T+(u32)rl*256+(cb^rsw));
    #pragma unroll
    for(int n8=0;n8<8;n8++){
      s16x8 af=*(const s16x8*)(W2p+((n8*4+kc)<<9)+lane*8);
      a2[n8]=__builtin_amdgcn_mfma_f32_16x16x32_bf16(af,bf,a2[n8],0,0,0);
    }
  }
  {
    float s=0.f,q=0.f;
    #pragma unroll
    for(int n8=0;n8<8;n8++){
      int c0=n8*16+lk*4;
      float4 b4=*(const float4*)(cb2+c0);
      float vb[4]={b4.x,b4.y,b4.z,b4.w};
      #pragma unroll
      for(int j=0;j<4;j++){
        float v=a2[n8][j]+vb[j];
        a2[n8][j]=v;
        s+=v; q+=v*v;
      }
    }
    s+=__shfl_xor(s,16); s+=__shfl_xor(s,32);
    q+=__shfl_xor(q,16); q+=__shfl_xor(q,32);
    float mu=s*(1.f/128.f);
    float rsig=rsqrtf(q*(1.f/128.f)-mu*mu+1e-5f);
    #pragma unroll
    for(int n8=0;n8<8;n8++){
      int c0=n8*16+lk*4;
      float4 g4=*(const float4*)(lng+c0);
      float4 e4=*(const float4*)(lnb+c0);
      float g[4]={g4.x,g4.y,g4.z,g4.w}, e[4]={e4.x,e4.y,e4.z,e4.w};
      float ov[4];
      #pragma unroll
      for(int j=0;j<4;j++) ov[j]=(a2[n8][j]-mu)*rsig*g[j]+e[j];
      *(uint2*)((char*)T+(u32)rl*256+(((u32)(2*c0))^rsw))=pk4(ov);
    }
  }
  __syncthreads();
  uint4* hp=(uint4*)(hio+(size_t)row0*H);
  #pragma unroll
  for(int p=0;p<4;p++){
    int i=t+p*256;
    u32 row=(u32)(i>>4), colb=(u32)((i&15)*16);
    int grow=row0+(int)row;
    uint4 v=*(const uint4*)((const char*)T+row*256+(colb^((row&7)<<4)));
    uint4 r=hp[i];
    float vv[8],rv[8],o8[8];
    unp8(v,vv); unp8(r,rv);
    float vm=validv[grow]?1.f:0.f;
    #pragma unroll
    for(int j=0;j<8;j++) o8[j]=(rv[j]+vv[j])*vm;
    hp[i]=pk8(o8);
  }
}

// ---- h_node = mean of two root rows
__global__ void k_npool(const u16* __restrict__ h, u16* __restrict__ hn){
  int i=blockIdx.x*blockDim.x+threadIdx.x;
  if(i>=NN*16) return;
  int n=i>>4, q=i&15;
  const uint4* hp=(const uint4*)h;
  float a[8],b[8],o[8];
  unp8(hp[(size_t)n*1024+q],a);
  unp8(hp[(size_t)n*1024+512+q],b);
  #pragma unroll
  for(int e=0;e<8;e++) o[e]=(a[e]+b[e])*0.5f;
  ((uint4*)hn)[i]=pk8(o);
}

// ---- global GINE aggregation per node
__global__ __launch_bounds__(128) void k_gagg(const u16* __restrict__ hn, const float* __restrict__ be,
                      const int* __restrict__ goff, const int* __restrict__ gcnt,
                      const int* __restrict__ gpack, const float* __restrict__ epsp, int layer,
                      u16* __restrict__ hhg){
  __shared__ float bes[16][128];
  int n=blockIdx.x, c=threadIdx.x;
  for(int i=0;i<16;i++) bes[i][c]=be[i*128+c];
  __syncthreads();
  float acc=0.f;
  int o=goff[n], e=o+gcnt[n];
  for(;o<e;o++){
    int p=gpack[o];
    acc+=fmaxf(b2f(hn[(size_t)(p>>4)*H+c])+bes[p&15][c],0.f);
  }
  hhg[(size_t)n*H+c]=f2b(fmaf(1.f+epsp[layer],b2f(hn[(size_t)n*H+c]),acc));
}

// ---- final pooling
__global__ __launch_bounds__(128) void k_pool(const u16* __restrict__ h, const int* __restrict__ valid,
                      const int* __restrict__ batch, float* __restrict__ oacc){
  __shared__ float cs[2];
  int n=blockIdx.x, c=threadIdx.x;
  if(c<2){
    int s=0;
    for(int j=0;j<32;j++) s+=valid[n*64+c*32+j];
    cs[c]=fmaxf((float)s,1.f);
  }
  __syncthreads();
  size_t base=(size_t)n*64*H;
  float a0=0.f,a1=0.f;
  for(int j=0;j<32;j++){
    a0+=b2f(h[base+(size_t)j*H+c]);
    a1+=b2f(h[base+(size_t)(32+j)*H+c]);
  }
  float nodef=0.5f*(a0/cs[0]+a1/cs[1]);
  atomicAdd(&oacc[batch[n]*H+c],nodef);
}

__global__ void k_out(const float* __restrict__ acc, const int* __restrict__ flag, void* __restrict__ out){
  int i=blockIdx.x*blockDim.x+threadIdx.x;
  if(i>=NGRAPH*H) return;
  if(*flag) ((__hip_bfloat16*)out)[i]=__float2bfloat16(acc[i]);
  else ((float*)out)[i]=acc[i];
}

extern "C" void kernel_launch(void* const* d_in, const int* in_sizes, int n_in,
                              void* d_out, int out_size, void* d_ws, size_t ws_size,
                              hipStream_t stream){
  (void)n_in; (void)out_size;
  int pofs[27]; pofs[0]=0;
  for(int i=0;i<26;i++) pofs[i+1]=pofs[i]+in_sizes[i];
  int ptot=pofs[26];

  char* wsb=(char*)d_ws;
  size_t off=0;
  auto alloc=[&](size_t bytes)->char*{ char* p=wsb+off; off+=(bytes+255)&~(size_t)255; return p; };
  int*   flag =(int*)  alloc(4);
  float* par  =(float*)alloc((size_t)ptot*4);
  u16*   h    =(u16*)  alloc((size_t)SKK*H*2);
  u16*   X    =(u16*)  alloc((size_t)SKK*H*2);
  u16*   wt   =(u16*)  alloc((size_t)28*HH*2);
  u16*   wt3  =(u16*)  alloc((size_t)HH*2);
  float* bias3=(float*)alloc(H*4);
  float* rf   =(float*)alloc((size_t)NN*H*4);
  u16*   bondb=(u16*)  alloc((size_t)16*H*2);
  u16*   hn   =(u16*)  alloc((size_t)NN*H*2);
  u16*   hhg  =(u16*)  alloc((size_t)NN*H*2);
  u16*   ag   =(u16*)  alloc((size_t)NN*H*2);
  u16*   bb   =(u16*)  alloc((size_t)NN*H*2);
  // ---- contiguous zero-init region (one memset) ----
  int*   ecnt =(int*)  alloc(SS*4);
  int*   ecur =(int*)  alloc(SS*4);
  int*   gcnt =(int*)  alloc(NN*4);
  int*   gcur =(int*)  alloc(NN*4);
  float* stats=(float*)alloc(LNUM*512*4);
  float* oacc =(float*)alloc((size_t)NGRAPH*H*4);
  size_t zbytes=(size_t)SS*4+SS*4+NN*4+NN*4+LNUM*512*4+(size_t)NGRAPH*H*4;
  // ---- rest ----
  int* eoff  =(int*)alloc(SS*4);
  int* epack =(int*)alloc((size_t)EI*4);
  int* dstoff=(int*)alloc((size_t)SS*32*4);
  int* goff  =(int*)alloc(NN*4);
  int* gpack =(int*)alloc((size_t)EG*4);

  if(off>ws_size) return;

  const int* xids =(const int*)d_in[26];
  const int* iei  =(const int*)d_in[27];
  const int* iea  =(const int*)d_in[28];
  const int* gei  =(const int*)d_in[29];
  const int* gea  =(const int*)d_in[30];
  const int* nids =(const int*)d_in[31];
  const int* valid=(const int*)d_in[32];
  const int* batch=(const int*)d_in[33];

  const float* atom=par+pofs[0];
  const float* bond=par+pofs[1];
  const float* rw_w=par+pofs[2];
  const float* rw_b=par+pofs[3];
  const float* rwse=par+pofs[4];
  const float* leps=par+pofs[5];
  const float* lb1 =par+pofs[7];
  const float* lb2 =par+pofs[9];
  const float* lbng=par+pofs[10];
  const float* lbnb=par+pofs[11];
  const float* geps=par+pofs[12];
  const float* gb1 =par+pofs[14];
  const float* gb2 =par+pofs[16];
  const float* gbng=par+pofs[17];
  const float* gbnb=par+pofs[18];
  const float* cw1 =par+pofs[20];
  const float* cb1 =par+pofs[21];
  const float* cb2 =par+pofs[23];
  const float* lngp=par+pofs[24];
  const float* lnbp=par+pofs[25];

  k_sniff<<<1,256,0,stream>>>((const u16*)d_in[0], flag);
  CvtArgs ca;
  for(int i=0;i<26;i++){ ca.p[i]=d_in[i]; ca.start[i]=pofs[i]; }
  ca.start[26]=ptot;
  k_convert<<<1024,256,0,stream>>>(ca, flag, par);

  TransArgs ta;
  for(int l=0;l<LNUM;l++){
    ta.src[l*7+0]=pofs[6]+l*HH;           // lw1
    ta.src[l*7+1]=pofs[8]+l*HH;           // lw2
    ta.src[l*7+2]=pofs[13]+l*HH;          // gw1
    ta.src[l*7+3]=pofs[15]+l*HH;          // gw2
    ta.src[l*7+4]=pofs[19]+l*HH;          // bcw
    ta.src[l*7+5]=pofs[20]+l*2*HH+HH;     // cw1 bottom half
    ta.src[l*7+6]=pofs[22]+l*HH;          // cw2
  }
  k_trans<<<28,256,0,stream>>>(par, ta, wt);
  k_cvtbond<<<8,256,0,stream>>>(bond, bondb);

  (void)hipMemsetAsync(ecnt,0,zbytes,stream);

  k_hist<<<2048,256,0,stream>>>(iei+EI, EI, 5, ecnt);
  k_scan<<<1,1024,0,stream>>>(ecnt, eoff, SS);
  k_scatter_i<<<2048,256,0,stream>>>(iei, iea, eoff, ecur, epack);
  k_sortsub<<<SS,128,0,stream>>>(eoff, ecnt, epack, dstoff);
  k_hist<<<512,256,0,stream>>>(gei+EG, EG, 0, gcnt);
  k_scan<<<1,1024,0,stream>>>(gcnt, goff, NN);
  k_scatter_g<<<512,256,0,stream>>>(gei, gea, goff, gcur, gpack);

  k_rwse<<<NN,128,0,stream>>>(rwse, rw_w, rw_b, rf);
  k_h0<<<(SKK*16)/256,256,0,stream>>>(atom, rf, xids, nids, valid, h);

  for(int l=0;l<LNUM;l++){
    float* stl_l=stats+l*512;
    float* stg_l=stats+l*512+256;
    if(l==0){
      k_fused1<0><<<SS/2,256,0,stream>>>(h, bondb, eoff, ecnt, epack, dstoff, leps, l,
          wt+(size_t)(l*7+0)*HH, lb1+l*H, wt+(size_t)(l*7+1)*HH, lb2+l*H, X, stl_l,
          nullptr,nullptr,nullptr,nullptr,nullptr,nullptr,nullptr,nullptr,nullptr);
    } else {
      int pl=l-1;
      k_fused1<1><<<SS/2,256,0,stream>>>(h, bondb, eoff, ecnt, epack, dstoff, leps, l,
          wt+(size_t)(l*7+0)*HH, lb1+l*H, wt+(size_t)(l*7+1)*HH, lb2+l*H, X, stl_l,
          wt3, bias3, bb, wt+(size_t)(pl*7+6)*HH, cb2+pl*H,
          lngp+pl*H, lnbp+pl*H, valid, h);
    }
    k_npool<<<(NN*16)/256,256,0,stream>>>(h, hn);
    k_gagg<<<NN,128,0,stream>>>(hn, bond, goff, gcnt, gpack, geps, l, hhg);
    k_mlp2n<<<NN/64,256,0,stream>>>(hhg, wt+(size_t)(l*7+2)*HH, gb1+l*H,
        wt+(size_t)(l*7+3)*HH, gb2+l*H, ag, stg_l);
    k_bcast<<<NN/64,256,0,stream>>>(hn, ag, stg_l, gbng+l*H, gbnb+l*H,
        wt+(size_t)(l*7+4)*HH, wt+(size_t)(l*7+5)*HH, bb);
    k_prepw3<<<128,128,0,stream>>>(cw1+(size_t)l*2*HH, cb1+l*H, stl_l, lbng+l*H, lbnb+l*H, wt3, bias3);
  }
  {
    int l=LNUM-1;
    k_tail<<<SKK/64,256,0,stream>>>(X, wt3, bias3, bb,
        wt+(size_t)(l*7+6)*HH, cb2+l*H, lngp+l*H, lnbp+l*H, valid, h);
  }
  k_pool<<<NN,128,0,stream>>>(h, valid, batch, oacc);
  k_out<<<(NGRAPH*H+255)/256,256,0,stream>>>(oacc, flag, d_out);
}

// Round 11
// 1181.401 us; speedup vs baseline: 3.6700x; 1.0316x over previous
//
#include <hip/hip_runtime.h>
#include <hip/hip_bf16.h>

#define H 128
#define HH 16384
#define LNUM 4
#define NN 4096
#define SS 8192
#define SKK 262144
#define EI 1048576
#define EG 65536
#define NGRAPH 64

typedef unsigned short u16;
typedef unsigned int u32;
typedef __attribute__((ext_vector_type(8))) short s16x8;
typedef __attribute__((ext_vector_type(4))) float f32x4;

__device__ __forceinline__ float b2f(u32 u){ return __uint_as_float(u<<16); }
__device__ __forceinline__ u16 f2b(float f){
  union { __hip_bfloat16 b; u16 u; } x;
  x.b=__float2bfloat16(f);
  return x.u;
}
__device__ __forceinline__ void unp8(uint4 v, float* f){
  f[0]=b2f(v.x&0xFFFF); f[1]=b2f(v.x>>16);
  f[2]=b2f(v.y&0xFFFF); f[3]=b2f(v.y>>16);
  f[4]=b2f(v.z&0xFFFF); f[5]=b2f(v.z>>16);
  f[6]=b2f(v.w&0xFFFF); f[7]=b2f(v.w>>16);
}
__device__ __forceinline__ void unp4(uint2 v, float* f){
  f[0]=b2f(v.x&0xFFFF); f[1]=b2f(v.x>>16);
  f[2]=b2f(v.y&0xFFFF); f[3]=b2f(v.y>>16);
}
__device__ __forceinline__ uint4 pk8(const float* f){
  uint4 r;
  r.x=(u32)f2b(f[0])|((u32)f2b(f[1])<<16);
  r.y=(u32)f2b(f[2])|((u32)f2b(f[3])<<16);
  r.z=(u32)f2b(f[4])|((u32)f2b(f[5])<<16);
  r.w=(u32)f2b(f[6])|((u32)f2b(f[7])<<16);
  return r;
}
__device__ __forceinline__ uint2 pk4(const float* f){
  uint2 r;
  r.x=(u32)f2b(f[0])|((u32)f2b(f[1])<<16);
  r.y=(u32)f2b(f[2])|((u32)f2b(f[3])<<16);
  return r;
}

struct CvtArgs {
  const void* p[26];
  int start[27];
};
struct TransArgs { int src[28]; };

// ---- dtype sniff
__global__ void k_sniff(const u16* __restrict__ a, int* __restrict__ flag){
  __shared__ int cnt;
  if(threadIdx.x==0) cnt=0;
  __syncthreads();
  int big=0;
  for(int i=threadIdx.x;i<2048;i+=256){
    int e=(a[i]>>7)&0xFF;
    if(e>=127) big++;
  }
  atomicAdd(&cnt,big);
  __syncthreads();
  if(threadIdx.x==0) *flag=(cnt<16)?1:0;
}

__global__ void k_convert(CvtArgs args, const int* __restrict__ flag, float* __restrict__ dst){
  int fl=*flag;
  int total=args.start[26];
  for(int i=blockIdx.x*blockDim.x+threadIdx.x;i<total;i+=gridDim.x*blockDim.x){
    int a=0;
    while(args.start[a+1]<=i) a++;
    int j=i-args.start[a];
    float v;
    if(fl) v=b2f(((const u16*)args.p[a])[j]);
    else   v=((const float*)args.p[a])[j];
    dst[i]=v;
  }
}

// ---- static weights: f32 [K][N] -> bf16 fragment-major packed
__global__ __launch_bounds__(256) void k_trans(const float* __restrict__ par, TransArgs ta, u16* __restrict__ wt){
  const float* s=par+ta.src[blockIdx.x];
  u16* d=wt+(size_t)blockIdx.x*HH;
  for(int i=threadIdx.x;i<HH;i+=256){
    int j=i&7, lane=(i>>3)&63, fc=i>>9;
    int n=fc>>2, kc=fc&3, lr=lane&15, lk=lane>>4;
    int outc=n*16+lr, k=kc*32+lk*8+j;
    d[i]=f2b(s[(size_t)k*H+outc]);
  }
}

// ---- bond emb f32 -> bf16
__global__ void k_cvtbond(const float* __restrict__ b, u16* __restrict__ bb){
  int i=blockIdx.x*blockDim.x+threadIdx.x;
  if(i<16*H) bb[i]=f2b(b[i]);
}

// ---- fold local-BN affine into cw1_top, packed output
__global__ __launch_bounds__(128) void k_prepw3(const float* __restrict__ w, const float* __restrict__ cb1,
                        const float* __restrict__ stl, const float* __restrict__ gl, const float* __restrict__ bl,
                        u16* __restrict__ wt3p, float* __restrict__ bias3){
  __shared__ float red[128];
  int c=blockIdx.x, k=threadIdx.x;
  float mu=stl[k]*(1.f/262144.f);
  float var=stl[128+k]*(1.f/262144.f)-mu*mu;
  float s=gl[k]*rsqrtf(var+1e-5f);
  float tt=bl[k]-mu*s;
  float wv=w[(size_t)k*H+c];
  int idx=(((c>>4)*4+(k>>5))*64+((k>>3)&3)*16+(c&15))*8+(k&7);
  wt3p[idx]=f2b(s*wv);
  red[k]=tt*wv;
  __syncthreads();
  for(int d=64;d>0;d>>=1){ if(k<d) red[k]+=red[k+d]; __syncthreads(); }
  if(k==0) bias3[c]=cb1[c]+red[0];
}

// ---- edge bucketing
__global__ void k_hist(const int* __restrict__ idx, int n, int shift, int* __restrict__ cnt){
  for(int i=blockIdx.x*blockDim.x+threadIdx.x;i<n;i+=gridDim.x*blockDim.x)
    atomicAdd(&cnt[idx[i]>>shift],1);
}

__global__ void k_scan(const int* __restrict__ cnt, int* __restrict__ off, int nbins){
  __shared__ int ts[1024];
  int t=threadIdx.x;
  int per=nbins>>10;
  int base=t*per;
  int s=0;
  for(int j=0;j<per;j++) s+=cnt[base+j];
  ts[t]=s;
  __syncthreads();
  for(int d=1;d<1024;d<<=1){
    int v=(t>=d)?ts[t-d]:0;
    __syncthreads();
    ts[t]+=v;
    __syncthreads();
  }
  int ex=(t==0)?0:ts[t-1];
  for(int j=0;j<per;j++){ off[base+j]=ex; ex+=cnt[base+j]; }
}

__global__ void k_scatter_i(const int* __restrict__ ei, const int* __restrict__ ea,
                            const int* __restrict__ off, int* __restrict__ cur, int* __restrict__ pack){
  for(int i=blockIdx.x*blockDim.x+threadIdx.x;i<EI;i+=gridDim.x*blockDim.x){
    int s=ei[i], d=ei[EI+i];
    int sub=d>>5;
    int pos=off[sub]+atomicAdd(&cur[sub],1);
    pack[pos]=((s&31)<<9)|((d&31)<<4)|(ea[i]&15);
  }
}

// ---- sort each subgraph's edges by dst-lane; persist per-dst segment starts
__global__ __launch_bounds__(128) void k_sortsub(const int* __restrict__ eoff, const int* __restrict__ ecnt,
                                                 int* __restrict__ epack, int* __restrict__ dstoff){
  __shared__ int ein[512];
  __shared__ int eout[512];
  __shared__ int bcnt[32];
  __shared__ int bpos[32];
  int sub=blockIdx.x, t=threadIdx.x;
  int o=eoff[sub];
  int n=ecnt[sub]; if(n>512) n=512;
  for(int i=t;i<n;i+=128) ein[i]=epack[o+i];
  if(t<32) bcnt[t]=0;
  __syncthreads();
  for(int i=t;i<n;i+=128) atomicAdd(&bcnt[(ein[i]>>4)&31],1);
  __syncthreads();
  if(t==0){
    int s=0;
    for(int b=0;b<32;b++){ bpos[b]=s; s+=bcnt[b]; }
  }
  __syncthreads();
  if(t<32) dstoff[sub*32+t]=bpos[t];
  __syncthreads();
  for(int i=t;i<n;i+=128){
    int p=ein[i];
    int pos=atomicAdd(&bpos[(p>>4)&31],1);
    eout[pos]=p;
  }
  __syncthreads();
  for(int i=t;i<n;i+=128) epack[o+i]=eout[i];
}

__global__ void k_scatter_g(const int* __restrict__ ei, const int* __restrict__ ea,
                            const int* __restrict__ off, int* __restrict__ cur, int* __restrict__ pack){
  for(int i=blockIdx.x*blockDim.x+threadIdx.x;i<EG;i+=gridDim.x*blockDim.x){
    int s=ei[i], d=ei[EG+i];
    int pos=off[d]+atomicAdd(&cur[d],1);
    pack[pos]=(s<<4)|(ea[i]&15);
  }
}

// ---- rf = relu(rwse @ rwse_w + rwse_b)
__global__ __launch_bounds__(128) void k_rwse(const float* __restrict__ rwse, const float* __restrict__ w,
                      const float* __restrict__ b, float* __restrict__ rf){
  __shared__ float ws[16*128];
  __shared__ float rv[16];
  int n=blockIdx.x, c=threadIdx.x;
  for(int i=c;i<2048;i+=128) ws[i]=w[i];
  if(c<16) rv[c]=rwse[n*16+c];
  __syncthreads();
  float acc=b[c];
  for(int j=0;j<16;j++) acc=fmaf(rv[j],ws[j*128+c],acc);
  rf[(size_t)n*H+c]=fmaxf(acc,0.f);
}

// ---- h0
__global__ void k_h0(const float* __restrict__ atom, const float* __restrict__ rf,
                     const int* __restrict__ xids, const int* __restrict__ nids,
                     const int* __restrict__ valid, u16* __restrict__ h){
  int i=blockIdx.x*blockDim.x+threadIdx.x;
  if(i>=SKK*16) return;
  int r=i>>4, q=i&15;
  const float4* ap=(const float4*)(atom+(size_t)xids[r]*H)+q*2;
  const float4* bp=(const float4*)(rf+(size_t)nids[r]*H)+q*2;
  float4 a0=ap[0],a1=ap[1],b0=bp[0],b1=bp[1];
  float vm=valid[r]?1.f:0.f;
  float f[8]={(a0.x+b0.x)*vm,(a0.y+b0.y)*vm,(a0.z+b0.z)*vm,(a0.w+b0.w)*vm,
              (a1.x+b1.x)*vm,(a1.y+b1.y)*vm,(a1.z+b1.z)*vm,(a1.w+b1.w)*vm};
  ((uint4*)h)[i]=pk8(f);
}

// ==== FUSED mega-kernel:
//  TAIL=1: prev-layer tail (h update kept in LDS) ; then flattened pipelined
//  segment-parallel local GINE agg + 2-GEMM MLP + stats -> X
template<int TAIL>
__global__ __launch_bounds__(256,4) void k_fused1(
    const u16* __restrict__ h, const u16* __restrict__ beb,
    const int* __restrict__ eoff, const int* __restrict__ ecnt, const int* __restrict__ epack,
    const int* __restrict__ dstoff,
    const float* __restrict__ epsp, int layer,
    const u16* __restrict__ W1p, const float* __restrict__ b1,
    const u16* __restrict__ W2p, const float* __restrict__ b2,
    u16* __restrict__ Xg, float* __restrict__ stats,
    const u16* __restrict__ W3p, const float* __restrict__ bias3,
    const u16* __restrict__ bbv,
    const u16* __restrict__ Wc2p, const float* __restrict__ cb2,
    const float* __restrict__ lng, const float* __restrict__ lnb,
    const int* __restrict__ validv, u16* __restrict__ hio)
{
  __shared__ u16 hs[64*128];      // swizzled h; later MLP intermediate
  __shared__ u16 agx[64*128];     // tail T / X_in / output staging
  __shared__ u16 bes[16*128];
  __shared__ u16 epku[2][512];    // packed edges (14-bit); sst overlays after agg
  __shared__ int doff[2][32];
  float* sst=(float*)&epku[0][0];

  int t=threadIdx.x;
  int grp=t>>7, c=t&127;
  size_t hbase=(size_t)blockIdx.x*64*H;
  int wave=t>>6, lane=t&63, lr=lane&15, lk=lane>>4;
  int rl=wave*16+lr;
  u32 rsw=((u32)(rl&7))<<4;
  int row0=blockIdx.x*64;

  // early staging (global loads overlap tail compute)
  {
    u32 row=(u32)(t>>4), colb=(u32)((t&15)*16);
    *(uint4*)((char*)bes+row*256+(colb^((row&7)<<4)))=((const uint4*)beb)[t];
  }
  int sub=blockIdx.x*2+grp;
  int n=min(ecnt[sub],512);
  int o=eoff[sub];
  if(c<32) doff[grp][c]=dstoff[sub*32+c];
  for(int i=c;i<n;i+=128) epku[grp][i]=(u16)epack[o+i];

  if(TAIL){
    // tail phase 1: gelu(X@W3 + bias3 + bbv[node]) -> agx
    f32x4 a1t[8];
    #pragma unroll
    for(int n8=0;n8<8;n8++) a1t[n8]=(f32x4){0.f,0.f,0.f,0.f};
    const s16x8* B0=(const s16x8*)(Xg+(size_t)(row0+rl)*H);
    #pragma unroll
    for(int kc=0;kc<4;kc++){
      s16x8 bf=B0[kc*4+lk];
      #pragma unroll
      for(int n8=0;n8<8;n8++){
        s16x8 af=*(const s16x8*)(W3p+((n8*4+kc)<<9)+lane*8);
        a1t[n8]=__builtin_amdgcn_mfma_f32_16x16x32_bf16(af,bf,a1t[n8],0,0,0);
      }
    }
    #pragma unroll
    for(int n8=0;n8<8;n8++){
      int c0=n8*16+lk*4;
      float4 b4=*(const float4*)(bias3+c0);
      float rb[4];
      unp4(*(const uint2*)(bbv+(size_t)blockIdx.x*H+c0),rb);
      float vb[4]={b4.x,b4.y,b4.z,b4.w};
      float v[4];
      #pragma unroll
      for(int j=0;j<4;j++){
        float x=a1t[n8][j]+vb[j]+rb[j];
        v[j]=0.5f*x*(1.f+erff(x*0.70710678118654752f));
      }
      *(uint2*)((char*)agx+(u32)rl*256+(((u32)(2*c0))^rsw))=pk4(v);
    }
    // tail phase 2: @Wc2 + LN -> agx
    f32x4 a2t[8];
    #pragma unroll
    for(int n8=0;n8<8;n8++) a2t[n8]=(f32x4){0.f,0.f,0.f,0.f};
    #pragma unroll
    for(int kc=0;kc<4;kc++){
      u32 cb=(u32)((kc*32+lk*8)*2);
      s16x8 bf=*(const s16x8*)((char*)agx+(u32)rl*256+(cb^rsw));
      #pragma unroll
      for(int n8=0;n8<8;n8++){
        s16x8 af=*(const s16x8*)(Wc2p+((n8*4+kc)<<9)+lane*8);
        a2t[n8]=__builtin_amdgcn_mfma_f32_16x16x32_bf16(af,bf,a2t[n8],0,0,0);
      }
    }
    {
      float s=0.f,q=0.f;
      #pragma unroll
      for(int n8=0;n8<8;n8++){
        int c0=n8*16+lk*4;
        float4 b4=*(const float4*)(cb2+c0);
        float vb[4]={b4.x,b4.y,b4.z,b4.w};
        #pragma unroll
        for(int j=0;j<4;j++){
          float v=a2t[n8][j]+vb[j];
          a2t[n8][j]=v;
          s+=v; q+=v*v;
        }
      }
      s+=__shfl_xor(s,16); s+=__shfl_xor(s,32);
      q+=__shfl_xor(q,16); q+=__shfl_xor(q,32);
      float mu=s*(1.f/128.f);
      float rsig=rsqrtf(q*(1.f/128.f)-mu*mu+1e-5f);
      #pragma unroll
      for(int n8=0;n8<8;n8++){
        int c0=n8*16+lk*4;
        float4 g4=*(const float4*)(lng+c0);
        float4 e4=*(const float4*)(lnb+c0);
        float g[4]={g4.x,g4.y,g4.z,g4.w}, e[4]={e4.x,e4.y,e4.z,e4.w};
        float ov[4];
        #pragma unroll
        for(int j=0;j<4;j++) ov[j]=(a2t[n8][j]-mu)*rsig*g[j]+e[j];
        *(uint2*)((char*)agx+(u32)rl*256+(((u32)(2*c0))^rsw))=pk4(ov);
      }
    }
    __syncthreads();
    // flush: h_new = (h_old + LN)*valid -> global h AND hs (swizzled)
    uint4* hp=(uint4*)(hio+hbase);
    #pragma unroll
    for(int p=0;p<4;p++){
      int i=t+p*256;
      u32 row=(u32)(i>>4), colb=(u32)((i&15)*16);
      int grow=row0+(int)row;
      uint4 v=*(const uint4*)((const char*)agx+row*256+(colb^((row&7)<<4)));
      uint4 r=hp[i];
      float vv[8],rv[8],o8[8];
      unp8(v,vv); unp8(r,rv);
      float vm=validv[grow]?1.f:0.f;
      #pragma unroll
      for(int j=0;j<8;j++) o8[j]=(rv[j]+vv[j])*vm;
      uint4 pk=pk8(o8);
      hp[i]=pk;
      *(uint4*)((char*)hs+row*256+(colb^((row&7)<<4)))=pk;
    }
  } else {
    const uint4* src=(const uint4*)(h+hbase);
    #pragma unroll
    for(int i0=0;i0<4;i0++){
      int i=t+i0*256;
      u32 row=(u32)(i>>4), colb=(u32)((i&15)*16);
      *(uint4*)((char*)hs+row*256+(colb^((row&7)<<4)))=src[i];
    }
  }
  __syncthreads();

  // ---- init agx = (1+eps)*h
  {
    float ep=1.f+epsp[layer];
    #pragma unroll
    for(int p=0;p<4;p++){
      int i=t+p*256;
      u32 row=(u32)(i>>4), colb=(u32)((i&15)*16);
      u32 off=row*256+(colb^((row&7)<<4));
      float hf[8],o8[8];
      unp8(*(const uint4*)((const char*)hs+off),hf);
      #pragma unroll
      for(int j=0;j<8;j++) o8[j]=ep*hf[j];
      *(uint4*)((char*)agx+off)=pk8(o8);
    }
  }
  __syncthreads();

  // ---- flattened aggregation: thread owns 4 dsts x 8 channels, 2-deep pipeline
  {
    int slot=c>>4, chg=c&15;
    u32 cbyte=(u32)chg*16;
    int d0=slot*4;
    int sA=doff[grp][d0],   eAs=doff[grp][d0+1];
    int sB=doff[grp][d0+1], eBs=doff[grp][d0+2];
    int sC=doff[grp][d0+2], eCs=doff[grp][d0+3];
    int sD=doff[grp][d0+3];
    int eDs=(d0+3==31)?n:doff[grp][d0+4];
    int c1=eAs-sA;
    int c2=c1+eBs-sB;
    int c3=c2+eCs-sC;
    int tot=c3+eDs-sD;
    const u16* ep_=&epku[grp][0];
    auto VIDX=[&](int j)->int{
      return (j<c1)? sA+j : (j<c2)? sB+j-c1 : (j<c3)? sC+j-c2 : sD+j-c3;
    };
    auto LDP=[&](int p, uint4& hv, uint4& bv){
      u32 srow=(u32)(grp*32+(p>>9));
      u32 erow=(u32)(p&15);
      hv=*(const uint4*)((const char*)hs+srow*256+(cbyte^((srow&7)<<4)));
      bv=*(const uint4*)((const char*)bes+erow*256+(cbyte^((erow&7)<<4)));
    };
    int pA=0,pBv=0,pP0=0,pP1=0;
    uint4 hvA,bvA,hvB,bvB;
    hvA=bvA=hvB=bvB=make_uint4(0,0,0,0);
    if(tot>0){ pA=ep_[VIDX(0)]; LDP(pA,hvA,bvA); }
    if(tot>1){ pBv=ep_[VIDX(1)]; LDP(pBv,hvB,bvB); }
    pP0=(tot>2)?ep_[VIDX(2)]:0;
    pP1=(tot>3)?ep_[VIDX(3)]:0;
    float acc[8]={0.f,0.f,0.f,0.f,0.f,0.f,0.f,0.f};
    int cur=-1;
    int j=0;
    while(j<tot){
      { // consume A
        float hf[8],bf8[8];
        unp8(hvA,hf); unp8(bvA,bf8);
        int pc=pA;
        if(j+2<tot){ pA=pP0; LDP(pA,hvA,bvA); }
        pP0=pP1;
        pP1=ep_[(j+4<tot)?VIDX(j+4):0];
        int dl=(pc>>4)&31;
        if(dl!=cur){
          if(cur>=0){
            u32 drow=(u32)(grp*32+cur);
            u32 aoff=drow*256+(cbyte^((drow&7)<<4));
            float of[8];
            unp8(*(const uint4*)((const char*)agx+aoff),of);
            #pragma unroll
            for(int q=0;q<8;q++) of[q]+=acc[q];
            *(uint4*)((char*)agx+aoff)=pk8(of);
          }
          #pragma unroll
          for(int q=0;q<8;q++) acc[q]=0.f;
          cur=dl;
        }
        #pragma unroll
        for(int q=0;q<8;q++) acc[q]+=fmaxf(hf[q]+bf8[q],0.f);
      }
      j++;
      if(j>=tot) break;
      { // consume B
        float hf[8],bf8[8];
        unp8(hvB,hf); unp8(bvB,bf8);
        int pc=pBv;
        if(j+2<tot){ pBv=pP0; LDP(pBv,hvB,bvB); }
        pP0=pP1;
        pP1=ep_[(j+4<tot)?VIDX(j+4):0];
        int dl=(pc>>4)&31;
        if(dl!=cur){
          if(cur>=0){
            u32 drow=(u32)(grp*32+cur);
            u32 aoff=drow*256+(cbyte^((drow&7)<<4));
            float of[8];
            unp8(*(const uint4*)((const char*)agx+aoff),of);
            #pragma unroll
            for(int q=0;q<8;q++) of[q]+=acc[q];
            *(uint4*)((char*)agx+aoff)=pk8(of);
          }
          #pragma unroll
          for(int q=0;q<8;q++) acc[q]=0.f;
          cur=dl;
        }
        #pragma unroll
        for(int q=0;q<8;q++) acc[q]+=fmaxf(hf[q]+bf8[q],0.f);
      }
      j++;
    }
    if(cur>=0){
      u32 drow=(u32)(grp*32+cur);
      u32 aoff=drow*256+(cbyte^((drow&7)<<4));
      float of[8];
      unp8(*(const uint4*)((const char*)agx+aoff),of);
      #pragma unroll
      for(int q=0;q<8;q++) of[q]+=acc[q];
      *(uint4*)((char*)agx+aoff)=pk8(of);
    }
  }
  __syncthreads();
  sst[t]=0.f;        // overlays dead epku
  __syncthreads();

  // ---- MLP phase 1: relu(X_in@W1+b1) -> hs
  f32x4 a1[8];
  #pragma unroll
  for(int n8=0;n8<8;n8++) a1[n8]=(f32x4){0.f,0.f,0.f,0.f};
  #pragma unroll
  for(int kc=0;kc<4;kc++){
    u32 cb=(u32)((kc*32+lk*8)*2);
    s16x8 bf=*(const s16x8*)((char*)agx+(u32)rl*256+(cb^rsw));
    #pragma unroll
    for(int n8=0;n8<8;n8++){
      s16x8 af=*(const s16x8*)(W1p+((n8*4+kc)<<9)+lane*8);
      a1[n8]=__builtin_amdgcn_mfma_f32_16x16x32_bf16(af,bf,a1[n8],0,0,0);
    }
  }
  #pragma unroll
  for(int n8=0;n8<8;n8++){
    int c0=n8*16+lk*4;
    float4 b4=*(const float4*)(b1+c0);
    float v[4]={fmaxf(a1[n8][0]+b4.x,0.f),fmaxf(a1[n8][1]+b4.y,0.f),
                fmaxf(a1[n8][2]+b4.z,0.f),fmaxf(a1[n8][3]+b4.w,0.f)};
    *(uint2*)((char*)hs+(u32)rl*256+(((u32)(2*c0))^rsw))=pk4(v);
  }
  // ---- MLP phase 2: relu(.@W2+b2) -> agx + stats
  f32x4 a2[8];
  #pragma unroll
  for(int n8=0;n8<8;n8++) a2[n8]=(f32x4){0.f,0.f,0.f,0.f};
  #pragma unroll
  for(int kc=0;kc<4;kc++){
    u32 cb=(u32)((kc*32+lk*8)*2);
    s16x8 bf=*(const s16x8*)((char*)hs+(u32)rl*256+(cb^rsw));
    #pragma unroll
    for(int n8=0;n8<8;n8++){
      s16x8 af=*(const s16x8*)(W2p+((n8*4+kc)<<9)+lane*8);
      a2[n8]=__builtin_amdgcn_mfma_f32_16x16x32_bf16(af,bf,a2[n8],0,0,0);
    }
  }
  #pragma unroll
  for(int n8=0;n8<8;n8++){
    int c0=n8*16+lk*4;
    float4 b4=*(const float4*)(b2+c0);
    float v[4]={fmaxf(a2[n8][0]+b4.x,0.f),fmaxf(a2[n8][1]+b4.y,0.f),
                fmaxf(a2[n8][2]+b4.z,0.f),fmaxf(a2[n8][3]+b4.w,0.f)};
    *(uint2*)((char*)agx+(u32)rl*256+(((u32)(2*c0))^rsw))=pk4(v);
    float s[4],q[4];
    #pragma unroll
    for(int j2=0;j2<4;j2++){ s[j2]=v[j2]; q[j2]=v[j2]*v[j2]; }
    #pragma unroll
    for(int j2=0;j2<4;j2++){
      #pragma unroll
      for(int d=1;d<16;d<<=1){
        s[j2]+=__shfl_xor(s[j2],d);
        q[j2]+=__shfl_xor(q[j2],d);
      }
    }
    if(lr==0){
      #pragma unroll
      for(int j2=0;j2<4;j2++){
        atomicAdd(&sst[c0+j2],s[j2]);
        atomicAdd(&sst[128+c0+j2],q[j2]);
      }
    }
  }
  __syncthreads();
  uint4* out4=(uint4*)(Xg+hbase);
  #pragma unroll
  for(int p=0;p<4;p++){
    int i=t+p*256;
    u32 row=(u32)(i>>4), colb=(u32)((i&15)*16);
    out4[i]=*(const uint4*)((const char*)agx+row*256+(colb^((row&7)<<4)));
  }
  atomicAdd(&stats[t],sst[t]);
}

// ==== node-path MLP (64-row tile)
__global__ __launch_bounds__(256) void k_mlp2n(
    const u16* __restrict__ A, const u16* __restrict__ W1p, const float* __restrict__ b1,
    const u16* __restrict__ W2p, const float* __restrict__ b2,
    u16* __restrict__ out, float* __restrict__ stats)
{
  __shared__ u16 T[64*128];
  __shared__ float sst[256];
  int t=threadIdx.x;
  sst[t]=0.f;
  int wave=t>>6, lane=t&63, lr=lane&15, lk=lane>>4;
  int rl=wave*16+lr;
  u32 rsw=((u32)(rl&7))<<4;
  int row0=blockIdx.x*64;
  f32x4 a1[8];
  #pragma unroll
  for(int n8=0;n8<8;n8++) a1[n8]=(f32x4){0.f,0.f,0.f,0.f};
  const s16x8* B0=(const s16x8*)(A+(size_t)(row0+rl)*H);
  #pragma unroll
  for(int kc=0;kc<4;kc++){
    s16x8 bf=B0[kc*4+lk];
    #pragma unroll
    for(int n8=0;n8<8;n8++){
      s16x8 af=*(const s16x8*)(W1p+((n8*4+kc)<<9)+lane*8);
      a1[n8]=__builtin_amdgcn_mfma_f32_16x16x32_bf16(af,bf,a1[n8],0,0,0);
    }
  }
  #pragma unroll
  for(int n8=0;n8<8;n8++){
    int c0=n8*16+lk*4;
    float4 b4=*(const float4*)(b1+c0);
    float v[4]={fmaxf(a1[n8][0]+b4.x,0.f),fmaxf(a1[n8][1]+b4.y,0.f),
                fmaxf(a1[n8][2]+b4.z,0.f),fmaxf(a1[n8][3]+b4.w,0.f)};
    *(uint2*)((char*)T+(u32)rl*256+(((u32)(2*c0))^rsw))=pk4(v);
  }
  f32x4 a2[8];
  #pragma unroll
  for(int n8=0;n8<8;n8++) a2[n8]=(f32x4){0.f,0.f,0.f,0.f};
  #pragma unroll
  for(int kc=0;kc<4;kc++){
    u32 cb=(u32)((kc*32+lk*8)*2);
    s16x8 bf=*(const s16x8*)((char*)T+(u32)rl*256+(cb^rsw));
    #pragma unroll
    for(int n8=0;n8<8;n8++){
      s16x8 af=*(const s16x8*)(W2p+((n8*4+kc)<<9)+lane*8);
      a2[n8]=__builtin_amdgcn_mfma_f32_16x16x32_bf16(af,bf,a2[n8],0,0,0);
    }
  }
  #pragma unroll
  for(int n8=0;n8<8;n8++){
    int c0=n8*16+lk*4;
    float4 b4=*(const float4*)(b2+c0);
    float v[4]={fmaxf(a2[n8][0]+b4.x,0.f),fmaxf(a2[n8][1]+b4.y,0.f),
                fmaxf(a2[n8][2]+b4.z,0.f),fmaxf(a2[n8][3]+b4.w,0.f)};
    *(uint2*)((char*)T+(u32)rl*256+(((u32)(2*c0))^rsw))=pk4(v);
    float s[4],q[4];
    #pragma unroll
    for(int j=0;j<4;j++){ s[j]=v[j]; q[j]=v[j]*v[j]; }
    #pragma unroll
    for(int j=0;j<4;j++){
      #pragma unroll
      for(int d=1;d<16;d<<=1){
        s[j]+=__shfl_xor(s[j],d);
        q[j]+=__shfl_xor(q[j],d);
      }
    }
    if(lr==0){
      #pragma unroll
      for(int j=0;j<4;j++){
        atomicAdd(&sst[c0+j],s[j]);
        atomicAdd(&sst[128+c0+j],q[j]);
      }
    }
  }
  __syncthreads();
  uint4* out4=(uint4*)(out+(size_t)row0*H);
  #pragma unroll
  for(int p=0;p<4;p++){
    int i=t+p*256;
    u32 row=(u32)(i>>4), colb=(u32)((i&15)*16);
    out4[i]=*(const uint4*)((const char*)T+row*256+(colb^((row&7)<<4)));
  }
  atomicAdd(&stats[t],sst[t]);
}

// ==== fused node broadcast: bb = ((hn + BN(ag)) @ bcw) @ cw1_bot
__global__ __launch_bounds__(256) void k_bcast(
    const u16* __restrict__ hn, const u16* __restrict__ ag,
    const float* __restrict__ stg, const float* __restrict__ gg, const float* __restrict__ bg,
    const u16* __restrict__ Wbcp, const u16* __restrict__ Wc1p,
    u16* __restrict__ bb)
{
  __shared__ u16 T[64*128];
  __shared__ u16 T2[64*128];
  __shared__ float ssh[128], tsh[128];
  int t=threadIdx.x;
  int row0=blockIdx.x*64;
  if(t<128){
    float mu=stg[t]*(1.f/4096.f);
    float var=stg[128+t]*(1.f/4096.f)-mu*mu;
    float s=gg[t]*rsqrtf(var+1e-5f);
    ssh[t]=s; tsh[t]=bg[t]-mu*s;
  }
  __syncthreads();
  #pragma unroll
  for(int i0=0;i0<4;i0++){
    int i=t+i0*256;
    u32 row=(u32)(i>>4);
    int cb8=(i&15)*8;
    float hv[8],av[8],o8[8];
    unp8(((const uint4*)(hn+(size_t)row0*H))[i],hv);
    unp8(((const uint4*)(ag+(size_t)row0*H))[i],av);
    #pragma unroll
    for(int j=0;j<8;j++) o8[j]=hv[j]+fmaf(av[j],ssh[cb8+j],tsh[cb8+j]);
    *(uint4*)((char*)T+row*256+(((u32)(cb8*2))^((row&7)<<4)))=pk8(o8);
  }
  __syncthreads();
  int wave=t>>6, lane=t&63, lr=lane&15, lk=lane>>4;
  int rl=wave*16+lr;
  u32 rsw=((u32)(rl&7))<<4;
  f32x4 a1[8];
  #pragma unroll
  for(int n8=0;n8<8;n8++) a1[n8]=(f32x4){0.f,0.f,0.f,0.f};
  #pragma unroll
  for(int kc=0;kc<4;kc++){
    u32 cb=(u32)((kc*32+lk*8)*2);
    s16x8 bf=*(const s16x8*)((char*)T+(u32)rl*256+(cb^rsw));
    #pragma unroll
    for(int n8=0;n8<8;n8++){
      s16x8 af=*(const s16x8*)(Wbcp+((n8*4+kc)<<9)+lane*8);
      a1[n8]=__builtin_amdgcn_mfma_f32_16x16x32_bf16(af,bf,a1[n8],0,0,0);
    }
  }
  #pragma unroll
  for(int n8=0;n8<8;n8++){
    int c0=n8*16+lk*4;
    float v[4]={a1[n8][0],a1[n8][1],a1[n8][2],a1[n8][3]};
    *(uint2*)((char*)T2+(u32)rl*256+(((u32)(2*c0))^rsw))=pk4(v);
  }
  f32x4 a2[8];
  #pragma unroll
  for(int n8=0;n8<8;n8++) a2[n8]=(f32x4){0.f,0.f,0.f,0.f};
  #pragma unroll
  for(int kc=0;kc<4;kc++){
    u32 cb=(u32)((kc*32+lk*8)*2);
    s16x8 bf=*(const s16x8*)((char*)T2+(u32)rl*256+(cb^rsw));
    #pragma unroll
    for(int n8=0;n8<8;n8++){
      s16x8 af=*(const s16x8*)(Wc1p+((n8*4+kc)<<9)+lane*8);
      a2[n8]=__builtin_amdgcn_mfma_f32_16x16x32_bf16(af,bf,a2[n8],0,0,0);
    }
  }
  #pragma unroll
  for(int n8=0;n8<8;n8++){
    int c0=n8*16+lk*4;
    float v[4]={a2[n8][0],a2[n8][1],a2[n8][2],a2[n8][3]};
    *(uint2*)((char*)T+(u32)rl*256+(((u32)(2*c0))^rsw))=pk4(v);
  }
  __syncthreads();
  uint4* out4=(uint4*)(bb+(size_t)row0*H);
  #pragma unroll
  for(int p=0;p<4;p++){
    int i=t+p*256;
    u32 row=(u32)(i>>4), colb=(u32)((i&15)*16);
    out4[i]=*(const uint4*)((const char*)T+row*256+(colb^((row&7)<<4)));
  }
}

// ==== final tail + pooling: h_new computed in-block, pooled; h not written
__global__ __launch_bounds__(256) void k_tailpool(
    const u16* __restrict__ X, const u16* __restrict__ W3p, const float* __restrict__ bias3,
    const u16* __restrict__ bb,
    const u16* __restrict__ W2p, const float* __restrict__ cb2,
    const float* __restrict__ lng, const float* __restrict__ lnb,
    const int* __restrict__ validv, const u16* __restrict__ hres,
    const int* __restrict__ batch, float* __restrict__ oacc)
{
  __shared__ u16 T[64*128];
  __shared__ float pbuf[256];
  __shared__ float cntsh[2];
  int t=threadIdx.x;
  int wave=t>>6, lane=t&63, lr=lane&15, lk=lane>>4;
  int rl=wave*16+lr;
  u32 rsw=((u32)(rl&7))<<4;
  int row0=blockIdx.x*64;
  f32x4 acc[8];
  #pragma unroll
  for(int n8=0;n8<8;n8++) acc[n8]=(f32x4){0.f,0.f,0.f,0.f};
  const s16x8* B0=(const s16x8*)(X+(size_t)(row0+rl)*H);
  #pragma unroll
  for(int kc=0;kc<4;kc++){
    s16x8 bf=B0[kc*4+lk];
    #pragma unroll
    for(int n8=0;n8<8;n8++){
      s16x8 af=*(const s16x8*)(W3p+((n8*4+kc)<<9)+lane*8);
      acc[n8]=__builtin_amdgcn_mfma_f32_16x16x32_bf16(af,bf,acc[n8],0,0,0);
    }
  }
  #pragma unroll
  for(int n8=0;n8<8;n8++){
    int c0=n8*16+lk*4;
    float4 b4=*(const float4*)(bias3+c0);
    float rb[4];
    unp4(*(const uint2*)(bb+(size_t)blockIdx.x*H+c0),rb);
    float vb[4]={b4.x,b4.y,b4.z,b4.w};
    float v[4];
    #pragma unroll
    for(int j=0;j<4;j++){
      float x=acc[n8][j]+vb[j]+rb[j];
      v[j]=0.5f*x*(1.f+erff(x*0.70710678118654752f));
    }
    *(uint2*)((char*)T+(u32)rl*256+(((u32)(2*c0))^rsw))=pk4(v);
  }
  f32x4 a2[8];
  #pragma unroll
  for(int n8=0;n8<8;n8++) a2[n8]=(f32x4){0.f,0.f,0.f,0.f};
  #pragma unroll
  for(int kc=0;kc<4;kc++){
    u32 cb=(u32)((kc*32+lk*8)*2);
    s16x8 bf=*(const s16x8*)((char*)T+(u32)rl*256+(cb^rsw));
    #pragma unroll
    for(int n8=0;n8<8;n8++){
      s16x8 af=*(const s16x8*)(W2p+((n8*4+kc)<<9)+lane*8);
      a2[n8]=__builtin_amdgcn_mfma_f32_16x16x32_bf16(af,bf,a2[n8],0,0,0);
    }
  }
  {
    float s=0.f,q=0.f;
    #pragma unroll
    for(int n8=0;n8<8;n8++){
      int c0=n8*16+lk*4;
      float4 b4=*(const float4*)(cb2+c0);
      float vb[4]={b4.x,b4.y,b4.z,b4.w};
      #pragma unroll
      for(int j=0;j<4;j++){
        float v=a2[n8][j]+vb[j];
        a2[n8][j]=v;
        s+=v; q+=v*v;
      }
    }
    s+=__shfl_xor(s,16); s+=__shfl_xor(s,32);
    q+=__shfl_xor(q,16); q+=__shfl_xor(q,32);
    float mu=s*(1.f/128.f);
    float rsig=rsqrtf(q*(1.f/128.f)-mu*mu+1e-5f);
    #pragma unroll
    for(int n8=0;n8<8;n8++){
      int c0=n8*16+lk*4;
      float4 g4=*(const float4*)(lng+c0);
      float4 e4=*(const float4*)(lnb+c0);
      float g[4]={g4.x,g4.y,g4.z,g4.w}, e[4]={e4.x,e4.y,e4.z,e4.w};
      float ov[4];
      #pragma unroll
      for(int j=0;j<4;j++) ov[j]=(a2[n8][j]-mu)*rsig*g[j]+e[j];
      *(uint2*)((char*)T+(u32)rl*256+(((u32)(2*c0))^rsw))=pk4(ov);
    }
  }
  pbuf[t]=0.f;
  if(t<2){
    int s=0;
    for(int j2=0;j2<32;j2++) s+=validv[row0+t*32+j2]?1:0;
    cntsh[t]=fmaxf((float)s,1.f);
  }
  __syncthreads();
  // h_new = (h_old + LN)*valid; accumulate per-subgraph sums (rows p<2 -> sub0)
  const uint4* hp=(const uint4*)(hres+(size_t)row0*H);
  float s0[8]={0,0,0,0,0,0,0,0}, s1[8]={0,0,0,0,0,0,0,0};
  #pragma unroll
  for(int p=0;p<4;p++){
    int i=t+p*256;
    u32 row=(u32)(i>>4), colb=(u32)((i&15)*16);
    int grow=row0+(int)row;
    uint4 v=*(const uint4*)((const char*)T+row*256+(colb^((row&7)<<4)));
    uint4 r=hp[i];
    float vv[8],rv[8];
    unp8(v,vv); unp8(r,rv);
    float vm=validv[grow]?1.f:0.f;
    #pragma unroll
    for(int j2=0;j2<8;j2++){
      float hn=(rv[j2]+vv[j2])*vm;
      if(p<2) s0[j2]+=hn; else s1[j2]+=hn;
    }
  }
  #pragma unroll
  for(int j2=0;j2<8;j2++){
    s0[j2]+=__shfl_xor(s0[j2],16); s0[j2]+=__shfl_xor(s0[j2],32);
    s1[j2]+=__shfl_xor(s1[j2],16); s1[j2]+=__shfl_xor(s1[j2],32);
  }
  if((lane&48)==0){
    int ch=(lane&15)*8;
    #pragma unroll
    for(int j2=0;j2<8;j2++){
      atomicAdd(&pbuf[ch+j2],s0[j2]);
      atomicAdd(&pbuf[128+ch+j2],s1[j2]);
    }
  }
  __syncthreads();
  if(t<128){
    float nodef=0.5f*(pbuf[t]/cntsh[0]+pbuf[128+t]/cntsh[1]);
    atomicAdd(&oacc[batch[blockIdx.x]*H+t],nodef);
  }
}

// ---- h_node = mean of two root rows
__global__ void k_npool(const u16* __restrict__ h, u16* __restrict__ hn){
  int i=blockIdx.x*blockDim.x+threadIdx.x;
  if(i>=NN*16) return;
  int n=i>>4, q=i&15;
  const uint4* hp=(const uint4*)h;
  float a[8],b[8],o[8];
  unp8(hp[(size_t)n*1024+q],a);
  unp8(hp[(size_t)n*1024+512+q],b);
  #pragma unroll
  for(int e=0;e<8;e++) o[e]=(a[e]+b[e])*0.5f;
  ((uint4*)hn)[i]=pk8(o);
}

// ---- global GINE aggregation per node
__global__ __launch_bounds__(128) void k_gagg(const u16* __restrict__ hn, const float* __restrict__ be,
                      const int* __restrict__ goff, const int* __restrict__ gcnt,
                      const int* __restrict__ gpack, const float* __restrict__ epsp, int layer,
                      u16* __restrict__ hhg){
  __shared__ float bes[16][128];
  int n=blockIdx.x, c=threadIdx.x;
  for(int i=0;i<16;i++) bes[i][c]=be[i*128+c];
  __syncthreads();
  float acc=0.f;
  int o=goff[n], e=o+gcnt[n];
  for(;o<e;o++){
    int p=gpack[o];
    acc+=fmaxf(b2f(hn[(size_t)(p>>4)*H+c])+bes[p&15][c],0.f);
  }
  hhg[(size_t)n*H+c]=f2b(fmaf(1.f+epsp[layer],b2f(hn[(size_t)n*H+c]),acc));
}

__global__ void k_out(const float* __restrict__ acc, const int* __restrict__ flag, void* __restrict__ out){
  int i=blockIdx.x*blockDim.x+threadIdx.x;
  if(i>=NGRAPH*H) return;
  if(*flag) ((__hip_bfloat16*)out)[i]=__float2bfloat16(acc[i]);
  else ((float*)out)[i]=acc[i];
}

extern "C" void kernel_launch(void* const* d_in, const int* in_sizes, int n_in,
                              void* d_out, int out_size, void* d_ws, size_t ws_size,
                              hipStream_t stream){
  (void)n_in; (void)out_size;
  int pofs[27]; pofs[0]=0;
  for(int i=0;i<26;i++) pofs[i+1]=pofs[i]+in_sizes[i];
  int ptot=pofs[26];

  char* wsb=(char*)d_ws;
  size_t off=0;
  auto alloc=[&](size_t bytes)->char*{ char* p=wsb+off; off+=(bytes+255)&~(size_t)255; return p; };
  int*   flag =(int*)  alloc(4);
  float* par  =(float*)alloc((size_t)ptot*4);
  u16*   h    =(u16*)  alloc((size_t)SKK*H*2);
  u16*   X    =(u16*)  alloc((size_t)SKK*H*2);
  u16*   wt   =(u16*)  alloc((size_t)28*HH*2);
  u16*   wt3  =(u16*)  alloc((size_t)HH*2);
  float* bias3=(float*)alloc(H*4);
  float* rf   =(float*)alloc((size_t)NN*H*4);
  u16*   bondb=(u16*)  alloc((size_t)16*H*2);
  u16*   hn   =(u16*)  alloc((size_t)NN*H*2);
  u16*   hhg  =(u16*)  alloc((size_t)NN*H*2);
  u16*   ag   =(u16*)  alloc((size_t)NN*H*2);
  u16*   bb   =(u16*)  alloc((size_t)NN*H*2);
  // ---- contiguous zero-init region (one memset) ----
  int*   ecnt =(int*)  alloc(SS*4);
  int*   ecur =(int*)  alloc(SS*4);
  int*   gcnt =(int*)  alloc(NN*4);
  int*   gcur =(int*)  alloc(NN*4);
  float* stats=(float*)alloc(LNUM*512*4);
  float* oacc =(float*)alloc((size_t)NGRAPH*H*4);
  size_t zbytes=(size_t)SS*4+SS*4+NN*4+NN*4+LNUM*512*4+(size_t)NGRAPH*H*4;
  // ---- rest ----
  int* eoff  =(int*)alloc(SS*4);
  int* epack =(int*)alloc((size_t)EI*4);
  int* dstoff=(int*)alloc((size_t)SS*32*4);
  int* goff  =(int*)alloc(NN*4);
  int* gpack =(int*)alloc((size_t)EG*4);

  if(off>ws_size) return;

  const int* xids =(const int*)d_in[26];
  const int* iei  =(const int*)d_in[27];
  const int* iea  =(const int*)d_in[28];
  const int* gei  =(const int*)d_in[29];
  const int* gea  =(const int*)d_in[30];
  const int* nids =(const int*)d_in[31];
  const int* valid=(const int*)d_in[32];
  const int* batch=(const int*)d_in[33];

  const float* atom=par+pofs[0];
  const float* bond=par+pofs[1];
  const float* rw_w=par+pofs[2];
  const float* rw_b=par+pofs[3];
  const float* rwse=par+pofs[4];
  const float* leps=par+pofs[5];
  const float* lb1 =par+pofs[7];
  const float* lb2 =par+pofs[9];
  const float* lbng=par+pofs[10];
  const float* lbnb=par+pofs[11];
  const float* geps=par+pofs[12];
  const float* gb1 =par+pofs[14];
  const float* gb2 =par+pofs[16];
  const float* gbng=par+pofs[17];
  const float* gbnb=par+pofs[18];
  const float* cw1 =par+pofs[20];
  const float* cb1 =par+pofs[21];
  const float* cb2 =par+pofs[23];
  const float* lngp=par+pofs[24];
  const float* lnbp=par+pofs[25];

  k_sniff<<<1,256,0,stream>>>((const u16*)d_in[0], flag);
  CvtArgs ca;
  for(int i=0;i<26;i++){ ca.p[i]=d_in[i]; ca.start[i]=pofs[i]; }
  ca.start[26]=ptot;
  k_convert<<<1024,256,0,stream>>>(ca, flag, par);

  TransArgs ta;
  for(int l=0;l<LNUM;l++){
    ta.src[l*7+0]=pofs[6]+l*HH;           // lw1
    ta.src[l*7+1]=pofs[8]+l*HH;           // lw2
    ta.src[l*7+2]=pofs[13]+l*HH;          // gw1
    ta.src[l*7+3]=pofs[15]+l*HH;          // gw2
    ta.src[l*7+4]=pofs[19]+l*HH;          // bcw
    ta.src[l*7+5]=pofs[20]+l*2*HH+HH;     // cw1 bottom half
    ta.src[l*7+6]=pofs[22]+l*HH;          // cw2
  }
  k_trans<<<28,256,0,stream>>>(par, ta, wt);
  k_cvtbond<<<8,256,0,stream>>>(bond, bondb);

  (void)hipMemsetAsync(ecnt,0,zbytes,stream);

  k_hist<<<2048,256,0,stream>>>(iei+EI, EI, 5, ecnt);
  k_scan<<<1,1024,0,stream>>>(ecnt, eoff, SS);
  k_scatter_i<<<2048,256,0,stream>>>(iei, iea, eoff, ecur, epack);
  k_sortsub<<<SS,128,0,stream>>>(eoff, ecnt, epack, dstoff);
  k_hist<<<512,256,0,stream>>>(gei+EG, EG, 0, gcnt);
  k_scan<<<1,1024,0,stream>>>(gcnt, goff, NN);
  k_scatter_g<<<512,256,0,stream>>>(gei, gea, goff, gcur, gpack);

  k_rwse<<<NN,128,0,stream>>>(rwse, rw_w, rw_b, rf);
  k_h0<<<(SKK*16)/256,256,0,stream>>>(atom, rf, xids, nids, valid, h);

  for(int l=0;l<LNUM;l++){
    float* stl_l=stats+l*512;
    float* stg_l=stats+l*512+256;
    if(l==0){
      k_fused1<0><<<SS/2,256,0,stream>>>(h, bondb, eoff, ecnt, epack, dstoff, leps, l,
          wt+(size_t)(l*7+0)*HH, lb1+l*H, wt+(size_t)(l*7+1)*HH, lb2+l*H, X, stl_l,
          nullptr,nullptr,nullptr,nullptr,nullptr,nullptr,nullptr,nullptr,nullptr);
    } else {
      int pl=l-1;
      k_fused1<1><<<SS/2,256,0,stream>>>(h, bondb, eoff, ecnt, epack, dstoff, leps, l,
          wt+(size_t)(l*7+0)*HH, lb1+l*H, wt+(size_t)(l*7+1)*HH, lb2+l*H, X, stl_l,
          wt3, bias3, bb, wt+(size_t)(pl*7+6)*HH, cb2+pl*H,
          lngp+pl*H, lnbp+pl*H, valid, h);
    }
    k_npool<<<(NN*16)/256,256,0,stream>>>(h, hn);
    k_gagg<<<NN,128,0,stream>>>(hn, bond, goff, gcnt, gpack, geps, l, hhg);
    k_mlp2n<<<NN/64,256,0,stream>>>(hhg, wt+(size_t)(l*7+2)*HH, gb1+l*H,
        wt+(size_t)(l*7+3)*HH, gb2+l*H, ag, stg_l);
    k_bcast<<<NN/64,256,0,stream>>>(hn, ag, stg_l, gbng+l*H, gbnb+l*H,
        wt+(size_t)(l*7+4)*HH, wt+(size_t)(l*7+5)*HH, bb);
    k_prepw3<<<128,128,0,stream>>>(cw1+(size_t)l*2*HH, cb1+l*H, stl_l, lbng+l*H, lbnb+l*H, wt3, bias3);
  }
  {
    int l=LNUM-1;
    k_tailpool<<<SKK/64,256,0,stream>>>(X, wt3, bias3, bb,
        wt+(size_t)(l*7+6)*HH, cb2+l*H, lngp+l*H, lnbp+l*H, valid, h, batch, oacc);
  }
  k_out<<<(NGRAPH*H+255)/256,256,0,stream>>>(oacc, flag, d_out);
}